// Round 2
// baseline (26248.953 us; speedup 1.0000x reference)
//
#include <hip/hip_runtime.h>
#include <math.h>
#include <cstddef>

// ---------------- constants ----------------
constexpr int E = 256, H = 256, H3 = 768;
constexpr int GUH = 3072, GFC = 1024, DEC = 512;
constexpr int NNODES = 87381, NINT = 21845, LEAF0 = 21845, NLEAF = 65536;

static __device__ __forceinline__ float sigf(float x) { return 1.0f / (1.0f + expf(-x)); }

// ---------------- tiled NT GEMM ----------------
// C[m,n] = sum_k A[m*lda+k]*B[n*ldb+k] + bias[n]? + Cin[m*ldc+n]?
// BM=BN=128, BK=16, 256 threads, 8x8 per thread. K multiple of 16,
// lda/ldb multiples of 4, A/B 16B-aligned. Cin==C allowed (in-place add).
__global__ __launch_bounds__(256) void gemm_nt(
    const float* __restrict__ A, int lda,
    const float* __restrict__ B, int ldb,
    const float* __restrict__ bias,
    const float* __restrict__ Cin,
    float* __restrict__ C, int ldc,
    int M, int N, int K)
{
    __shared__ float As[16][128];
    __shared__ float Bs[16][128];
    const int m0 = blockIdx.y * 128, n0 = blockIdx.x * 128;
    const int tid = threadIdx.x;
    const int tx = tid & 15, ty = tid >> 4;

    float acc[8][8];
#pragma unroll
    for (int i = 0; i < 8; ++i)
#pragma unroll
        for (int j = 0; j < 8; ++j) acc[i][j] = 0.0f;

    for (int k0 = 0; k0 < K; k0 += 16) {
#pragma unroll
        for (int v = 0; v < 2; ++v) {
            int idx = tid + v * 256;       // 0..511 over 128x4 float4 grid
            int row = idx >> 2;
            int c4 = idx & 3;
            float4 a = make_float4(0, 0, 0, 0);
            int gm = m0 + row;
            if (gm < M) a = *(const float4*)&A[(size_t)gm * lda + k0 + c4 * 4];
            As[c4 * 4 + 0][row] = a.x; As[c4 * 4 + 1][row] = a.y;
            As[c4 * 4 + 2][row] = a.z; As[c4 * 4 + 3][row] = a.w;
            float4 b = make_float4(0, 0, 0, 0);
            int gn = n0 + row;
            if (gn < N) b = *(const float4*)&B[(size_t)gn * ldb + k0 + c4 * 4];
            Bs[c4 * 4 + 0][row] = b.x; Bs[c4 * 4 + 1][row] = b.y;
            Bs[c4 * 4 + 2][row] = b.z; Bs[c4 * 4 + 3][row] = b.w;
        }
        __syncthreads();
#pragma unroll
        for (int kk = 0; kk < 16; ++kk) {
            float4 a0 = *(const float4*)&As[kk][ty * 8];
            float4 a1 = *(const float4*)&As[kk][ty * 8 + 4];
            float4 b0 = *(const float4*)&Bs[kk][tx * 8];
            float4 b1 = *(const float4*)&Bs[kk][tx * 8 + 4];
            float av[8] = { a0.x,a0.y,a0.z,a0.w,a1.x,a1.y,a1.z,a1.w };
            float bv[8] = { b0.x,b0.y,b0.z,b0.w,b1.x,b1.y,b1.z,b1.w };
#pragma unroll
            for (int i = 0; i < 8; ++i)
#pragma unroll
                for (int j = 0; j < 8; ++j)
                    acc[i][j] = fmaf(av[i], bv[j], acc[i][j]);
        }
        __syncthreads();
    }

#pragma unroll
    for (int i = 0; i < 8; ++i) {
        int gm = m0 + ty * 8 + i;
        if (gm >= M) break;
#pragma unroll
        for (int j = 0; j < 8; ++j) {
            int gn = n0 + tx * 8 + j;
            if (gn < N) {
                float v = acc[i][j];
                if (bias) v += bias[gn];
                if (Cin)  v += Cin[(size_t)gm * ldc + gn];
                C[(size_t)gm * ldc + gn] = v;
            }
        }
    }
}

// ---------------- elementwise kernels ----------------

// LSTM cell step (torch gate order i,f,g,o), g:[n,4*HH], h/c:[n,HH]
template<int HH>
__global__ __launch_bounds__(256) void lstm_step(
    const float* __restrict__ g, float* __restrict__ h, float* __restrict__ c,
    int n, int init)
{
    int idx = blockIdx.x * 256 + threadIdx.x;
    if (idx >= n * HH) return;
    int row = idx / HH;
    int col = idx - row * HH;
    const float* gr = g + (size_t)row * 4 * HH;
    float gi = gr[col], gf = gr[HH + col], gg = gr[2 * HH + col], go = gr[3 * HH + col];
    float cc = sigf(gi) * tanhf(gg);
    if (!init) cc = fmaf(sigf(gf), c[idx], cc);
    c[idx] = cc;
    h[idx] = sigf(go) * tanhf(cc);
}

// fcm (in) = h_ch @ U_f_w.T ; (out) = c_child * sigmoid(x_f_parent + fcm)
// fcm rows are children in order; child abs id = cst + r; parent local = r>>2.
__global__ __launch_bounds__(256) void fc_msg(
    float* __restrict__ fcm, const float* __restrict__ c,
    const float* __restrict__ xf_l, int cst, int Cn)
{
    int idx = blockIdx.x * 256 + threadIdx.x;
    if (idx >= Cn * 4 * H) return;
    int r = idx >> 8, col = idx & 255;
    int pl = r >> 2;
    int child = cst + r;
    float f = sigf(xf_l[(size_t)pl * H + col] + fcm[idx]);
    fcm[idx] = c[(size_t)child * H + col] * f;
}

// leaves: iou:[count,768] local -> h,c rows abs0..abs0+count
__global__ __launch_bounds__(256) void leaf_apply(
    const float* __restrict__ iou, float* __restrict__ h, float* __restrict__ c,
    int abs0, int count)
{
    int row = blockIdx.x;
    if (row >= count) return;
    int col = threadIdx.x;
    const float* r = iou + (size_t)row * H3;
    float i = r[col], o = r[H + col], u = r[2 * H + col];
    float cc = sigf(i) * tanhf(u);
    size_t off = (size_t)(abs0 + row) * H + col;
    c[off] = cc;
    h[off] = sigf(o) * tanhf(cc);
}

// internal apply: iou = x_iou_local + Uh_sum ; c = sig(i)*tanh(u)+fc_sum ; h = sig(o)*tanh(c)
__global__ __launch_bounds__(256) void node_apply(
    const float* __restrict__ xiou_l, const float* __restrict__ h_uh,
    const float* __restrict__ h_fc, float* __restrict__ h, float* __restrict__ c,
    int sa, int Cn)
{
    int idx = blockIdx.x * 256 + threadIdx.x;
    if (idx >= Cn * H) return;
    int row = idx >> 8, col = idx & 255;
    const float* xr = xiou_l + (size_t)row * H3;
    const float* ur = h_uh + (size_t)row * H3;
    float i = xr[col] + ur[col];
    float o = xr[H + col] + ur[H + col];
    float u = xr[2 * H + col] + ur[2 * H + col];
    float cc = sigf(i) * tanhf(u) + h_fc[idx];
    size_t off = (size_t)(sa + row) * H + col;
    c[off] = cc;
    h[off] = sigf(o) * tanhf(cc);
}

__global__ __launch_bounds__(256) void bias_prep(
    const float* __restrict__ a, const float* __restrict__ b, float* __restrict__ o, int n)
{
    int i = blockIdx.x * 256 + threadIdx.x;
    if (i < n) o[i] = a[i] + b[i];
}

__global__ __launch_bounds__(256) void transpose_768x256(
    const float* __restrict__ in, float* __restrict__ out)
{
    int idx = blockIdx.x * 256 + threadIdx.x; // 196608
    if (idx >= H3 * E) return;
    int r = idx >> 8, cidx = idx & 255;
    out[(size_t)cidx * H3 + r] = in[idx];
}

// LayerNorm(512) + tanh, in-place on y:[Nrows,512]; one wave per row
__global__ __launch_bounds__(256) void ln_tanh(
    float* __restrict__ y, const float* __restrict__ g, const float* __restrict__ b,
    int Nrows)
{
    int wave = threadIdx.x >> 6;
    int lane = threadIdx.x & 63;
    int row = blockIdx.x * 4 + wave;
    if (row >= Nrows) return;
    float* yr = y + (size_t)row * DEC;
    float4 v0 = *(const float4*)&yr[lane * 8];
    float4 v1 = *(const float4*)&yr[lane * 8 + 4];
    float s = v0.x + v0.y + v0.z + v0.w + v1.x + v1.y + v1.z + v1.w;
    float s2 = v0.x * v0.x + v0.y * v0.y + v0.z * v0.z + v0.w * v0.w +
               v1.x * v1.x + v1.y * v1.y + v1.z * v1.z + v1.w * v1.w;
#pragma unroll
    for (int off = 32; off; off >>= 1) {
        s += __shfl_xor(s, off);
        s2 += __shfl_xor(s2, off);
    }
    float m = s * (1.0f / DEC);
    float var = s2 * (1.0f / DEC) - m * m;
    float rstd = rsqrtf(var + 1e-5f);
    float vals[8] = { v0.x,v0.y,v0.z,v0.w,v1.x,v1.y,v1.z,v1.w };
    float o[8];
#pragma unroll
    for (int j = 0; j < 8; ++j) {
        int colj = lane * 8 + j;
        o[j] = tanhf((vals[j] - m) * rstd * g[colj] + b[colj]);
    }
    *(float4*)&yr[lane * 8] = make_float4(o[0], o[1], o[2], o[3]);
    *(float4*)&yr[lane * 8 + 4] = make_float4(o[4], o[5], o[6], o[7]);
}

// ---------------- host ----------------
static inline void launch_gemm(const float* A, int lda, const float* B, int ldb,
    const float* bias, const float* Cin, float* C, int ldc,
    int M, int N, int K, hipStream_t s)
{
    dim3 grid((N + 127) / 128, (M + 127) / 128);
    gemm_nt<<<grid, 256, 0, s>>>(A, lda, B, ldb, bias, Cin, C, ldc, M, N, K);
}

extern "C" void kernel_launch(void* const* d_in, const int* in_sizes, int n_in,
                              void* d_out, int out_size, void* d_ws, size_t ws_size,
                              hipStream_t stream)
{
    (void)in_sizes; (void)n_in; (void)out_size;
    const float* embed   = (const float*)d_in[0];
    const float* W_iou_w = (const float*)d_in[1];
    const float* W_iou_b = (const float*)d_in[2];
    const float* U_iou_w = (const float*)d_in[3];
    const float* W_f_w   = (const float*)d_in[4];
    const float* W_f_b   = (const float*)d_in[5];
    const float* U_f_w   = (const float*)d_in[6];
    const float* uh_wih  = (const float*)d_in[7];
    const float* uh_whh  = (const float*)d_in[8];
    const float* uh_bih  = (const float*)d_in[9];
    const float* uh_bhh  = (const float*)d_in[10];
    const float* fc_wih  = (const float*)d_in[11];
    const float* fc_whh  = (const float*)d_in[12];
    const float* fc_bih  = (const float*)d_in[13];
    const float* fc_bhh  = (const float*)d_in[14];
    const float* out_w   = (const float*)d_in[15];
    const float* out_b   = (const float*)d_in[16];
    const float* ln_g    = (const float*)d_in[17];
    const float* ln_b    = (const float*)d_in[18];

    // ---- node state lives in d_out: hbuf | cbuf == exactly out_size floats ----
    float* out  = (float*)d_out;
    float* hbuf = out;                           // [NNODES, H]
    float* cbuf = out + (size_t)NNODES * H;      // [NNODES, H]

    // ---- adaptive chunk size from ws_size ----
    // fixed ws: folded (GUH*E) + Ut (E*H3) + bsu (GUH) + bsf (GFC)
    // per-chunk: xiou_l 768 + xf_l 256 + gbuf 3072 + gfc 1024 + hfc 256 + cfc 256
    //            + h_uh 768 + c_uh 768 + fcm 1024 = 8192 floats per row
    size_t avail = ws_size / sizeof(float);
    size_t fixedW = (size_t)GUH * E + (size_t)E * H3 + GUH + GFC;   // 987,136
    long long room = (long long)avail - (long long)fixedW - 4096;
    long long Cl = room / 8192;
    int C;
    if (Cl >= 16384) C = 16384;
    else if (Cl <= 256) C = 256;
    else C = (int)((Cl / 256) * 256);

    float* ws = (float*)d_ws;
    size_t o = 0;
    float* folded = ws + o; o += (size_t)GUH * E;
    float* Ut     = ws + o; o += (size_t)E * H3;
    float* bsu    = ws + o; o += GUH;
    float* bsf    = ws + o; o += GFC;
    float* xiou_l = ws + o; o += (size_t)C * H3;
    float* xf_l   = ws + o; o += (size_t)C * H;
    float* gbuf   = ws + o; o += (size_t)C * GUH;   // also leaf-iou (4C x 768) & out staging (C x 512)
    float* gfc    = ws + o; o += (size_t)C * GFC;
    float* hfc    = ws + o; o += (size_t)C * H;
    float* cfc    = ws + o; o += (size_t)C * H;
    float* h_uh   = ws + o; o += (size_t)C * H3;
    float* c_uh   = ws + o; o += (size_t)C * H3;
    float* fcm    = ws + o; o += (size_t)C * GFC;

    // ---- prep ----
    bias_prep<<<(GUH + 255) / 256, 256, 0, stream>>>(uh_bih, uh_bhh, bsu, GUH);
    bias_prep<<<(GFC + 255) / 256, 256, 0, stream>>>(fc_bih, fc_bhh, bsf, GFC);
    transpose_768x256<<<(H3 * E + 255) / 256, 256, 0, stream>>>(U_iou_w, Ut);
    // folded[g,e] = sum_h uh_wih[g,h] * U_iou_w[h,e]  (B = Ut, NT form)
    launch_gemm(uh_wih, H3, Ut, H3, nullptr, nullptr, folded, E, GUH, E, H3, stream);

    // ---- leaves (chunks of 4C rows through gbuf) ----
    for (int ls = 0; ls < NLEAF; ls += 4 * C) {
        int Ln = NLEAF - ls < 4 * C ? NLEAF - ls : 4 * C;
        launch_gemm(embed + (size_t)(LEAF0 + ls) * E, E, W_iou_w, E, W_iou_b, nullptr,
                    gbuf, H3, Ln, H3, E, stream);
        leaf_apply<<<Ln, 256, 0, stream>>>(gbuf, hbuf, cbuf, LEAF0 + ls, Ln);
    }

    // ---- levels, deepest internal -> root, chunked over nodes ----
    const int counts[8] = { 1, 4, 16, 64, 256, 1024, 4096, 16384 };
    const int offs[8]   = { 0, 1, 5, 21, 85, 341, 1365, 5461 };
    for (int d = 7; d >= 0; --d) {
        int n = counts[d], start = offs[d];
        for (int s = 0; s < n; s += C) {
            int Cn = n - s < C ? n - s : C;
            int sa = start + s;          // absolute node start
            int cst = 4 * sa + 1;        // absolute child start

            // per-chunk x projections
            launch_gemm(embed + (size_t)sa * E, E, W_iou_w, E, W_iou_b, nullptr,
                        xiou_l, H3, Cn, H3, E, stream);
            launch_gemm(embed + (size_t)sa * E, E, W_f_w, E, W_f_b, nullptr,
                        xf_l, H, Cn, H, E, stream);

            // fc messages: pre = h_ch @ U_f_w.T ; fcm = c_ch * sigmoid(x_f + pre)
            launch_gemm(hbuf + (size_t)cst * H, H, U_f_w, H, nullptr, nullptr,
                        fcm, H, 4 * Cn, H, H, stream);
            fc_msg<<<(4 * Cn * H + 255) / 256, 256, 0, stream>>>(fcm, cbuf, xf_l, cst, Cn);

            // step 0 (h=c=0): g = token ih (+bias)
            launch_gemm(xiou_l, H3, uh_wih, H3, bsu, nullptr, gbuf, GUH, Cn, GUH, H3, stream);
            lstm_step<H3><<<(Cn * H3 + 255) / 256, 256, 0, stream>>>(gbuf, h_uh, c_uh, Cn, 1);
            launch_gemm(xf_l, H, fc_wih, H, bsf, nullptr, gfc, GFC, Cn, GFC, H, stream);
            lstm_step<H><<<(Cn * H + 255) / 256, 256, 0, stream>>>(gfc, hfc, cfc, Cn, 1);

            // steps 1..4: per-child messages
            for (int t = 1; t <= 4; ++t) {
                launch_gemm(hbuf + (size_t)(cst + t - 1) * H, 4 * H, folded, E, bsu, nullptr,
                            gbuf, GUH, Cn, GUH, E, stream);
                launch_gemm(h_uh, H3, uh_whh, H3, nullptr, gbuf,
                            gbuf, GUH, Cn, GUH, H3, stream);
                lstm_step<H3><<<(Cn * H3 + 255) / 256, 256, 0, stream>>>(gbuf, h_uh, c_uh, Cn, 0);

                launch_gemm(fcm + (size_t)(t - 1) * H, 4 * H, fc_wih, H, bsf, nullptr,
                            gfc, GFC, Cn, GFC, H, stream);
                launch_gemm(hfc, H, fc_whh, H, nullptr, gfc,
                            gfc, GFC, Cn, GFC, H, stream);
                lstm_step<H><<<(Cn * H + 255) / 256, 256, 0, stream>>>(gfc, hfc, cfc, Cn, 0);
            }

            // step 5 (token again; recompute token ih)
            launch_gemm(xiou_l, H3, uh_wih, H3, bsu, nullptr, gbuf, GUH, Cn, GUH, H3, stream);
            launch_gemm(h_uh, H3, uh_whh, H3, nullptr, gbuf, gbuf, GUH, Cn, GUH, H3, stream);
            lstm_step<H3><<<(Cn * H3 + 255) / 256, 256, 0, stream>>>(gbuf, h_uh, c_uh, Cn, 0);
            launch_gemm(xf_l, H, fc_wih, H, bsf, nullptr, gfc, GFC, Cn, GFC, H, stream);
            launch_gemm(hfc, H, fc_whh, H, nullptr, gfc, gfc, GFC, Cn, GFC, H, stream);
            lstm_step<H><<<(Cn * H + 255) / 256, 256, 0, stream>>>(gfc, hfc, cfc, Cn, 0);

            // apply node func
            node_apply<<<(Cn * H + 255) / 256, 256, 0, stream>>>(
                xiou_l, h_uh, hfc, hbuf, cbuf, sa, Cn);
        }
    }

    // ---- output projection (descending chunks; writes never clobber pending h reads) ----
    for (long long s = ((NNODES - 1) / C) * (long long)C; s >= 0; s -= C) {
        int Cn = (int)(NNODES - s < C ? NNODES - s : C);
        if (s >= C) {
            launch_gemm(hbuf + (size_t)s * H, H, out_w, H, out_b, nullptr,
                        out + (size_t)s * DEC, DEC, Cn, DEC, H, stream);
        } else {
            // s == 0: writes would overlap reads; stage through gbuf then D2D copy
            launch_gemm(hbuf, H, out_w, H, out_b, nullptr, gbuf, DEC, Cn, DEC, H, stream);
            hipMemcpyAsync(out, gbuf, (size_t)Cn * DEC * sizeof(float),
                           hipMemcpyDeviceToDevice, stream);
        }
    }

    // ---- LayerNorm + tanh over all rows ----
    ln_tanh<<<(NNODES + 3) / 4, 256, 0, stream>>>(out, ln_g, ln_b, NNODES);
}

// Round 4
// 9347.733 us; speedup vs baseline: 2.8081x; 2.8081x over previous
//
#include <hip/hip_runtime.h>
#include <math.h>
#include <cstddef>
#include <cstdint>

// ---------------- constants ----------------
constexpr int E = 256, H = 256, H3 = 768;
constexpr int GUH = 3072, GFC = 1024, DEC = 512;
constexpr int NNODES = 87381, LEAF0 = 21845, NLEAF = 65536;

typedef __attribute__((ext_vector_type(8))) short bf16x8;
typedef __attribute__((ext_vector_type(4))) float f32x4;
typedef unsigned int u32;
typedef __attribute__((address_space(1))) const u32 gu32;
typedef __attribute__((address_space(3))) u32 lu32;

static __device__ __forceinline__ float sigf(float x) { return 1.0f / (1.0f + expf(-x)); }
static __device__ __forceinline__ ushort f2bf(float x) {
    u32 u = __float_as_uint(x);
    return (ushort)((u + 0x7fffu + ((u >> 16) & 1u)) >> 16);   // RNE
}
static __device__ __forceinline__ float bf2f(ushort v) { return __uint_as_float(((u32)v) << 16); }

static __device__ __forceinline__ void gload16(const void* g, void* l) {
    __builtin_amdgcn_global_load_lds((gu32*)g, (lu32*)l, 16, 0, 0);
}

// ---------------- multi-pair MFMA NT GEMM ----------------
// C[m,n] = sum_p sum_k Ap[m,k]*Bp[n,k] + bias[n]?   (up to 4 pairs, K mult of 32)
// bf16 inputs. 128x128 tile, BK=32, 256 thr = 4 waves, 4x4 16x16x32 frags.
// N multiple of 128. M-edge rows are read OOB (must be inside the allocation)
// but never stored.
struct Pairs {
    const ushort* A[4];
    const ushort* B[4];
    int lda[4], ldb[4], K[4];
};

__global__ __launch_bounds__(256) void gemm_mfma(
    Pairs pr, const float* __restrict__ bias,
    float* __restrict__ Cf, ushort* __restrict__ Cb,
    int ldc, int M, int N)
{
    __shared__ ushort As[2][128 * 32];
    __shared__ ushort Bs[2][128 * 32];
    const int tid = threadIdx.x;
    const int m0 = blockIdx.y * 128, n0 = blockIdx.x * 128;
    const int wave = tid >> 6, lane = tid & 63;
    const int wm = (wave >> 1) * 64, wn = (wave & 1) * 64;
    const int lr = lane & 15, kg = lane >> 4;

    f32x4 acc[4][4];
#pragma unroll
    for (int i = 0; i < 4; ++i)
#pragma unroll
        for (int j = 0; j < 4; ++j) acc[i][j] = (f32x4){0.f, 0.f, 0.f, 0.f};

    const int nt = (pr.K[0] + pr.K[1] + pr.K[2] + pr.K[3]) >> 5;

    auto stage = [&](int t, int b) {
        int p = 0, rem = t;
        while (rem >= (pr.K[p] >> 5)) { rem -= pr.K[p] >> 5; ++p; }
        const ushort* Ap = pr.A[p];
        const ushort* Bp = pr.B[p];
        const int la = pr.lda[p], lb = pr.ldb[p], k0 = rem * 32;
#pragma unroll
        for (int v = 0; v < 2; ++v) {
            int idx = v * 256 + tid;
            int row = idx >> 2, c = idx & 3;
            gload16(Ap + (size_t)(m0 + row) * la + k0 + c * 8, &As[b][idx * 8]);
            gload16(Bp + (size_t)(n0 + row) * lb + k0 + c * 8, &Bs[b][idx * 8]);
        }
    };

    stage(0, 0);
    for (int t = 0; t < nt; ++t) {
        __syncthreads();                    // compiler drains vmcnt before barrier
        if (t + 1 < nt) stage(t + 1, (t + 1) & 1);
        const ushort* as = As[t & 1];
        const ushort* bs = Bs[t & 1];
        bf16x8 af[4], bfr[4];
#pragma unroll
        for (int i = 0; i < 4; ++i) {
            af[i]  = *(const bf16x8*)&as[(wm + i * 16 + lr) * 32 + kg * 8];
            bfr[i] = *(const bf16x8*)&bs[(wn + i * 16 + lr) * 32 + kg * 8];
        }
#pragma unroll
        for (int i = 0; i < 4; ++i)
#pragma unroll
            for (int j = 0; j < 4; ++j)
                acc[i][j] = __builtin_amdgcn_mfma_f32_16x16x32_bf16(af[i], bfr[j], acc[i][j], 0, 0, 0);
    }

    // D: col = lane&15, row = (lane>>4)*4 + r
#pragma unroll
    for (int i = 0; i < 4; ++i) {
#pragma unroll
        for (int j = 0; j < 4; ++j) {
            int col = n0 + wn + j * 16 + lr;
            float bv = bias ? bias[col] : 0.f;
#pragma unroll
            for (int r = 0; r < 4; ++r) {
                int rowg = m0 + wm + i * 16 + kg * 4 + r;
                if (rowg < M) {
                    float v = acc[i][j][r] + bv;
                    if (Cf) Cf[(size_t)rowg * ldc + col] = v;
                    if (Cb) Cb[(size_t)rowg * ldc + col] = f2bf(v);
                }
            }
        }
    }
}

// ---------------- f32 tiled NT GEMM (prep only: folded weight) ----------------
__global__ __launch_bounds__(256) void gemm_nt_f32(
    const float* __restrict__ A, int lda,
    const float* __restrict__ B, int ldb,
    float* __restrict__ C, int ldc, int M, int N, int K)
{
    __shared__ float As[16][128];
    __shared__ float Bs[16][128];
    const int m0 = blockIdx.y * 128, n0 = blockIdx.x * 128;
    const int tid = threadIdx.x;
    const int tx = tid & 15, ty = tid >> 4;
    float acc[8][8];
#pragma unroll
    for (int i = 0; i < 8; ++i)
#pragma unroll
        for (int j = 0; j < 8; ++j) acc[i][j] = 0.0f;
    for (int k0 = 0; k0 < K; k0 += 16) {
#pragma unroll
        for (int v = 0; v < 2; ++v) {
            int idx = tid + v * 256;
            int row = idx >> 2, c4 = idx & 3;
            float4 a = make_float4(0, 0, 0, 0);
            int gm = m0 + row;
            if (gm < M) a = *(const float4*)&A[(size_t)gm * lda + k0 + c4 * 4];
            As[c4 * 4 + 0][row] = a.x; As[c4 * 4 + 1][row] = a.y;
            As[c4 * 4 + 2][row] = a.z; As[c4 * 4 + 3][row] = a.w;
            float4 b = make_float4(0, 0, 0, 0);
            int gn = n0 + row;
            if (gn < N) b = *(const float4*)&B[(size_t)gn * ldb + k0 + c4 * 4];
            Bs[c4 * 4 + 0][row] = b.x; Bs[c4 * 4 + 1][row] = b.y;
            Bs[c4 * 4 + 2][row] = b.z; Bs[c4 * 4 + 3][row] = b.w;
        }
        __syncthreads();
#pragma unroll
        for (int kk = 0; kk < 16; ++kk) {
            float4 a0 = *(const float4*)&As[kk][ty * 8];
            float4 a1 = *(const float4*)&As[kk][ty * 8 + 4];
            float4 b0 = *(const float4*)&Bs[kk][tx * 8];
            float4 b1 = *(const float4*)&Bs[kk][tx * 8 + 4];
            float av[8] = { a0.x,a0.y,a0.z,a0.w,a1.x,a1.y,a1.z,a1.w };
            float bv[8] = { b0.x,b0.y,b0.z,b0.w,b1.x,b1.y,b1.z,b1.w };
#pragma unroll
            for (int i = 0; i < 8; ++i)
#pragma unroll
                for (int j = 0; j < 8; ++j)
                    acc[i][j] = fmaf(av[i], bv[j], acc[i][j]);
        }
        __syncthreads();
    }
#pragma unroll
    for (int i = 0; i < 8; ++i) {
        int gm = m0 + ty * 8 + i;
        if (gm >= M) break;
#pragma unroll
        for (int j = 0; j < 8; ++j) {
            int gn = n0 + tx * 8 + j;
            if (gn < N) C[(size_t)gm * ldc + gn] = acc[i][j];
        }
    }
}

// ---------------- elementwise kernels ----------------

// LSTM step (torch order i,f,g,o): g f32 [n,4HH] -> h (f32 + bf16), c f32
template<int HH>
__global__ __launch_bounds__(256) void lstm_step(
    const float* __restrict__ g, float* __restrict__ hf, ushort* __restrict__ hb,
    float* __restrict__ c, int n, int init)
{
    int idx = blockIdx.x * 256 + threadIdx.x;
    int tot = n * (HH / 4);
    if (idx >= tot) return;
    int row = idx / (HH / 4);
    int c4 = (idx - row * (HH / 4)) * 4;
    const float* gr = g + (size_t)row * 4 * HH;
    float4 gi = *(const float4*)&gr[c4];
    float4 gf = *(const float4*)&gr[HH + c4];
    float4 gg = *(const float4*)&gr[2 * HH + c4];
    float4 go = *(const float4*)&gr[3 * HH + c4];
    size_t off = (size_t)row * HH + c4;
    float4 cp = make_float4(0.f, 0.f, 0.f, 0.f);
    if (!init) cp = *(const float4*)&c[off];
    float gia[4] = { gi.x,gi.y,gi.z,gi.w }, gfa[4] = { gf.x,gf.y,gf.z,gf.w };
    float gga[4] = { gg.x,gg.y,gg.z,gg.w }, goa[4] = { go.x,go.y,go.z,go.w };
    float cpa[4] = { cp.x,cp.y,cp.z,cp.w };
    float cc[4], hh[4]; ushort hu[4];
#pragma unroll
    for (int j = 0; j < 4; ++j) {
        float v = sigf(gia[j]) * tanhf(gga[j]);
        if (!init) v = fmaf(sigf(gfa[j]), cpa[j], v);
        cc[j] = v;
        hh[j] = sigf(goa[j]) * tanhf(v);
        hu[j] = f2bf(hh[j]);
    }
    *(float4*)&c[off] = make_float4(cc[0], cc[1], cc[2], cc[3]);
    *(float4*)&hf[off] = make_float4(hh[0], hh[1], hh[2], hh[3]);
    *(ushort4*)&hb[off] = make_ushort4(hu[0], hu[1], hu[2], hu[3]);
}

// fcm = c_child * sigmoid(x_f_parent + pre) -> bf16
__global__ __launch_bounds__(256) void fc_msg(
    const float* __restrict__ pre, const float* __restrict__ xf_f,
    const float* __restrict__ cbuf, ushort* __restrict__ fcm,
    int cst, int Cn)
{
    int idx = blockIdx.x * 256 + threadIdx.x;
    int tot = Cn * 4 * (H / 4);
    if (idx >= tot) return;
    int r = idx >> 6;
    int c4 = (idx & 63) * 4;
    int pl = r >> 2;
    int child = cst + r;
    float4 p = *(const float4*)&pre[(size_t)r * H + c4];
    float4 xv = *(const float4*)&xf_f[(size_t)pl * H + c4];
    float4 cv = *(const float4*)&cbuf[(size_t)child * H + c4];
    ushort o0 = f2bf(cv.x * sigf(xv.x + p.x));
    ushort o1 = f2bf(cv.y * sigf(xv.y + p.y));
    ushort o2 = f2bf(cv.z * sigf(xv.z + p.z));
    ushort o3 = f2bf(cv.w * sigf(xv.w + p.w));
    *(ushort4*)&fcm[(size_t)r * H + c4] = make_ushort4(o0, o1, o2, o3);
}

// leaves: iou f32 [count,768] -> h (f32+bf16), c f32 at rows abs0..
__global__ __launch_bounds__(256) void leaf_apply(
    const float* __restrict__ iou, float* __restrict__ hf, ushort* __restrict__ hb,
    float* __restrict__ c, int abs0, int count)
{
    int idx = blockIdx.x * 256 + threadIdx.x;
    int tot = count * (H / 4);
    if (idx >= tot) return;
    int row = idx >> 6;
    int c4 = (idx & 63) * 4;
    const float* r = iou + (size_t)row * H3;
    float4 vi = *(const float4*)&r[c4];
    float4 vo = *(const float4*)&r[H + c4];
    float4 vu = *(const float4*)&r[2 * H + c4];
    float ia[4] = { vi.x,vi.y,vi.z,vi.w }, oa[4] = { vo.x,vo.y,vo.z,vo.w }, ua[4] = { vu.x,vu.y,vu.z,vu.w };
    size_t off = (size_t)(abs0 + row) * H + c4;
    float cc[4], hh[4]; ushort hu[4];
#pragma unroll
    for (int j = 0; j < 4; ++j) {
        cc[j] = sigf(ia[j]) * tanhf(ua[j]);
        hh[j] = sigf(oa[j]) * tanhf(cc[j]);
        hu[j] = f2bf(hh[j]);
    }
    *(float4*)&c[off] = make_float4(cc[0], cc[1], cc[2], cc[3]);
    *(float4*)&hf[off] = make_float4(hh[0], hh[1], hh[2], hh[3]);
    *(ushort4*)&hb[off] = make_ushort4(hu[0], hu[1], hu[2], hu[3]);
}

// internal apply: all inputs f32 master
__global__ __launch_bounds__(256) void node_apply(
    const float* __restrict__ xiou_f, const float* __restrict__ h_uh_f,
    const float* __restrict__ hfc_f, float* __restrict__ hf, ushort* __restrict__ hb,
    float* __restrict__ c, int sa, int Cn)
{
    int idx = blockIdx.x * 256 + threadIdx.x;
    int tot = Cn * (H / 4);
    if (idx >= tot) return;
    int row = idx >> 6;
    int c4 = (idx & 63) * 4;
    const float* xr = xiou_f + (size_t)row * H3;
    const float* ur = h_uh_f + (size_t)row * H3;
    float4 xi = *(const float4*)&xr[c4];
    float4 xo = *(const float4*)&xr[H + c4];
    float4 xu = *(const float4*)&xr[2 * H + c4];
    float4 ui = *(const float4*)&ur[c4];
    float4 uo = *(const float4*)&ur[H + c4];
    float4 uu = *(const float4*)&ur[2 * H + c4];
    float4 fv = *(const float4*)&hfc_f[(size_t)row * H + c4];
    float xia[4] = { xi.x,xi.y,xi.z,xi.w }, xoa[4] = { xo.x,xo.y,xo.z,xo.w }, xua[4] = { xu.x,xu.y,xu.z,xu.w };
    float uia[4] = { ui.x,ui.y,ui.z,ui.w }, uoa[4] = { uo.x,uo.y,uo.z,uo.w }, uua[4] = { uu.x,uu.y,uu.z,uu.w };
    float fva[4] = { fv.x,fv.y,fv.z,fv.w };
    size_t off = (size_t)(sa + row) * H + c4;
    float cc[4], hh[4]; ushort hu[4];
#pragma unroll
    for (int j = 0; j < 4; ++j) {
        float iv = xia[j] + uia[j];
        float ov = xoa[j] + uoa[j];
        float uv = xua[j] + uua[j];
        float cv = sigf(iv) * tanhf(uv) + fva[j];
        cc[j] = cv;
        hh[j] = sigf(ov) * tanhf(cv);
        hu[j] = f2bf(hh[j]);
    }
    *(float4*)&c[off] = make_float4(cc[0], cc[1], cc[2], cc[3]);
    *(float4*)&hf[off] = make_float4(hh[0], hh[1], hh[2], hh[3]);
    *(ushort4*)&hb[off] = make_ushort4(hu[0], hu[1], hu[2], hu[3]);
}

__global__ __launch_bounds__(256) void bias_sum(
    const float* __restrict__ a, const float* __restrict__ b, float* __restrict__ o, int n)
{
    int i = blockIdx.x * 256 + threadIdx.x;
    if (i < n) o[i] = a[i] + b[i];
}

__global__ __launch_bounds__(256) void cvt_bf16(
    const float* __restrict__ in, ushort* __restrict__ out, int n)
{
    int idx = blockIdx.x * 256 + threadIdx.x;
    if (idx * 4 >= n) return;
    float4 v = *(const float4*)&in[idx * 4];
    *(ushort4*)&out[idx * 4] = make_ushort4(f2bf(v.x), f2bf(v.y), f2bf(v.z), f2bf(v.w));
}

// split f32 -> hi bf16 + lo bf16  (x ~= hi + lo, ~2^-17 relative)
__global__ __launch_bounds__(256) void cvt_split(
    const float* __restrict__ in, ushort* __restrict__ hi, ushort* __restrict__ lo, int n)
{
    int idx = blockIdx.x * 256 + threadIdx.x;
    if (idx * 4 >= n) return;
    float4 v = *(const float4*)&in[idx * 4];
    float va[4] = { v.x, v.y, v.z, v.w };
    ushort ha[4], la[4];
#pragma unroll
    for (int j = 0; j < 4; ++j) {
        ha[j] = f2bf(va[j]);
        la[j] = f2bf(va[j] - bf2f(ha[j]));
    }
    *(ushort4*)&hi[idx * 4] = make_ushort4(ha[0], ha[1], ha[2], ha[3]);
    *(ushort4*)&lo[idx * 4] = make_ushort4(la[0], la[1], la[2], la[3]);
}

// h_lo = bf16(h_f32 - bf2f(h_hi))
__global__ __launch_bounds__(256) void make_hlo(
    const float* __restrict__ hf, const ushort* __restrict__ hb,
    ushort* __restrict__ lo, int n)
{
    int idx = blockIdx.x * 256 + threadIdx.x;
    if (idx * 4 >= n) return;
    float4 v = *(const float4*)&hf[idx * 4];
    ushort4 hv = *(const ushort4*)&hb[idx * 4];
    float va[4] = { v.x, v.y, v.z, v.w };
    ushort ha[4] = { hv.x, hv.y, hv.z, hv.w };
    ushort la[4];
#pragma unroll
    for (int j = 0; j < 4; ++j) la[j] = f2bf(va[j] - bf2f(ha[j]));
    *(ushort4*)&lo[idx * 4] = make_ushort4(la[0], la[1], la[2], la[3]);
}

// U_iou_w f32 [768,256] -> f32 [256,768] transpose
__global__ __launch_bounds__(256) void transpose_f32(
    const float* __restrict__ in, float* __restrict__ out)
{
    int idx = blockIdx.x * 256 + threadIdx.x;
    if (idx >= H3 * E) return;
    int r = idx >> 8, c = idx & 255;
    out[(size_t)c * H3 + r] = in[idx];
}

// LayerNorm(512)+tanh in-place, one wave per row
__global__ __launch_bounds__(256) void ln_tanh(
    float* __restrict__ y, const float* __restrict__ g, const float* __restrict__ b,
    int Nrows)
{
    int wave = threadIdx.x >> 6;
    int lane = threadIdx.x & 63;
    int row = blockIdx.x * 4 + wave;
    if (row >= Nrows) return;
    float* yr = y + (size_t)row * DEC;
    float4 v0 = *(const float4*)&yr[lane * 8];
    float4 v1 = *(const float4*)&yr[lane * 8 + 4];
    float s = v0.x + v0.y + v0.z + v0.w + v1.x + v1.y + v1.z + v1.w;
    float s2 = v0.x * v0.x + v0.y * v0.y + v0.z * v0.z + v0.w * v0.w +
               v1.x * v1.x + v1.y * v1.y + v1.z * v1.z + v1.w * v1.w;
#pragma unroll
    for (int off = 32; off; off >>= 1) {
        s += __shfl_xor(s, off);
        s2 += __shfl_xor(s2, off);
    }
    float m = s * (1.0f / DEC);
    float var = s2 * (1.0f / DEC) - m * m;
    float rstd = rsqrtf(var + 1e-5f);
    float vals[8] = { v0.x,v0.y,v0.z,v0.w,v1.x,v1.y,v1.z,v1.w };
    float o[8];
#pragma unroll
    for (int j = 0; j < 8; ++j) {
        int colj = lane * 8 + j;
        o[j] = tanhf((vals[j] - m) * rstd * g[colj] + b[colj]);
    }
    *(float4*)&yr[lane * 8] = make_float4(o[0], o[1], o[2], o[3]);
    *(float4*)&yr[lane * 8 + 4] = make_float4(o[4], o[5], o[6], o[7]);
}

// ---------------- host ----------------
static void g_mfma(hipStream_t s, int M, int N,
    const float* bias, float* Cf, ushort* Cb, int ldc,
    const ushort* A0, int la0, const ushort* B0, int lb0, int K0,
    const ushort* A1 = nullptr, int la1 = 0, const ushort* B1 = nullptr, int lb1 = 0, int K1 = 0,
    const ushort* A2 = nullptr, int la2 = 0, const ushort* B2 = nullptr, int lb2 = 0, int K2 = 0,
    const ushort* A3 = nullptr, int la3 = 0, const ushort* B3 = nullptr, int lb3 = 0, int K3 = 0)
{
    Pairs p;
    p.A[0] = A0; p.B[0] = B0; p.lda[0] = la0; p.ldb[0] = lb0; p.K[0] = K0;
    p.A[1] = A1; p.B[1] = B1; p.lda[1] = la1; p.ldb[1] = lb1; p.K[1] = K1;
    p.A[2] = A2; p.B[2] = B2; p.lda[2] = la2; p.ldb[2] = lb2; p.K[2] = K2;
    p.A[3] = A3; p.B[3] = B3; p.lda[3] = la3; p.ldb[3] = lb3; p.K[3] = K3;
    dim3 grid(N / 128, (M + 127) / 128);
    gemm_mfma<<<grid, 256, 0, s>>>(p, bias, Cf, Cb, ldc, M, N);
}

extern "C" void kernel_launch(void* const* d_in, const int* in_sizes, int n_in,
                              void* d_out, int out_size, void* d_ws, size_t ws_size,
                              hipStream_t stream)
{
    (void)in_sizes; (void)n_in; (void)out_size;
    const float* embed   = (const float*)d_in[0];
    const float* W_iou_w = (const float*)d_in[1];
    const float* W_iou_b = (const float*)d_in[2];
    const float* U_iou_w = (const float*)d_in[3];
    const float* W_f_w   = (const float*)d_in[4];
    const float* W_f_b   = (const float*)d_in[5];
    const float* U_f_w   = (const float*)d_in[6];
    const float* uh_wih  = (const float*)d_in[7];
    const float* uh_whh  = (const float*)d_in[8];
    const float* uh_bih  = (const float*)d_in[9];
    const float* uh_bhh  = (const float*)d_in[10];
    const float* fc_wih  = (const float*)d_in[11];
    const float* fc_whh  = (const float*)d_in[12];
    const float* fc_bih  = (const float*)d_in[13];
    const float* fc_bhh  = (const float*)d_in[14];
    const float* out_w   = (const float*)d_in[15];
    const float* out_b   = (const float*)d_in[16];
    const float* ln_g    = (const float*)d_in[17];
    const float* ln_b    = (const float*)d_in[18];

    // d_out: f32 master h + c, fills out_size exactly
    float* out    = (float*)d_out;
    float* hbuf_f = out;                          // [NNODES, H] f32
    float* cbuf   = out + (size_t)NNODES * H;     // [NNODES, H] f32

    float* ws = (float*)d_ws;
    size_t o = 0;
    ushort* embed_bf = (ushort*)(ws + o); o += (size_t)NNODES * E / 2;
    ushort* hbuf_bf  = (ushort*)(ws + o); o += (size_t)NNODES * H / 2;
    ushort* wiou_hi  = (ushort*)(ws + o); o += (size_t)H3 * E / 2;
    ushort* wiou_lo  = (ushort*)(ws + o); o += (size_t)H3 * E / 2;
    ushort* wf_hi    = (ushort*)(ws + o); o += (size_t)H * E / 2;
    ushort* wf_lo    = (ushort*)(ws + o); o += (size_t)H * E / 2;
    ushort* uf_hi    = (ushort*)(ws + o); o += (size_t)H * H / 2;
    ushort* uf_lo    = (ushort*)(ws + o); o += (size_t)H * H / 2;
    ushort* wih_hi   = (ushort*)(ws + o); o += (size_t)GUH * H3 / 2;
    ushort* wih_lo   = (ushort*)(ws + o); o += (size_t)GUH * H3 / 2;
    ushort* whh_hi   = (ushort*)(ws + o); o += (size_t)GUH * H3 / 2;
    ushort* whh_lo   = (ushort*)(ws + o); o += (size_t)GUH * H3 / 2;
    ushort* fih_hi   = (ushort*)(ws + o); o += (size_t)GFC * H / 2;
    ushort* fih_lo   = (ushort*)(ws + o); o += (size_t)GFC * H / 2;
    ushort* fhh_hi   = (ushort*)(ws + o); o += (size_t)GFC * H / 2;
    ushort* fhh_lo   = (ushort*)(ws + o); o += (size_t)GFC * H / 2;
    ushort* ow_hi    = (ushort*)(ws + o); o += (size_t)DEC * H / 2;
    ushort* ow_lo    = (ushort*)(ws + o); o += (size_t)DEC * H / 2;
    ushort* fold_hi  = (ushort*)(ws + o); o += (size_t)GUH * E / 2;
    ushort* fold_lo  = (ushort*)(ws + o); o += (size_t)GUH * E / 2;
    float*  fold_f   = ws + o; o += (size_t)GUH * E;
    float*  Ut       = ws + o; o += (size_t)E * H3;
    float*  bsu      = ws + o; o += GUH;
    float*  bsf      = ws + o; o += GFC;

    // per-chunk floats/row: 768+384+256+128+3072+1024+256+128+256+768+384+768+1024+512+128 = 9856
    size_t avail = ws_size / 4;
    long long room = (long long)avail - (long long)o - 8192;
    long long Cl = room / 9856;
    int C;
    if (Cl >= 16384) C = 16384;
    else if (Cl <= 256) C = 256;
    else C = (int)((Cl / 256) * 256);

    float*  xiou_f  = ws + o; o += (size_t)C * H3;
    ushort* xiou_bf = (ushort*)(ws + o); o += (size_t)C * H3 / 2;
    float*  xf_f    = ws + o; o += (size_t)C * H;
    ushort* xf_bf   = (ushort*)(ws + o); o += (size_t)C * H / 2;
    float*  gbuf    = ws + o; o += (size_t)C * GUH;   // also leaf iou [4C,768]
    float*  gfc     = ws + o; o += (size_t)C * GFC;
    float*  hfc_f   = ws + o; o += (size_t)C * H;
    ushort* hfc_bf  = (ushort*)(ws + o); o += (size_t)C * H / 2;
    float*  cfc     = ws + o; o += (size_t)C * H;
    float*  h_uh_f  = ws + o; o += (size_t)C * H3;
    ushort* h_uh_bf = (ushort*)(ws + o); o += (size_t)C * H3 / 2;
    float*  c_uh    = ws + o; o += (size_t)C * H3;
    float*  fcm_pre = ws + o; o += (size_t)C * GFC;
    ushort* fcm_bf  = (ushort*)(ws + o); o += (size_t)C * GFC / 2;
    ushort* h_lo    = (ushort*)(ws + o); o += (size_t)C * H / 2;

    // ---- prep: conversions, splits, folded weight ----
    auto CVT = [&](const float* s, ushort* dv, int n) {
        cvt_bf16<<<(n / 4 + 255) / 256, 256, 0, stream>>>(s, dv, n);
    };
    auto SPLIT = [&](const float* s, ushort* hi, ushort* lo, int n) {
        cvt_split<<<(n / 4 + 255) / 256, 256, 0, stream>>>(s, hi, lo, n);
    };
    CVT(embed, embed_bf, NNODES * E);
    SPLIT(W_iou_w, wiou_hi, wiou_lo, H3 * E);
    SPLIT(W_f_w, wf_hi, wf_lo, H * E);
    SPLIT(U_f_w, uf_hi, uf_lo, H * H);
    SPLIT(uh_wih, wih_hi, wih_lo, GUH * H3);
    SPLIT(uh_whh, whh_hi, whh_lo, GUH * H3);
    SPLIT(fc_wih, fih_hi, fih_lo, GFC * H);
    SPLIT(fc_whh, fhh_hi, fhh_lo, GFC * H);
    SPLIT(out_w, ow_hi, ow_lo, DEC * H);
    bias_sum<<<(GUH + 255) / 256, 256, 0, stream>>>(uh_bih, uh_bhh, bsu, GUH);
    bias_sum<<<(GFC + 255) / 256, 256, 0, stream>>>(fc_bih, fc_bhh, bsf, GFC);
    transpose_f32<<<(H3 * E + 255) / 256, 256, 0, stream>>>(U_iou_w, Ut);
    {   // folded = uh_wih @ U_iou_w in f32, then split
        dim3 grid(E / 128, GUH / 128);
        gemm_nt_f32<<<grid, 256, 0, stream>>>(uh_wih, H3, Ut, H3, fold_f, E, GUH, E, H3);
        SPLIT(fold_f, fold_hi, fold_lo, GUH * E);
    }

    // ---- leaves (chunks of 4C rows through gbuf) ----
    for (int ls = 0; ls < NLEAF; ls += 4 * C) {
        int Ln = NLEAF - ls < 4 * C ? NLEAF - ls : 4 * C;
        g_mfma(stream, Ln, H3, W_iou_b, gbuf, nullptr, H3,
               embed_bf + (size_t)(LEAF0 + ls) * E, E, wiou_hi, E, E,
               embed_bf + (size_t)(LEAF0 + ls) * E, E, wiou_lo, E, E);
        leaf_apply<<<(Ln * 64 + 255) / 256, 256, 0, stream>>>(
            gbuf, hbuf_f, hbuf_bf, cbuf, LEAF0 + ls, Ln);
    }

    // ---- levels, deepest internal -> root ----
    const int counts[8] = { 1, 4, 16, 64, 256, 1024, 4096, 16384 };
    const int offs[8]   = { 0, 1, 5, 21, 85, 341, 1365, 5461 };
    for (int d = 7; d >= 0; --d) {
        int n = counts[d], start = offs[d];
        for (int s = 0; s < n; s += C) {
            int Cn = n - s < C ? n - s : C;
            int sa = start + s;
            int cst = 4 * sa + 1;

            // x projections (f32 master + bf16 shadow)
            g_mfma(stream, Cn, H3, W_iou_b, xiou_f, xiou_bf, H3,
                   embed_bf + (size_t)sa * E, E, wiou_hi, E, E,
                   embed_bf + (size_t)sa * E, E, wiou_lo, E, E);
            g_mfma(stream, Cn, H, W_f_b, xf_f, xf_bf, H,
                   embed_bf + (size_t)sa * E, E, wf_hi, E, E,
                   embed_bf + (size_t)sa * E, E, wf_lo, E, E);

            // fc messages
            g_mfma(stream, 4 * Cn, H, nullptr, fcm_pre, nullptr, H,
                   hbuf_bf + (size_t)cst * H, H, uf_hi, H, H,
                   hbuf_bf + (size_t)cst * H, H, uf_lo, H, H);
            fc_msg<<<(4 * Cn * 64 + 255) / 256, 256, 0, stream>>>(
                fcm_pre, xf_f, cbuf, fcm_bf, cst, Cn);

            // step 0 (h=c=0): g = token ih + biases
            g_mfma(stream, Cn, GUH, bsu, gbuf, nullptr, GUH,
                   xiou_bf, H3, wih_hi, H3, H3,
                   xiou_bf, H3, wih_lo, H3, H3);
            lstm_step<H3><<<(Cn * 192 + 255) / 256, 256, 0, stream>>>(gbuf, h_uh_f, h_uh_bf, c_uh, Cn, 1);
            g_mfma(stream, Cn, GFC, bsf, gfc, nullptr, GFC,
                   xf_bf, H, fih_hi, H, H,
                   xf_bf, H, fih_lo, H, H);
            lstm_step<H><<<(Cn * 64 + 255) / 256, 256, 0, stream>>>(gfc, hfc_f, hfc_bf, cfc, Cn, 1);

            // steps 1..4: msg ih (folded hi/lo) + recurrent hh (hi/lo)
            for (int t = 1; t <= 4; ++t) {
                g_mfma(stream, Cn, GUH, bsu, gbuf, nullptr, GUH,
                       hbuf_bf + (size_t)(cst + t - 1) * H, 4 * H, fold_hi, E, E,
                       hbuf_bf + (size_t)(cst + t - 1) * H, 4 * H, fold_lo, E, E,
                       h_uh_bf, H3, whh_hi, H3, H3,
                       h_uh_bf, H3, whh_lo, H3, H3);
                lstm_step<H3><<<(Cn * 192 + 255) / 256, 256, 0, stream>>>(gbuf, h_uh_f, h_uh_bf, c_uh, Cn, 0);
                g_mfma(stream, Cn, GFC, bsf, gfc, nullptr, GFC,
                       fcm_bf + (size_t)(t - 1) * H, 4 * H, fih_hi, H, H,
                       fcm_bf + (size_t)(t - 1) * H, 4 * H, fih_lo, H, H,
                       hfc_bf, H, fhh_hi, H, H,
                       hfc_bf, H, fhh_lo, H, H);
                lstm_step<H><<<(Cn * 64 + 255) / 256, 256, 0, stream>>>(gfc, hfc_f, hfc_bf, cfc, Cn, 0);
            }

            // step 5: token ih + hh
            g_mfma(stream, Cn, GUH, bsu, gbuf, nullptr, GUH,
                   xiou_bf, H3, wih_hi, H3, H3,
                   xiou_bf, H3, wih_lo, H3, H3,
                   h_uh_bf, H3, whh_hi, H3, H3,
                   h_uh_bf, H3, whh_lo, H3, H3);
            lstm_step<H3><<<(Cn * 192 + 255) / 256, 256, 0, stream>>>(gbuf, h_uh_f, h_uh_bf, c_uh, Cn, 0);
            g_mfma(stream, Cn, GFC, bsf, gfc, nullptr, GFC,
                   xf_bf, H, fih_hi, H, H,
                   xf_bf, H, fih_lo, H, H,
                   hfc_bf, H, fhh_hi, H, H,
                   hfc_bf, H, fhh_lo, H, H);
            lstm_step<H><<<(Cn * 64 + 255) / 256, 256, 0, stream>>>(gfc, hfc_f, hfc_bf, cfc, Cn, 0);

            node_apply<<<(Cn * 64 + 255) / 256, 256, 0, stream>>>(
                xiou_f, h_uh_f, hfc_f, hbuf_f, hbuf_bf, cbuf, sa, Cn);
        }
    }

    // ---- output projection (near-f32 via hi/lo), descending chunks ----
    // GEMM reads only ws (hbuf_bf, h_lo); writes to out may clobber hbuf_f rows
    // [2s, 2s+2Cn) which are only ever read (by make_hlo) at rows < s afterwards.
    long long top = ((long long)(NNODES - 1) / C) * C;
    for (long long s = top; s >= 0; s -= C) {
        int Cn = (int)((long long)NNODES - s < C ? (long long)NNODES - s : C);
        make_hlo<<<(Cn * 64 + 255) / 256, 256, 0, stream>>>(
            hbuf_f + (size_t)s * H, hbuf_bf + (size_t)s * H, h_lo, Cn * H);
        g_mfma(stream, Cn, DEC, out_b, out + (size_t)s * DEC, nullptr, DEC,
               hbuf_bf + (size_t)s * H, H, ow_hi, H, H,
               h_lo, H, ow_hi, H, H,
               hbuf_bf + (size_t)s * H, H, ow_lo, H, H);
    }

    ln_tanh<<<(NNODES + 3) / 4, 256, 0, stream>>>(out, ln_g, ln_b, NNODES);
}

// Round 5
// 6187.421 us; speedup vs baseline: 4.2423x; 1.5108x over previous
//
#include <hip/hip_runtime.h>
#include <math.h>
#include <cstddef>
#include <cstdint>

// ---------------- constants ----------------
constexpr int E = 256, H = 256, H3 = 768;
constexpr int GUH = 3072, GFC = 1024, DEC = 512;
constexpr int NNODES = 87381, LEAF0 = 21845, NLEAF = 65536;

using f16 = _Float16;
typedef __attribute__((ext_vector_type(8))) _Float16 f16x8;
typedef __attribute__((ext_vector_type(4))) _Float16 f16x4;
typedef __attribute__((ext_vector_type(4))) float f32x4;
typedef unsigned int u32;
typedef __attribute__((address_space(1))) const u32 gu32;
typedef __attribute__((address_space(3))) u32 lu32;

static __device__ __forceinline__ float sigf(float x) { return 1.0f / (1.0f + expf(-x)); }

static __device__ __forceinline__ void gload16(const void* g, void* l) {
    __builtin_amdgcn_global_load_lds((gu32*)g, (lu32*)l, 16, 0, 0);
}

// ---------------- multi-pair MFMA NT GEMM (fp16) ----------------
// C[m,n] = sum_p sum_k Ap[m,k]*Bp[n,k] + bias[n]?   (up to 4 pairs, K mult of 32)
// 128x128 tile, BK=32, 256 thr = 4 waves, 4x4 16x16x32 frags.
// N multiple of 128. M-edge rows are read OOB (must stay inside the ws/out
// allocations) but never stored.
struct Pairs {
    const f16* A[4];
    const f16* B[4];
    int lda[4], ldb[4], K[4];
};

__global__ __launch_bounds__(256) void gemm_mfma(
    Pairs pr, const float* __restrict__ bias,
    float* __restrict__ Cf, f16* __restrict__ Ch,
    int ldc, int M, int N)
{
    __shared__ f16 As[2][128 * 32];
    __shared__ f16 Bs[2][128 * 32];
    const int tid = threadIdx.x;
    const int m0 = blockIdx.y * 128, n0 = blockIdx.x * 128;
    const int wave = tid >> 6, lane = tid & 63;
    const int wm = (wave >> 1) * 64, wn = (wave & 1) * 64;
    const int lr = lane & 15, kg = lane >> 4;

    f32x4 acc[4][4];
#pragma unroll
    for (int i = 0; i < 4; ++i)
#pragma unroll
        for (int j = 0; j < 4; ++j) acc[i][j] = (f32x4){0.f, 0.f, 0.f, 0.f};

    const int nt = (pr.K[0] + pr.K[1] + pr.K[2] + pr.K[3]) >> 5;

    auto stage = [&](int t, int b) {
        int p = 0, rem = t;
        while (rem >= (pr.K[p] >> 5)) { rem -= pr.K[p] >> 5; ++p; }
        const f16* Ap = pr.A[p];
        const f16* Bp = pr.B[p];
        const int la = pr.lda[p], lb = pr.ldb[p], k0 = rem * 32;
#pragma unroll
        for (int v = 0; v < 2; ++v) {
            int idx = v * 256 + tid;
            int row = idx >> 2, c = idx & 3;
            gload16(Ap + (size_t)(m0 + row) * la + k0 + c * 8, &As[b][idx * 8]);
            gload16(Bp + (size_t)(n0 + row) * lb + k0 + c * 8, &Bs[b][idx * 8]);
        }
    };

    stage(0, 0);
    for (int t = 0; t < nt; ++t) {
        __syncthreads();                    // compiler drains vmcnt before barrier
        if (t + 1 < nt) stage(t + 1, (t + 1) & 1);
        const f16* as = As[t & 1];
        const f16* bs = Bs[t & 1];
        f16x8 af[4], bfr[4];
#pragma unroll
        for (int i = 0; i < 4; ++i) {
            af[i]  = *(const f16x8*)&as[(wm + i * 16 + lr) * 32 + kg * 8];
            bfr[i] = *(const f16x8*)&bs[(wn + i * 16 + lr) * 32 + kg * 8];
        }
#pragma unroll
        for (int i = 0; i < 4; ++i)
#pragma unroll
            for (int j = 0; j < 4; ++j)
                acc[i][j] = __builtin_amdgcn_mfma_f32_16x16x32_f16(af[i], bfr[j], acc[i][j], 0, 0, 0);
    }

    // D: col = lane&15, row = (lane>>4)*4 + r
#pragma unroll
    for (int i = 0; i < 4; ++i) {
#pragma unroll
        for (int j = 0; j < 4; ++j) {
            int col = n0 + wn + j * 16 + lr;
            float bv = bias ? bias[col] : 0.f;
#pragma unroll
            for (int r = 0; r < 4; ++r) {
                int rowg = m0 + wm + i * 16 + kg * 4 + r;
                if (rowg < M) {
                    float v = acc[i][j][r] + bv;
                    if (Cf) Cf[(size_t)rowg * ldc + col] = v;
                    if (Ch) Ch[(size_t)rowg * ldc + col] = (f16)v;
                }
            }
        }
    }
}

// ---------------- f32 tiled NT GEMM (prep only: folded weight) ----------------
__global__ __launch_bounds__(256) void gemm_nt_f32(
    const float* __restrict__ A, int lda,
    const float* __restrict__ B, int ldb,
    float* __restrict__ C, int ldc, int M, int N, int K)
{
    __shared__ float As[16][128];
    __shared__ float Bs[16][128];
    const int m0 = blockIdx.y * 128, n0 = blockIdx.x * 128;
    const int tid = threadIdx.x;
    const int tx = tid & 15, ty = tid >> 4;
    float acc[8][8];
#pragma unroll
    for (int i = 0; i < 8; ++i)
#pragma unroll
        for (int j = 0; j < 8; ++j) acc[i][j] = 0.0f;
    for (int k0 = 0; k0 < K; k0 += 16) {
#pragma unroll
        for (int v = 0; v < 2; ++v) {
            int idx = tid + v * 256;
            int row = idx >> 2, c4 = idx & 3;
            float4 a = make_float4(0, 0, 0, 0);
            int gm = m0 + row;
            if (gm < M) a = *(const float4*)&A[(size_t)gm * lda + k0 + c4 * 4];
            As[c4 * 4 + 0][row] = a.x; As[c4 * 4 + 1][row] = a.y;
            As[c4 * 4 + 2][row] = a.z; As[c4 * 4 + 3][row] = a.w;
            float4 b = make_float4(0, 0, 0, 0);
            int gn = n0 + row;
            if (gn < N) b = *(const float4*)&B[(size_t)gn * ldb + k0 + c4 * 4];
            Bs[c4 * 4 + 0][row] = b.x; Bs[c4 * 4 + 1][row] = b.y;
            Bs[c4 * 4 + 2][row] = b.z; Bs[c4 * 4 + 3][row] = b.w;
        }
        __syncthreads();
#pragma unroll
        for (int kk = 0; kk < 16; ++kk) {
            float4 a0 = *(const float4*)&As[kk][ty * 8];
            float4 a1 = *(const float4*)&As[kk][ty * 8 + 4];
            float4 b0 = *(const float4*)&Bs[kk][tx * 8];
            float4 b1 = *(const float4*)&Bs[kk][tx * 8 + 4];
            float av[8] = { a0.x,a0.y,a0.z,a0.w,a1.x,a1.y,a1.z,a1.w };
            float bv[8] = { b0.x,b0.y,b0.z,b0.w,b1.x,b1.y,b1.z,b1.w };
#pragma unroll
            for (int i = 0; i < 8; ++i)
#pragma unroll
                for (int j = 0; j < 8; ++j)
                    acc[i][j] = fmaf(av[i], bv[j], acc[i][j]);
        }
        __syncthreads();
    }
#pragma unroll
    for (int i = 0; i < 8; ++i) {
        int gm = m0 + ty * 8 + i;
        if (gm >= M) break;
#pragma unroll
        for (int j = 0; j < 8; ++j) {
            int gn = n0 + tx * 8 + j;
            if (gn < N) C[(size_t)gm * ldc + gn] = acc[i][j];
        }
    }
}

// ---------------- elementwise kernels ----------------

// LSTM step (torch order i,f,g,o): g f32 [n,4HH] -> hf f32, hh f16, c f32
template<int HH>
__global__ __launch_bounds__(256) void lstm_step(
    const float* __restrict__ g, float* __restrict__ hf, f16* __restrict__ hh,
    float* __restrict__ c, int n, int init)
{
    int idx = blockIdx.x * 256 + threadIdx.x;
    int tot = n * (HH / 4);
    if (idx >= tot) return;
    int row = idx / (HH / 4);
    int c4 = (idx - row * (HH / 4)) * 4;
    const float* gr = g + (size_t)row * 4 * HH;
    float4 gi = *(const float4*)&gr[c4];
    float4 gf = *(const float4*)&gr[HH + c4];
    float4 gg = *(const float4*)&gr[2 * HH + c4];
    float4 go = *(const float4*)&gr[3 * HH + c4];
    size_t off = (size_t)row * HH + c4;
    float4 cp = make_float4(0.f, 0.f, 0.f, 0.f);
    if (!init) cp = *(const float4*)&c[off];
    float gia[4] = { gi.x,gi.y,gi.z,gi.w }, gfa[4] = { gf.x,gf.y,gf.z,gf.w };
    float gga[4] = { gg.x,gg.y,gg.z,gg.w }, goa[4] = { go.x,go.y,go.z,go.w };
    float cpa[4] = { cp.x,cp.y,cp.z,cp.w };
    float cc[4], hv[4]; f16x4 hq;
#pragma unroll
    for (int j = 0; j < 4; ++j) {
        float v = sigf(gia[j]) * tanhf(gga[j]);
        if (!init) v = fmaf(sigf(gfa[j]), cpa[j], v);
        cc[j] = v;
        hv[j] = sigf(goa[j]) * tanhf(v);
        hq[j] = (f16)hv[j];
    }
    *(float4*)&c[off] = make_float4(cc[0], cc[1], cc[2], cc[3]);
    *(float4*)&hf[off] = make_float4(hv[0], hv[1], hv[2], hv[3]);
    *(f16x4*)&hh[off] = hq;
}

// fcm = c_child * sigmoid(x_f_parent + pre) -> f16
__global__ __launch_bounds__(256) void fc_msg(
    const float* __restrict__ pre, const float* __restrict__ xf_f,
    const float* __restrict__ cbuf, f16* __restrict__ fcm,
    int cst, int Cn)
{
    int idx = blockIdx.x * 256 + threadIdx.x;
    int tot = Cn * 4 * (H / 4);
    if (idx >= tot) return;
    int r = idx >> 6;
    int c4 = (idx & 63) * 4;
    int pl = r >> 2;
    int child = cst + r;
    float4 p = *(const float4*)&pre[(size_t)r * H + c4];
    float4 xv = *(const float4*)&xf_f[(size_t)pl * H + c4];
    float4 cv = *(const float4*)&cbuf[(size_t)child * H + c4];
    f16x4 o;
    o[0] = (f16)(cv.x * sigf(xv.x + p.x));
    o[1] = (f16)(cv.y * sigf(xv.y + p.y));
    o[2] = (f16)(cv.z * sigf(xv.z + p.z));
    o[3] = (f16)(cv.w * sigf(xv.w + p.w));
    *(f16x4*)&fcm[(size_t)r * H + c4] = o;
}

// leaves: iou f32 [count,768] -> hh f16, c f32 at rows abs0..
__global__ __launch_bounds__(256) void leaf_apply(
    const float* __restrict__ iou, f16* __restrict__ hh, float* __restrict__ c,
    int abs0, int count)
{
    int idx = blockIdx.x * 256 + threadIdx.x;
    int tot = count * (H / 4);
    if (idx >= tot) return;
    int row = idx >> 6;
    int c4 = (idx & 63) * 4;
    const float* r = iou + (size_t)row * H3;
    float4 vi = *(const float4*)&r[c4];
    float4 vo = *(const float4*)&r[H + c4];
    float4 vu = *(const float4*)&r[2 * H + c4];
    float ia[4] = { vi.x,vi.y,vi.z,vi.w }, oa[4] = { vo.x,vo.y,vo.z,vo.w }, ua[4] = { vu.x,vu.y,vu.z,vu.w };
    size_t off = (size_t)(abs0 + row) * H + c4;
    float cc[4]; f16x4 hq;
#pragma unroll
    for (int j = 0; j < 4; ++j) {
        cc[j] = sigf(ia[j]) * tanhf(ua[j]);
        hq[j] = (f16)(sigf(oa[j]) * tanhf(cc[j]));
    }
    *(float4*)&c[off] = make_float4(cc[0], cc[1], cc[2], cc[3]);
    *(f16x4*)&hh[off] = hq;
}

// internal apply: iou = x_iou + Uh_sum; c = sig(i)*tanh(u)+fc_sum; h = sig(o)*tanh(c)
__global__ __launch_bounds__(256) void node_apply(
    const float* __restrict__ xiou_f, const float* __restrict__ h_uh_f,
    const float* __restrict__ hfc_f, f16* __restrict__ hh, float* __restrict__ c,
    int sa, int Cn)
{
    int idx = blockIdx.x * 256 + threadIdx.x;
    int tot = Cn * (H / 4);
    if (idx >= tot) return;
    int row = idx >> 6;
    int c4 = (idx & 63) * 4;
    const float* xr = xiou_f + (size_t)row * H3;
    const float* ur = h_uh_f + (size_t)row * H3;
    float4 xi = *(const float4*)&xr[c4];
    float4 xo = *(const float4*)&xr[H + c4];
    float4 xu = *(const float4*)&xr[2 * H + c4];
    float4 ui = *(const float4*)&ur[c4];
    float4 uo = *(const float4*)&ur[H + c4];
    float4 uu = *(const float4*)&ur[2 * H + c4];
    float4 fv = *(const float4*)&hfc_f[(size_t)row * H + c4];
    float xia[4] = { xi.x,xi.y,xi.z,xi.w }, xoa[4] = { xo.x,xo.y,xo.z,xo.w }, xua[4] = { xu.x,xu.y,xu.z,xu.w };
    float uia[4] = { ui.x,ui.y,ui.z,ui.w }, uoa[4] = { uo.x,uo.y,uo.z,uo.w }, uua[4] = { uu.x,uu.y,uu.z,uu.w };
    float fva[4] = { fv.x,fv.y,fv.z,fv.w };
    size_t off = (size_t)(sa + row) * H + c4;
    float cc[4]; f16x4 hq;
#pragma unroll
    for (int j = 0; j < 4; ++j) {
        float iv = xia[j] + uia[j];
        float ov = xoa[j] + uoa[j];
        float uv = xua[j] + uua[j];
        float cv = sigf(iv) * tanhf(uv) + fva[j];
        cc[j] = cv;
        hq[j] = (f16)(sigf(ov) * tanhf(cv));
    }
    *(float4*)&c[off] = make_float4(cc[0], cc[1], cc[2], cc[3]);
    *(f16x4*)&hh[off] = hq;
}

__global__ __launch_bounds__(256) void bias_sum(
    const float* __restrict__ a, const float* __restrict__ b, float* __restrict__ o, int n)
{
    int i = blockIdx.x * 256 + threadIdx.x;
    if (i < n) o[i] = a[i] + b[i];
}

__global__ __launch_bounds__(256) void cvt_f16(
    const float* __restrict__ in, f16* __restrict__ out, int n)
{
    int idx = blockIdx.x * 256 + threadIdx.x;
    if (idx * 4 >= n) return;
    float4 v = *(const float4*)&in[idx * 4];
    f16x4 o; o[0] = (f16)v.x; o[1] = (f16)v.y; o[2] = (f16)v.z; o[3] = (f16)v.w;
    *(f16x4*)&out[idx * 4] = o;
}

// U_iou_w f32 [768,256] -> f32 [256,768] transpose
__global__ __launch_bounds__(256) void transpose_f32(
    const float* __restrict__ in, float* __restrict__ out)
{
    int idx = blockIdx.x * 256 + threadIdx.x;
    if (idx >= H3 * E) return;
    int r = idx >> 8, c = idx & 255;
    out[(size_t)c * H3 + r] = in[idx];
}

// LayerNorm(512)+tanh in-place, one wave per row
__global__ __launch_bounds__(256) void ln_tanh(
    float* __restrict__ y, const float* __restrict__ g, const float* __restrict__ b,
    int Nrows)
{
    int wave = threadIdx.x >> 6;
    int lane = threadIdx.x & 63;
    int row = blockIdx.x * 4 + wave;
    if (row >= Nrows) return;
    float* yr = y + (size_t)row * DEC;
    float4 v0 = *(const float4*)&yr[lane * 8];
    float4 v1 = *(const float4*)&yr[lane * 8 + 4];
    float s = v0.x + v0.y + v0.z + v0.w + v1.x + v1.y + v1.z + v1.w;
    float s2 = v0.x * v0.x + v0.y * v0.y + v0.z * v0.z + v0.w * v0.w +
               v1.x * v1.x + v1.y * v1.y + v1.z * v1.z + v1.w * v1.w;
#pragma unroll
    for (int off = 32; off; off >>= 1) {
        s += __shfl_xor(s, off);
        s2 += __shfl_xor(s2, off);
    }
    float m = s * (1.0f / DEC);
    float var = s2 * (1.0f / DEC) - m * m;
    float rstd = rsqrtf(var + 1e-5f);
    float vals[8] = { v0.x,v0.y,v0.z,v0.w,v1.x,v1.y,v1.z,v1.w };
    float o[8];
#pragma unroll
    for (int j = 0; j < 8; ++j) {
        int colj = lane * 8 + j;
        o[j] = tanhf((vals[j] - m) * rstd * g[colj] + b[colj]);
    }
    *(float4*)&yr[lane * 8] = make_float4(o[0], o[1], o[2], o[3]);
    *(float4*)&yr[lane * 8 + 4] = make_float4(o[4], o[5], o[6], o[7]);
}

// ---------------- host ----------------
static void g_mfma(hipStream_t s, int M, int N,
    const float* bias, float* Cf, f16* Ch, int ldc,
    const f16* A0, int la0, const f16* B0, int lb0, int K0,
    const f16* A1 = nullptr, int la1 = 0, const f16* B1 = nullptr, int lb1 = 0, int K1 = 0)
{
    Pairs p;
    p.A[0] = A0; p.B[0] = B0; p.lda[0] = la0; p.ldb[0] = lb0; p.K[0] = K0;
    p.A[1] = A1; p.B[1] = B1; p.lda[1] = la1; p.ldb[1] = lb1; p.K[1] = K1;
    p.A[2] = nullptr; p.B[2] = nullptr; p.lda[2] = 0; p.ldb[2] = 0; p.K[2] = 0;
    p.A[3] = nullptr; p.B[3] = nullptr; p.lda[3] = 0; p.ldb[3] = 0; p.K[3] = 0;
    dim3 grid(N / 128, (M + 127) / 128);
    gemm_mfma<<<grid, 256, 0, s>>>(p, bias, Cf, Ch, ldc, M, N);
}

extern "C" void kernel_launch(void* const* d_in, const int* in_sizes, int n_in,
                              void* d_out, int out_size, void* d_ws, size_t ws_size,
                              hipStream_t stream)
{
    (void)in_sizes; (void)n_in; (void)out_size;
    const float* embed   = (const float*)d_in[0];
    const float* W_iou_w = (const float*)d_in[1];
    const float* W_iou_b = (const float*)d_in[2];
    const float* U_iou_w = (const float*)d_in[3];
    const float* W_f_w   = (const float*)d_in[4];
    const float* W_f_b   = (const float*)d_in[5];
    const float* U_f_w   = (const float*)d_in[6];
    const float* uh_wih  = (const float*)d_in[7];
    const float* uh_whh  = (const float*)d_in[8];
    const float* uh_bih  = (const float*)d_in[9];
    const float* uh_bhh  = (const float*)d_in[10];
    const float* fc_wih  = (const float*)d_in[11];
    const float* fc_whh  = (const float*)d_in[12];
    const float* fc_bih  = (const float*)d_in[13];
    const float* fc_bhh  = (const float*)d_in[14];
    const float* out_w   = (const float*)d_in[15];
    const float* out_b   = (const float*)d_in[16];
    const float* ln_g    = (const float*)d_in[17];
    const float* ln_b    = (const float*)d_in[18];

    // d_out: cbuf f32 [NNODES,H] in the low half; final y overwrites everything
    // after all levels are done (cbuf is dead by then).
    float* out  = (float*)d_out;
    float* cbuf = out;                            // [NNODES, H] f32

    float* ws = (float*)d_ws;
    size_t o = 0;
    f16* embed_h = (f16*)(ws + o); o += (size_t)NNODES * E / 2;
    f16* hbuf_h  = (f16*)(ws + o); o += (size_t)NNODES * H / 2;
    f16* wiou_h  = (f16*)(ws + o); o += (size_t)H3 * E / 2;
    f16* wf_h    = (f16*)(ws + o); o += (size_t)H * E / 2;
    f16* uf_h    = (f16*)(ws + o); o += (size_t)H * H / 2;
    f16* wih_h   = (f16*)(ws + o); o += (size_t)GUH * H3 / 2;
    f16* whh_h   = (f16*)(ws + o); o += (size_t)GUH * H3 / 2;
    f16* fih_h   = (f16*)(ws + o); o += (size_t)GFC * H / 2;
    f16* fhh_h   = (f16*)(ws + o); o += (size_t)GFC * H / 2;
    f16* ow_h    = (f16*)(ws + o); o += (size_t)DEC * H / 2;
    f16* fold_h  = (f16*)(ws + o); o += (size_t)GUH * E / 2;
    float* fold_f = ws + o; o += (size_t)GUH * E;
    float* Ut     = ws + o; o += (size_t)E * H3;
    float* bsu    = ws + o; o += GUH;
    float* bsf    = ws + o; o += GFC;

    // per-chunk f32 words/row:
    // xiou_f 768 + xiou_h 384 + xf_f 256 + xf_h 128 + gbuf 3072 + gfc 1024
    // + hfc_f 256 + hfc_h 128 + cfc 256 + h_uh_f 768 + h_uh_h 384 + c_uh 768
    // + fcm_pre 1024 + fcm_h 512 = 9728
    size_t avail = ws_size / 4;
    long long room = (long long)avail - (long long)o - 8192;
    long long Cl = room / 9728;
    int C;
    if (Cl >= 16384) C = 16384;
    else if (Cl <= 256) C = 256;
    else C = (int)((Cl / 256) * 256);

    float* xiou_f = ws + o; o += (size_t)C * H3;
    f16*   xiou_h = (f16*)(ws + o); o += (size_t)C * H3 / 2;
    float* xf_f   = ws + o; o += (size_t)C * H;
    f16*   xf_h   = (f16*)(ws + o); o += (size_t)C * H / 2;
    float* gbuf   = ws + o; o += (size_t)C * GUH;   // also leaf iou [4C,768]
    float* gfc    = ws + o; o += (size_t)C * GFC;
    float* hfc_f  = ws + o; o += (size_t)C * H;
    f16*   hfc_h  = (f16*)(ws + o); o += (size_t)C * H / 2;
    float* cfc    = ws + o; o += (size_t)C * H;
    float* h_uh_f = ws + o; o += (size_t)C * H3;
    f16*   h_uh_h = (f16*)(ws + o); o += (size_t)C * H3 / 2;
    float* c_uh   = ws + o; o += (size_t)C * H3;
    float* fcm_pre = ws + o; o += (size_t)C * GFC;
    f16*   fcm_h  = (f16*)(ws + o); o += (size_t)C * GFC / 2;

    // ---- prep: conversions + folded weight ----
    auto CVT = [&](const float* s, f16* dv, int n) {
        cvt_f16<<<(n / 4 + 255) / 256, 256, 0, stream>>>(s, dv, n);
    };
    CVT(embed, embed_h, NNODES * E);
    CVT(W_iou_w, wiou_h, H3 * E);
    CVT(W_f_w, wf_h, H * E);
    CVT(U_f_w, uf_h, H * H);
    CVT(uh_wih, wih_h, GUH * H3);
    CVT(uh_whh, whh_h, GUH * H3);
    CVT(fc_wih, fih_h, GFC * H);
    CVT(fc_whh, fhh_h, GFC * H);
    CVT(out_w, ow_h, DEC * H);
    bias_sum<<<(GUH + 255) / 256, 256, 0, stream>>>(uh_bih, uh_bhh, bsu, GUH);
    bias_sum<<<(GFC + 255) / 256, 256, 0, stream>>>(fc_bih, fc_bhh, bsf, GFC);
    transpose_f32<<<(H3 * E + 255) / 256, 256, 0, stream>>>(U_iou_w, Ut);
    {   // folded = uh_wih @ U_iou_w in f32, then cast
        dim3 grid(E / 128, GUH / 128);
        gemm_nt_f32<<<grid, 256, 0, stream>>>(uh_wih, H3, Ut, H3, fold_f, E, GUH, E, H3);
        CVT(fold_f, fold_h, GUH * E);
    }

    // ---- leaves (chunks of 4C rows through gbuf) ----
    for (int ls = 0; ls < NLEAF; ls += 4 * C) {
        int Ln = NLEAF - ls < 4 * C ? NLEAF - ls : 4 * C;
        g_mfma(stream, Ln, H3, W_iou_b, gbuf, nullptr, H3,
               embed_h + (size_t)(LEAF0 + ls) * E, E, wiou_h, E, E);
        leaf_apply<<<(Ln * 64 + 255) / 256, 256, 0, stream>>>(
            gbuf, hbuf_h + (size_t)(LEAF0 + ls) * H, cbuf + (size_t)(LEAF0 + ls) * H, 0, Ln);
    }

    // ---- levels, deepest internal -> root ----
    const int counts[8] = { 1, 4, 16, 64, 256, 1024, 4096, 16384 };
    const int offs[8]   = { 0, 1, 5, 21, 85, 341, 1365, 5461 };
    for (int d = 7; d >= 0; --d) {
        int n = counts[d], start = offs[d];
        for (int s = 0; s < n; s += C) {
            int Cn = n - s < C ? n - s : C;
            int sa = start + s;
            int cst = 4 * sa + 1;

            // x projections (f32 master + f16 shadow)
            g_mfma(stream, Cn, H3, W_iou_b, xiou_f, xiou_h, H3,
                   embed_h + (size_t)sa * E, E, wiou_h, E, E);
            g_mfma(stream, Cn, H, W_f_b, xf_f, xf_h, H,
                   embed_h + (size_t)sa * E, E, wf_h, E, E);

            // fc messages: pre = h_ch @ U_f.T; fcm = c_ch * sigmoid(x_f + pre)
            g_mfma(stream, 4 * Cn, H, nullptr, fcm_pre, nullptr, H,
                   hbuf_h + (size_t)cst * H, H, uf_h, H, H);
            fc_msg<<<(4 * Cn * 64 + 255) / 256, 256, 0, stream>>>(
                fcm_pre, xf_f, cbuf, fcm_h, cst, Cn);

            // step 0 (h=c=0): g = token ih + biases
            g_mfma(stream, Cn, GUH, bsu, gbuf, nullptr, GUH,
                   xiou_h, H3, wih_h, H3, H3);
            lstm_step<H3><<<(Cn * 192 + 255) / 256, 256, 0, stream>>>(gbuf, h_uh_f, h_uh_h, c_uh, Cn, 1);
            g_mfma(stream, Cn, GFC, bsf, gfc, nullptr, GFC,
                   xf_h, H, fih_h, H, H);
            lstm_step<H><<<(Cn * 64 + 255) / 256, 256, 0, stream>>>(gfc, hfc_f, hfc_h, cfc, Cn, 1);

            // steps 1..4: (msg @ folded) + (h @ whh)
            for (int t = 1; t <= 4; ++t) {
                g_mfma(stream, Cn, GUH, bsu, gbuf, nullptr, GUH,
                       hbuf_h + (size_t)(cst + t - 1) * H, 4 * H, fold_h, E, E,
                       h_uh_h, H3, whh_h, H3, H3);
                lstm_step<H3><<<(Cn * 192 + 255) / 256, 256, 0, stream>>>(gbuf, h_uh_f, h_uh_h, c_uh, Cn, 0);
                g_mfma(stream, Cn, GFC, bsf, gfc, nullptr, GFC,
                       fcm_h + (size_t)(t - 1) * H, 4 * H, fih_h, H, H,
                       hfc_h, H, fhh_h, H, H);
                lstm_step<H><<<(Cn * 64 + 255) / 256, 256, 0, stream>>>(gfc, hfc_f, hfc_h, cfc, Cn, 0);
            }

            // step 5: token ih + hh
            g_mfma(stream, Cn, GUH, bsu, gbuf, nullptr, GUH,
                   xiou_h, H3, wih_h, H3, H3,
                   h_uh_h, H3, whh_h, H3, H3);
            lstm_step<H3><<<(Cn * 192 + 255) / 256, 256, 0, stream>>>(gbuf, h_uh_f, h_uh_h, c_uh, Cn, 0);
            g_mfma(stream, Cn, GFC, bsf, gfc, nullptr, GFC,
                   xf_h, H, fih_h, H, H,
                   hfc_h, H, fhh_h, H, H);
            lstm_step<H><<<(Cn * 64 + 255) / 256, 256, 0, stream>>>(gfc, hfc_f, hfc_h, cfc, Cn, 0);

            node_apply<<<(Cn * 64 + 255) / 256, 256, 0, stream>>>(
                xiou_f, h_uh_f, hfc_f, hbuf_h + (size_t)sa * H, cbuf + (size_t)sa * H, 0, Cn);
        }
    }

    // ---- output projection: one GEMM (reads only ws; cbuf in d_out is dead) ----
    g_mfma(stream, NNODES, DEC, out_b, out, nullptr, DEC,
           hbuf_h, H, ow_h, H, H);

    ln_tanh<<<(NNODES + 3) / 4, 256, 0, stream>>>(out, ln_g, ln_b, NNODES);
}

// Round 10
// 5414.384 us; speedup vs baseline: 4.8480x; 1.1428x over previous
//
#include <hip/hip_runtime.h>
#include <math.h>
#include <cstddef>

// ---------------- constants ----------------
constexpr int E = 256, H = 256, H3 = 768;
constexpr int GUH = 3072, GFC = 1024, DEC = 512;
constexpr int NNODES = 87381, LEAF0 = 21845, NLEAF = 65536;

using f16 = _Float16;
typedef __attribute__((ext_vector_type(8))) _Float16 f16x8;
typedef __attribute__((ext_vector_type(4))) _Float16 f16x4;
typedef __attribute__((ext_vector_type(4))) float f32x4;
typedef unsigned int u32;
typedef __attribute__((address_space(1))) const u32 gu32;
typedef __attribute__((address_space(3))) u32 lu32;

static __device__ __forceinline__ float sigf(float x) { return 1.0f / (1.0f + expf(-x)); }
static __device__ __forceinline__ void gload16(const void* g, void* l) {
    __builtin_amdgcn_global_load_lds((gu32*)g, (lu32*)l, 16, 0, 0);
}

// ---------------- fused MFMA NT GEMM (single GArg per launch) ----------------
// out[m,n] = sum_k A0[m,k]B0[n,k] + sum_k A1[m,k]B1[n,k]  (K0/K1 mult of 32)
// EPI 0: +bias -> Cf f32 / Ch f16 (either or both)
// EPI 1: LSTM cell (fc only this round). B rows gate-interleaved:
//        row m <-> gate=(m>>4)&3, unit=(m>>7)*32+((m>>6)&1)*16+(m&15).
//        Fragment j == gate. Writes c (f32), h (f16), optional h f32 master.
// EPI 2: fc-message: fcm[r,col] = cch[r,col] * sigmoid(xff[r>>2,col] + acc)
// A rows are clamped to M-1 during staging (edge tiles read defined data).
struct GArg {
    const f16 *A0 = nullptr, *B0 = nullptr, *A1 = nullptr, *B1 = nullptr;
    int la0 = 0, lb0 = 0, K0 = 0, la1 = 0, lb1 = 0, K1 = 0;
    const float* bias = nullptr;
    float* Cf = nullptr; f16* Ch = nullptr; int ldc = 0;              // EPI 0
    float* cb = nullptr; f16* hb = nullptr; float* hf = nullptr;     // EPI 1
    int HH = 0; int init = 0;                                        // EPI 1
    const float* xff = nullptr; const float* cch = nullptr; f16* fcm = nullptr; // EPI 2
    int M = 0, N = 0;
};

template<int EPI>
__global__ __launch_bounds__(256) void gemm_one(GArg a)
{
    __shared__ f16 As[2][128 * 32];
    __shared__ f16 Bs[2][128 * 32];
    const int tid = threadIdx.x;
    const int m0 = blockIdx.y * 128, n0 = blockIdx.x * 128;
    const int wave = tid >> 6, lane = tid & 63;
    const int wm = (wave >> 1) * 64, wn = (wave & 1) * 64;
    const int lr = lane & 15, kg = lane >> 4;

    f32x4 acc[4][4];
#pragma unroll
    for (int i = 0; i < 4; ++i)
#pragma unroll
        for (int j = 0; j < 4; ++j) acc[i][j] = (f32x4){0.f, 0.f, 0.f, 0.f};

    const int nt1 = a.K0 >> 5;
    const int nt = nt1 + (a.K1 >> 5);

    auto stage = [&](int t, int b) {
        const f16* Ap; const f16* Bp; int la, lb, k0;
        if (t < nt1) { Ap = a.A0; Bp = a.B0; la = a.la0; lb = a.lb0; k0 = t * 32; }
        else         { Ap = a.A1; Bp = a.B1; la = a.la1; lb = a.lb1; k0 = (t - nt1) * 32; }
#pragma unroll
        for (int v = 0; v < 2; ++v) {
            int idx = v * 256 + tid;
            int row = idx >> 2, c = idx & 3;
            int ar = m0 + row;                 // clamp A rows: defined data only
            if (ar >= a.M) ar = a.M - 1;
            gload16(Ap + (size_t)ar * la + k0 + c * 8, &As[b][idx * 8]);
            gload16(Bp + (size_t)(n0 + row) * lb + k0 + c * 8, &Bs[b][idx * 8]);
        }
    };

    stage(0, 0);
    for (int t = 0; t < nt; ++t) {
        __syncthreads();                  // compiler drains vmcnt before barrier
        if (t + 1 < nt) stage(t + 1, (t + 1) & 1);
        const f16* as = As[t & 1];
        const f16* bs = Bs[t & 1];
        f16x8 af[4], bfr[4];
#pragma unroll
        for (int i = 0; i < 4; ++i) {
            af[i]  = *(const f16x8*)&as[(wm + i * 16 + lr) * 32 + kg * 8];
            bfr[i] = *(const f16x8*)&bs[(wn + i * 16 + lr) * 32 + kg * 8];
        }
#pragma unroll
        for (int i = 0; i < 4; ++i)
#pragma unroll
            for (int j = 0; j < 4; ++j)
                acc[i][j] = __builtin_amdgcn_mfma_f32_16x16x32_f16(af[i], bfr[j], acc[i][j], 0, 0, 0);
    }

    // D: col = lane&15, row = (lane>>4)*4 + r
    if constexpr (EPI == 0) {
#pragma unroll
        for (int i = 0; i < 4; ++i)
#pragma unroll
            for (int j = 0; j < 4; ++j) {
                int col = n0 + wn + j * 16 + lr;
                float bv = a.bias ? a.bias[col] : 0.f;
#pragma unroll
                for (int r = 0; r < 4; ++r) {
                    int rowg = m0 + wm + i * 16 + kg * 4 + r;
                    if (rowg < a.M) {
                        float v = acc[i][j][r] + bv;
                        if (a.Cf) a.Cf[(size_t)rowg * a.ldc + col] = v;
                        if (a.Ch) a.Ch[(size_t)rowg * a.ldc + col] = (f16)v;
                    }
                }
            }
    } else if constexpr (EPI == 1) {
        // unit index for this lane; fragment j is the gate (i,f,g,o)
        int ub = (n0 >> 2) + (wave & 1) * 16 + lr;
        float b0 = a.bias[n0 + wn + lr];
        float b1 = a.bias[n0 + wn + 16 + lr];
        float b2 = a.bias[n0 + wn + 32 + lr];
        float b3 = a.bias[n0 + wn + 48 + lr];
#pragma unroll
        for (int i = 0; i < 4; ++i)
#pragma unroll
            for (int r = 0; r < 4; ++r) {
                int rowg = m0 + wm + i * 16 + kg * 4 + r;
                if (rowg < a.M) {
                    float gi = acc[i][0][r] + b0;
                    float gf = acc[i][1][r] + b1;
                    float gg = acc[i][2][r] + b2;
                    float go = acc[i][3][r] + b3;
                    size_t off = (size_t)rowg * a.HH + ub;
                    float cn = sigf(gi) * tanhf(gg);
                    if (!a.init) cn = fmaf(sigf(gf), a.cb[off], cn);
                    a.cb[off] = cn;
                    float hv = sigf(go) * tanhf(cn);
                    a.hb[off] = (f16)hv;
                    if (a.hf) a.hf[off] = hv;     // f32 master (final step)
                }
            }
    } else {
#pragma unroll
        for (int i = 0; i < 4; ++i)
#pragma unroll
            for (int j = 0; j < 4; ++j) {
                int col = n0 + wn + j * 16 + lr;
#pragma unroll
                for (int r = 0; r < 4; ++r) {
                    int rowg = m0 + wm + i * 16 + kg * 4 + r;
                    if (rowg < a.M) {
                        float xv = a.xff[(size_t)(rowg >> 2) * H + col];
                        float cv = a.cch[(size_t)rowg * H + col];
                        a.fcm[(size_t)rowg * H + col] =
                            (f16)(cv * sigf(xv + acc[i][j][r]));
                    }
                }
            }
    }
}

// ---------------- f32 tiled NT GEMM (prep only: folded weight) ----------------
__global__ __launch_bounds__(256) void gemm_nt_f32(
    const float* __restrict__ A, int lda,
    const float* __restrict__ B, int ldb,
    float* __restrict__ C, int ldc, int M, int N, int K)
{
    __shared__ float As[16][128];
    __shared__ float Bs[16][128];
    const int m0 = blockIdx.y * 128, n0 = blockIdx.x * 128;
    const int tid = threadIdx.x;
    const int tx = tid & 15, ty = tid >> 4;
    float acc[8][8];
#pragma unroll
    for (int i = 0; i < 8; ++i)
#pragma unroll
        for (int j = 0; j < 8; ++j) acc[i][j] = 0.0f;
    for (int k0 = 0; k0 < K; k0 += 16) {
#pragma unroll
        for (int v = 0; v < 2; ++v) {
            int idx = tid + v * 256;
            int row = idx >> 2, c4 = idx & 3;
            float4 av = make_float4(0, 0, 0, 0);
            int gm = m0 + row;
            if (gm < M) av = *(const float4*)&A[(size_t)gm * lda + k0 + c4 * 4];
            As[c4 * 4 + 0][row] = av.x; As[c4 * 4 + 1][row] = av.y;
            As[c4 * 4 + 2][row] = av.z; As[c4 * 4 + 3][row] = av.w;
            float4 bv = make_float4(0, 0, 0, 0);
            int gn = n0 + row;
            if (gn < N) bv = *(const float4*)&B[(size_t)gn * ldb + k0 + c4 * 4];
            Bs[c4 * 4 + 0][row] = bv.x; Bs[c4 * 4 + 1][row] = bv.y;
            Bs[c4 * 4 + 2][row] = bv.z; Bs[c4 * 4 + 3][row] = bv.w;
        }
        __syncthreads();
#pragma unroll
        for (int kk = 0; kk < 16; ++kk) {
            float4 a0 = *(const float4*)&As[kk][ty * 8];
            float4 a1 = *(const float4*)&As[kk][ty * 8 + 4];
            float4 b0 = *(const float4*)&Bs[kk][tx * 8];
            float4 b1 = *(const float4*)&Bs[kk][tx * 8 + 4];
            float av[8] = { a0.x,a0.y,a0.z,a0.w,a1.x,a1.y,a1.z,a1.w };
            float bv[8] = { b0.x,b0.y,b0.z,b0.w,b1.x,b1.y,b1.z,b1.w };
#pragma unroll
            for (int i = 0; i < 8; ++i)
#pragma unroll
                for (int j = 0; j < 8; ++j)
                    acc[i][j] = fmaf(av[i], bv[j], acc[i][j]);
        }
        __syncthreads();
    }
#pragma unroll
    for (int i = 0; i < 8; ++i) {
        int gm = m0 + ty * 8 + i;
        if (gm >= M) break;
#pragma unroll
        for (int j = 0; j < 8; ++j) {
            int gn = n0 + tx * 8 + j;
            if (gn < N) C[(size_t)gm * ldc + gn] = acc[i][j];
        }
    }
}

// ---------------- elementwise / prep kernels ----------------

// LSTM step (uh path, R5-proven): g f32 [n,4HH] -> hf f32, hh f16, c f32
template<int HH>
__global__ __launch_bounds__(256) void lstm_step(
    const float* __restrict__ g, float* __restrict__ hf, f16* __restrict__ hh,
    float* __restrict__ c, int n, int init)
{
    int idx = blockIdx.x * 256 + threadIdx.x;
    int tot = n * (HH / 4);
    if (idx >= tot) return;
    int row = idx / (HH / 4);
    int c4 = (idx - row * (HH / 4)) * 4;
    const float* gr = g + (size_t)row * 4 * HH;
    float4 gi = *(const float4*)&gr[c4];
    float4 gf = *(const float4*)&gr[HH + c4];
    float4 gg = *(const float4*)&gr[2 * HH + c4];
    float4 go = *(const float4*)&gr[3 * HH + c4];
    size_t off = (size_t)row * HH + c4;
    float4 cp = make_float4(0.f, 0.f, 0.f, 0.f);
    if (!init) cp = *(const float4*)&c[off];
    float gia[4] = { gi.x,gi.y,gi.z,gi.w }, gfa[4] = { gf.x,gf.y,gf.z,gf.w };
    float gga[4] = { gg.x,gg.y,gg.z,gg.w }, goa[4] = { go.x,go.y,go.z,go.w };
    float cpa[4] = { cp.x,cp.y,cp.z,cp.w };
    float cc[4], hv[4]; f16x4 hq;
#pragma unroll
    for (int j = 0; j < 4; ++j) {
        float v = sigf(gia[j]) * tanhf(gga[j]);
        if (!init) v = fmaf(sigf(gfa[j]), cpa[j], v);
        cc[j] = v;
        hv[j] = sigf(goa[j]) * tanhf(v);
        hq[j] = (f16)hv[j];
    }
    *(float4*)&c[off] = make_float4(cc[0], cc[1], cc[2], cc[3]);
    *(float4*)&hf[off] = make_float4(hv[0], hv[1], hv[2], hv[3]);
    *(f16x4*)&hh[off] = hq;
}

// leaves: iou f32 [count,768] -> h f16, c f32 (pointers pre-offset)
__global__ __launch_bounds__(256) void leaf_apply(
    const float* __restrict__ iou, f16* __restrict__ hh, float* __restrict__ c,
    int count)
{
    int idx = blockIdx.x * 256 + threadIdx.x;
    int tot = count * (H / 4);
    if (idx >= tot) return;
    int row = idx >> 6;
    int c4 = (idx & 63) * 4;
    const float* r = iou + (size_t)row * H3;
    float4 vi = *(const float4*)&r[c4];
    float4 vo = *(const float4*)&r[H + c4];
    float4 vu = *(const float4*)&r[2 * H + c4];
    float ia[4] = { vi.x,vi.y,vi.z,vi.w }, oa[4] = { vo.x,vo.y,vo.z,vo.w }, ua[4] = { vu.x,vu.y,vu.z,vu.w };
    size_t off = (size_t)row * H + c4;
    float cc[4]; f16x4 hq;
#pragma unroll
    for (int j = 0; j < 4; ++j) {
        cc[j] = sigf(ia[j]) * tanhf(ua[j]);
        hq[j] = (f16)(sigf(oa[j]) * tanhf(cc[j]));
    }
    *(float4*)&c[off] = make_float4(cc[0], cc[1], cc[2], cc[3]);
    *(f16x4*)&hh[off] = hq;
}

// internal apply: f32 masters in; h f16 + c f32 out (pointers pre-offset)
__global__ __launch_bounds__(256) void node_apply(
    const float* __restrict__ xiou, const float* __restrict__ h_uh,
    const float* __restrict__ hfc, f16* __restrict__ hh, float* __restrict__ c,
    int Cn)
{
    int idx = blockIdx.x * 256 + threadIdx.x;
    int tot = Cn * (H / 4);
    if (idx >= tot) return;
    int row = idx >> 6;
    int c4 = (idx & 63) * 4;
    const float* xr = xiou + (size_t)row * H3;
    const float* ur = h_uh + (size_t)row * H3;
    float4 xi = *(const float4*)&xr[c4];
    float4 xo = *(const float4*)&xr[H + c4];
    float4 xu = *(const float4*)&xr[2 * H + c4];
    float4 ui = *(const float4*)&ur[c4];
    float4 uo = *(const float4*)&ur[H + c4];
    float4 uu = *(const float4*)&ur[2 * H + c4];
    float4 fv = *(const float4*)&hfc[(size_t)row * H + c4];
    float xia[4] = { xi.x,xi.y,xi.z,xi.w }, xoa[4] = { xo.x,xo.y,xo.z,xo.w }, xua[4] = { xu.x,xu.y,xu.z,xu.w };
    float uia[4] = { ui.x,ui.y,ui.z,ui.w }, uoa[4] = { uo.x,uo.y,uo.z,uo.w }, uua[4] = { uu.x,uu.y,uu.z,uu.w };
    float fva[4] = { fv.x,fv.y,fv.z,fv.w };
    size_t off = (size_t)row * H + c4;
    float cc[4]; f16x4 hq;
#pragma unroll
    for (int j = 0; j < 4; ++j) {
        float iv = xia[j] + uia[j];
        float ov = xoa[j] + uoa[j];
        float uv = xua[j] + uua[j];
        float cv = sigf(iv) * tanhf(uv) + fva[j];
        cc[j] = cv;
        hq[j] = (f16)(sigf(ov) * tanhf(cv));
    }
    *(float4*)&c[off] = make_float4(cc[0], cc[1], cc[2], cc[3]);
    *(f16x4*)&hh[off] = hq;
}

__global__ __launch_bounds__(256) void bias_sum(
    const float* __restrict__ a, const float* __restrict__ b, float* __restrict__ o, int n)
{
    int i = blockIdx.x * 256 + threadIdx.x;
    if (i < n) o[i] = a[i] + b[i];
}

__global__ __launch_bounds__(256) void cvt_f16(
    const float* __restrict__ in, f16* __restrict__ out, int n)
{
    int idx = blockIdx.x * 256 + threadIdx.x;
    if (idx * 4 >= n) return;
    float4 v = *(const float4*)&in[idx * 4];
    f16x4 o; o[0] = (f16)v.x; o[1] = (f16)v.y; o[2] = (f16)v.z; o[3] = (f16)v.w;
    *(f16x4*)&out[idx * 4] = o;
}

// gate-interleave row permutation + f32->f16:  dst[m,:] = src[gate*HH+unit,:]
__global__ __launch_bounds__(256) void permute_cvt(
    const float* __restrict__ src, f16* __restrict__ dst, int HH, int K, int tot4)
{
    int idx = blockIdx.x * 256 + threadIdx.x;
    if (idx >= tot4) return;
    int kq = K >> 2;
    int m = idx / kq;
    int k4 = (idx - m * kq) * 4;
    int gate = (m >> 4) & 3;
    int unit = (m >> 7) * 32 + ((m >> 6) & 1) * 16 + (m & 15);
    float4 v = *(const float4*)&src[(size_t)(gate * HH + unit) * K + k4];
    f16x4 o; o[0] = (f16)v.x; o[1] = (f16)v.y; o[2] = (f16)v.z; o[3] = (f16)v.w;
    *(f16x4*)&dst[(size_t)m * K + k4] = o;
}

__global__ __launch_bounds__(256) void permute_bias(
    const float* __restrict__ src, float* __restrict__ dst, int HH, int n)
{
    int m = blockIdx.x * 256 + threadIdx.x;
    if (m >= n) return;
    int gate = (m >> 4) & 3;
    int unit = (m >> 7) * 32 + ((m >> 6) & 1) * 16 + (m & 15);
    dst[m] = src[gate * HH + unit];
}

// U_iou_w f32 [768,256] -> f32 [256,768] transpose
__global__ __launch_bounds__(256) void transpose_f32(
    const float* __restrict__ in, float* __restrict__ out)
{
    int idx = blockIdx.x * 256 + threadIdx.x;
    if (idx >= H3 * E) return;
    int r = idx >> 8, c = idx & 255;
    out[(size_t)c * H3 + r] = in[idx];
}

// LayerNorm(512)+tanh in-place, one wave per row
__global__ __launch_bounds__(256) void ln_tanh(
    float* __restrict__ y, const float* __restrict__ g, const float* __restrict__ b,
    int Nrows)
{
    int wave = threadIdx.x >> 6;
    int lane = threadIdx.x & 63;
    int row = blockIdx.x * 4 + wave;
    if (row >= Nrows) return;
    float* yr = y + (size_t)row * DEC;
    float4 v0 = *(const float4*)&yr[lane * 8];
    float4 v1 = *(const float4*)&yr[lane * 8 + 4];
    float s = v0.x + v0.y + v0.z + v0.w + v1.x + v1.y + v1.z + v1.w;
    float s2 = v0.x * v0.x + v0.y * v0.y + v0.z * v0.z + v0.w * v0.w +
               v1.x * v1.x + v1.y * v1.y + v1.z * v1.z + v1.w * v1.w;
#pragma unroll
    for (int off = 32; off; off >>= 1) {
        s += __shfl_xor(s, off);
        s2 += __shfl_xor(s2, off);
    }
    float m = s * (1.0f / DEC);
    float var = s2 * (1.0f / DEC) - m * m;
    float rstd = rsqrtf(var + 1e-5f);
    float vals[8] = { v0.x,v0.y,v0.z,v0.w,v1.x,v1.y,v1.z,v1.w };
    float o[8];
#pragma unroll
    for (int j = 0; j < 8; ++j) {
        int colj = lane * 8 + j;
        o[j] = tanhf((vals[j] - m) * rstd * g[colj] + b[colj]);
    }
    *(float4*)&yr[lane * 8] = make_float4(o[0], o[1], o[2], o[3]);
    *(float4*)&yr[lane * 8 + 4] = make_float4(o[4], o[5], o[6], o[7]);
}

// ---------------- host ----------------
extern "C" void kernel_launch(void* const* d_in, const int* in_sizes, int n_in,
                              void* d_out, int out_size, void* d_ws, size_t ws_size,
                              hipStream_t stream)
{
    (void)in_sizes; (void)n_in; (void)out_size;
    const float* embed   = (const float*)d_in[0];
    const float* W_iou_w = (const float*)d_in[1];
    const float* W_iou_b = (const float*)d_in[2];
    const float* U_iou_w = (const float*)d_in[3];
    const float* W_f_w   = (const float*)d_in[4];
    const float* W_f_b   = (const float*)d_in[5];
    const float* U_f_w   = (const float*)d_in[6];
    const float* uh_wih  = (const float*)d_in[7];
    const float* uh_whh  = (const float*)d_in[8];
    const float* uh_bih  = (const float*)d_in[9];
    const float* uh_bhh  = (const float*)d_in[10];
    const float* fc_wih  = (const float*)d_in[11];
    const float* fc_whh  = (const float*)d_in[12];
    const float* fc_bih  = (const float*)d_in[13];
    const float* fc_bhh  = (const float*)d_in[14];
    const float* out_w   = (const float*)d_in[15];
    const float* out_b   = (const float*)d_in[16];
    const float* ln_g    = (const float*)d_in[17];
    const float* ln_b    = (const float*)d_in[18];

    // d_out: cbuf f32 [NNODES,H] low half (dead before final projection writes)
    float* out  = (float*)d_out;
    float* cbuf = out;

    float* ws = (float*)d_ws;
    size_t o = 0;
    f16* embed_h = (f16*)(ws + o); o += (size_t)NNODES * E / 2;
    f16* hbuf_h  = (f16*)(ws + o); o += (size_t)NNODES * H / 2;
    f16* wiou_h  = (f16*)(ws + o); o += (size_t)H3 * E / 2;
    f16* wf_h    = (f16*)(ws + o); o += (size_t)H * E / 2;
    f16* uf_h    = (f16*)(ws + o); o += (size_t)H * H / 2;
    f16* wih_h   = (f16*)(ws + o); o += (size_t)GUH * H3 / 2;   // PLAIN (R5 path)
    f16* whh_h   = (f16*)(ws + o); o += (size_t)GUH * H3 / 2;   // PLAIN (R5 path)
    f16* fih_p   = (f16*)(ws + o); o += (size_t)GFC * H / 2;    // gate-interleaved
    f16* fhh_p   = (f16*)(ws + o); o += (size_t)GFC * H / 2;    // gate-interleaved
    f16* ow_h    = (f16*)(ws + o); o += (size_t)DEC * H / 2;
    f16* fold_h  = (f16*)(ws + o); o += (size_t)GUH * E / 2;    // PLAIN (R5 path)
    float* fold_f = ws + o; o += (size_t)GUH * E;
    float* Ut     = ws + o; o += (size_t)E * H3;
    float* bsu    = ws + o; o += GUH;   // plain bias sum (uh)
    float* bsf    = ws + o; o += GFC;
    float* pbf    = ws + o; o += GFC;   // permuted bias sum (fc)

    // per-chunk f32 words/row:
    // xiou_f 768 + xiou_h 384 + xf_f 256 + xf_h 128 + gbuf 3072 + hfc_h 128
    // + hfc_f 256 + cfc 256 + h_uh_h 384 + h_uh_f 768 + c_uh 768 + fcm_h 512 = 7680
    size_t avail = ws_size / 4;
    long long room = (long long)avail - (long long)o - 8192;
    long long Cl = room / 7680;
    int C;
    if (Cl >= 16384) C = 16384;
    else if (Cl <= 256) C = 256;
    else C = (int)((Cl / 256) * 256);

    float* xiou_f = ws + o; o += (size_t)C * H3;
    f16*   xiou_h = (f16*)(ws + o); o += (size_t)C * H3 / 2;
    float* xf_f   = ws + o; o += (size_t)C * H;
    f16*   xf_h   = (f16*)(ws + o); o += (size_t)C * H / 2;
    float* gbuf   = ws + o; o += (size_t)C * GUH;   // uh gates f32; also leaf iou [4C,768]
    f16*   hfc_h  = (f16*)(ws + o); o += (size_t)C * H / 2;
    float* hfc_f  = ws + o; o += (size_t)C * H;
    float* cfc    = ws + o; o += (size_t)C * H;
    f16*   h_uh_h = (f16*)(ws + o); o += (size_t)C * H3 / 2;
    float* h_uh_f = ws + o; o += (size_t)C * H3;
    float* c_uh   = ws + o; o += (size_t)C * H3;
    f16*   fcm_h  = (f16*)(ws + o); o += (size_t)4 * C * H / 2;

    // ---- prep ----
    auto CVT = [&](const float* s, f16* dv, int n) {
        cvt_f16<<<(n / 4 + 255) / 256, 256, 0, stream>>>(s, dv, n);
    };
    CVT(embed, embed_h, NNODES * E);
    CVT(W_iou_w, wiou_h, H3 * E);
    CVT(W_f_w, wf_h, H * E);
    CVT(U_f_w, uf_h, H * H);
    CVT(out_w, ow_h, DEC * H);
    CVT(uh_wih, wih_h, GUH * H3);                       // plain
    CVT(uh_whh, whh_h, GUH * H3);                       // plain
    permute_cvt<<<(GFC * H / 4 + 255) / 256, 256, 0, stream>>>(fc_wih, fih_p, H, H, GFC * H / 4);
    permute_cvt<<<(GFC * H / 4 + 255) / 256, 256, 0, stream>>>(fc_whh, fhh_p, H, H, GFC * H / 4);
    bias_sum<<<(GUH + 255) / 256, 256, 0, stream>>>(uh_bih, uh_bhh, bsu, GUH);
    bias_sum<<<(GFC + 255) / 256, 256, 0, stream>>>(fc_bih, fc_bhh, bsf, GFC);
    permute_bias<<<(GFC + 255) / 256, 256, 0, stream>>>(bsf, pbf, H, GFC);
    transpose_f32<<<(H3 * E + 255) / 256, 256, 0, stream>>>(U_iou_w, Ut);
    {   // folded = uh_wih @ U_iou_w (f32), then plain cast
        dim3 grid(E / 128, GUH / 128);
        gemm_nt_f32<<<grid, 256, 0, stream>>>(uh_wih, H3, Ut, H3, fold_f, E, GUH, E, H3);
        CVT(fold_f, fold_h, GUH * E);
    }

    auto G0 = [&](const GArg& a, int nx, int ny) {
        gemm_one<0><<<dim3(nx, ny), 256, 0, stream>>>(a);
    };

    // ---- leaves ----
    for (int ls = 0; ls < NLEAF; ls += 4 * C) {
        int Ln = NLEAF - ls < 4 * C ? NLEAF - ls : 4 * C;
        GArg a{};
        a.A0 = embed_h + (size_t)(LEAF0 + ls) * E; a.la0 = E;
        a.B0 = wiou_h; a.lb0 = E; a.K0 = E;
        a.bias = W_iou_b; a.Cf = gbuf; a.ldc = H3; a.M = Ln; a.N = H3;
        G0(a, H3 / 128, (Ln + 127) / 128);
        leaf_apply<<<(Ln * 64 + 255) / 256, 256, 0, stream>>>(
            gbuf, hbuf_h + (size_t)(LEAF0 + ls) * H, cbuf + (size_t)(LEAF0 + ls) * H, Ln);
    }

    // ---- levels, deepest internal -> root ----
    const int counts[8] = { 1, 4, 16, 64, 256, 1024, 4096, 16384 };
    const int offs[8]   = { 0, 1, 5, 21, 85, 341, 1365, 5461 };
    for (int d = 7; d >= 0; --d) {
        int n = counts[d], start = offs[d];
        for (int s = 0; s < n; s += C) {
            int Cn = n - s < C ? n - s : C;
            int sa = start + s;
            int cst = 4 * sa + 1;
            int Mb = (Cn + 127) / 128;

            // x projections (f32 master + f16 shadow)
            {
                GArg u{};
                u.A0 = embed_h + (size_t)sa * E; u.la0 = E;
                u.B0 = wiou_h; u.lb0 = E; u.K0 = E;
                u.bias = W_iou_b; u.Cf = xiou_f; u.Ch = xiou_h; u.ldc = H3;
                u.M = Cn; u.N = H3;
                G0(u, H3 / 128, Mb);
                GArg f = u;
                f.B0 = wf_h; f.bias = W_f_b; f.Cf = xf_f; f.Ch = xf_h; f.ldc = H; f.N = H;
                G0(f, H / 128, Mb);
            }
            // fc messages (GEMM + fc_msg fused; x_f read from f32 master)
            {
                GArg a{};
                a.A0 = hbuf_h + (size_t)cst * H; a.la0 = H;
                a.B0 = uf_h; a.lb0 = H; a.K0 = H;
                a.xff = xf_f; a.cch = cbuf + (size_t)cst * H; a.fcm = fcm_h;
                a.M = 4 * Cn; a.N = H;
                gemm_one<2><<<dim3(H / 128, (4 * Cn + 127) / 128), 256, 0, stream>>>(a);
            }
            // 6 LSTM steps: uh via R5 path (EPI-0 + lstm_step), fc via EPI-1 fusion
            for (int t = 0; t <= 5; ++t) {
                // uh: gates to gbuf (f32), plain weights + bsu
                GArg u{};
                u.bias = bsu; u.Cf = gbuf; u.ldc = GUH; u.M = Cn; u.N = GUH;
                if (t == 0) {
                    u.A0 = xiou_h; u.la0 = H3; u.B0 = wih_h; u.lb0 = H3; u.K0 = H3;
                } else if (t <= 4) {
                    u.A0 = hbuf_h + (size_t)(cst + t - 1) * H; u.la0 = 4 * H;
                    u.B0 = fold_h; u.lb0 = E; u.K0 = E;
                    u.A1 = h_uh_h; u.la1 = H3; u.B1 = whh_h; u.lb1 = H3; u.K1 = H3;
                } else {
                    u.A0 = xiou_h; u.la0 = H3; u.B0 = wih_h; u.lb0 = H3; u.K0 = H3;
                    u.A1 = h_uh_h; u.la1 = H3; u.B1 = whh_h; u.lb1 = H3; u.K1 = H3;
                }
                G0(u, GUH / 128, Mb);
                lstm_step<H3><<<(Cn * 192 + 255) / 256, 256, 0, stream>>>(
                    gbuf, h_uh_f, h_uh_h, c_uh, Cn, t == 0);

                // fc: fused EPI-1 with permuted weights + pbf
                GArg f{};
                f.bias = pbf; f.cb = cfc; f.hb = hfc_h; f.HH = H; f.M = Cn; f.N = GFC;
                if (t == 5) f.hf = hfc_f;
                if (t == 0) {
                    f.A0 = xf_h; f.la0 = H; f.B0 = fih_p; f.lb0 = H; f.K0 = H;
                    f.init = 1;
                } else if (t <= 4) {
                    f.A0 = fcm_h + (size_t)(t - 1) * H; f.la0 = 4 * H;
                    f.B0 = fih_p; f.lb0 = H; f.K0 = H;
                    f.A1 = hfc_h; f.la1 = H; f.B1 = fhh_p; f.lb1 = H; f.K1 = H;
                } else {
                    f.A0 = xf_h; f.la0 = H; f.B0 = fih_p; f.lb0 = H; f.K0 = H;
                    f.A1 = hfc_h; f.la1 = H; f.B1 = fhh_p; f.lb1 = H; f.K1 = H;
                }
                gemm_one<1><<<dim3(GFC / 128, Mb), 256, 0, stream>>>(f);
            }
            // apply node func (f32 masters in)
            node_apply<<<(Cn * 64 + 255) / 256, 256, 0, stream>>>(
                xiou_f, h_uh_f, hfc_f,
                hbuf_h + (size_t)sa * H, cbuf + (size_t)sa * H, Cn);
        }
    }

    // ---- output projection (reads only ws; cbuf is dead) + LN/tanh ----
    {
        GArg a{};
        a.A0 = hbuf_h; a.la0 = H; a.B0 = ow_h; a.lb0 = H; a.K0 = H;
        a.bias = out_b; a.Cf = out; a.ldc = DEC; a.M = NNODES; a.N = DEC;
        G0(a, DEC / 128, (NNODES + 127) / 128);
    }
    ln_tanh<<<(NNODES + 3) / 4, 256, 0, stream>>>(out, ln_g, ln_b, NNODES);
}

// Round 11
// 5340.085 us; speedup vs baseline: 4.9155x; 1.0139x over previous
//
#include <hip/hip_runtime.h>
#include <math.h>
#include <cstddef>

// ---------------- constants ----------------
constexpr int E = 256, H = 256, H3 = 768;
constexpr int GUH = 3072, GFC = 1024, DEC = 512;
constexpr int NNODES = 87381, LEAF0 = 21845, NLEAF = 65536;

using f16 = _Float16;
typedef __attribute__((ext_vector_type(8))) _Float16 f16x8;
typedef __attribute__((ext_vector_type(4))) _Float16 f16x4;
typedef __attribute__((ext_vector_type(4))) float f32x4;
typedef unsigned int u32;
typedef __attribute__((address_space(1))) const u32 gu32;
typedef __attribute__((address_space(3))) u32 lu32;

static __device__ __forceinline__ float sigf(float x) { return 1.0f / (1.0f + expf(-x)); }
static __device__ __forceinline__ void gload16(const void* g, void* l) {
    __builtin_amdgcn_global_load_lds((gu32*)g, (lu32*)l, 16, 0, 0);
}

// ---------------- fused MFMA NT GEMM (single GArg per launch) ----------------
// out[m,n] = sum_k A0[m,k]B0[n,k] + sum_k A1[m,k]B1[n,k]  (K0/K1 mult of 32)
// EPI 0: +bias -> Cf f32 / Ch f16 (either or both)
// EPI 1: LSTM cell (fc path). B rows gate-interleaved:
//        row m <-> gate=(m>>4)&3, unit=(m>>7)*32+((m>>6)&1)*16+(m&15).
//        Fragment j == gate. Writes c (f32), h (f16), optional h f32 master.
// EPI 2: fc-message: fcm[r,col] = cch[r,col] * sigmoid(xff[r>>2,col] + acc)
// A rows are clamped to M-1 during staging (edge tiles read defined data).
// LDS anti-bank-conflict: 16B chunk c within each 64B row is stored at
// slot c ^ ((row>>1)&3) (swizzled GLOBAL source, linear LDS dest, swizzled
// read) -> fragment reads go from 8-way to 2-way (free) conflicts.
struct GArg {
    const f16 *A0 = nullptr, *B0 = nullptr, *A1 = nullptr, *B1 = nullptr;
    int la0 = 0, lb0 = 0, K0 = 0, la1 = 0, lb1 = 0, K1 = 0;
    const float* bias = nullptr;
    float* Cf = nullptr; f16* Ch = nullptr; int ldc = 0;              // EPI 0
    float* cb = nullptr; f16* hb = nullptr; float* hf = nullptr;     // EPI 1
    int HH = 0; int init = 0;                                        // EPI 1
    const float* xff = nullptr; const float* cch = nullptr; f16* fcm = nullptr; // EPI 2
    int M = 0, N = 0;
};

template<int EPI>
__global__ __launch_bounds__(256) void gemm_one(GArg a)
{
    __shared__ f16 As[2][128 * 32];
    __shared__ f16 Bs[2][128 * 32];
    const int tid = threadIdx.x;
    const int m0 = blockIdx.y * 128, n0 = blockIdx.x * 128;
    const int wave = tid >> 6, lane = tid & 63;
    const int wm = (wave >> 1) * 64, wn = (wave & 1) * 64;
    const int lr = lane & 15, kg = lane >> 4;
    const int px = kg ^ ((lr >> 1) & 3);   // swizzled chunk for fragment reads

    f32x4 acc[4][4];
#pragma unroll
    for (int i = 0; i < 4; ++i)
#pragma unroll
        for (int j = 0; j < 4; ++j) acc[i][j] = (f32x4){0.f, 0.f, 0.f, 0.f};

    const int nt1 = a.K0 >> 5;
    const int nt = nt1 + (a.K1 >> 5);

    auto stage = [&](int t, int b) {
        const f16* Ap; const f16* Bp; int la, lb, k0;
        if (t < nt1) { Ap = a.A0; Bp = a.B0; la = a.la0; lb = a.lb0; k0 = t * 32; }
        else         { Ap = a.A1; Bp = a.B1; la = a.la1; lb = a.lb1; k0 = (t - nt1) * 32; }
#pragma unroll
        for (int v = 0; v < 2; ++v) {
            int idx = v * 256 + tid;
            int row = idx >> 2, cph = idx & 3;
            int clog = cph ^ ((row >> 1) & 3);     // inverse swizzle on source
            int ar = m0 + row;                     // clamp A rows
            if (ar >= a.M) ar = a.M - 1;
            gload16(Ap + (size_t)ar * la + k0 + clog * 8, &As[b][idx * 8]);
            gload16(Bp + (size_t)(n0 + row) * lb + k0 + clog * 8, &Bs[b][idx * 8]);
        }
    };

    stage(0, 0);
    for (int t = 0; t < nt; ++t) {
        __syncthreads();                  // compiler drains vmcnt before barrier
        if (t + 1 < nt) stage(t + 1, (t + 1) & 1);
        const f16* as = As[t & 1];
        const f16* bs = Bs[t & 1];
        f16x8 af[4], bfr[4];
#pragma unroll
        for (int i = 0; i < 4; ++i) {
            af[i]  = *(const f16x8*)&as[(wm + i * 16 + lr) * 32 + px * 8];
            bfr[i] = *(const f16x8*)&bs[(wn + i * 16 + lr) * 32 + px * 8];
        }
#pragma unroll
        for (int i = 0; i < 4; ++i)
#pragma unroll
            for (int j = 0; j < 4; ++j)
                acc[i][j] = __builtin_amdgcn_mfma_f32_16x16x32_f16(af[i], bfr[j], acc[i][j], 0, 0, 0);
    }

    // D: col = lane&15, row = (lane>>4)*4 + r
    if constexpr (EPI == 0) {
#pragma unroll
        for (int i = 0; i < 4; ++i)
#pragma unroll
            for (int j = 0; j < 4; ++j) {
                int col = n0 + wn + j * 16 + lr;
                float bv = a.bias ? a.bias[col] : 0.f;
#pragma unroll
                for (int r = 0; r < 4; ++r) {
                    int rowg = m0 + wm + i * 16 + kg * 4 + r;
                    if (rowg < a.M) {
                        float v = acc[i][j][r] + bv;
                        if (a.Cf) a.Cf[(size_t)rowg * a.ldc + col] = v;
                        if (a.Ch) a.Ch[(size_t)rowg * a.ldc + col] = (f16)v;
                    }
                }
            }
    } else if constexpr (EPI == 1) {
        // unit index for this lane; fragment j is the gate (i,f,g,o)
        int ub = (n0 >> 2) + (wave & 1) * 16 + lr;
        float b0 = a.bias[n0 + wn + lr];
        float b1 = a.bias[n0 + wn + 16 + lr];
        float b2 = a.bias[n0 + wn + 32 + lr];
        float b3 = a.bias[n0 + wn + 48 + lr];
#pragma unroll
        for (int i = 0; i < 4; ++i)
#pragma unroll
            for (int r = 0; r < 4; ++r) {
                int rowg = m0 + wm + i * 16 + kg * 4 + r;
                if (rowg < a.M) {
                    float gi = acc[i][0][r] + b0;
                    float gf = acc[i][1][r] + b1;
                    float gg = acc[i][2][r] + b2;
                    float go = acc[i][3][r] + b3;
                    size_t off = (size_t)rowg * a.HH + ub;
                    float cn = sigf(gi) * tanhf(gg);
                    if (!a.init) cn = fmaf(sigf(gf), a.cb[off], cn);
                    a.cb[off] = cn;
                    float hv = sigf(go) * tanhf(cn);
                    a.hb[off] = (f16)hv;
                    if (a.hf) a.hf[off] = hv;     // f32 master (final step)
                }
            }
    } else {
#pragma unroll
        for (int i = 0; i < 4; ++i)
#pragma unroll
            for (int j = 0; j < 4; ++j) {
                int col = n0 + wn + j * 16 + lr;
#pragma unroll
                for (int r = 0; r < 4; ++r) {
                    int rowg = m0 + wm + i * 16 + kg * 4 + r;
                    if (rowg < a.M) {
                        float xv = a.xff[(size_t)(rowg >> 2) * H + col];
                        float cv = a.cch[(size_t)rowg * H + col];
                        a.fcm[(size_t)rowg * H + col] =
                            (f16)(cv * sigf(xv + acc[i][j][r]));
                    }
                }
            }
    }
}

// ---------------- f32 tiled NT GEMM (prep only: folded weight) ----------------
__global__ __launch_bounds__(256) void gemm_nt_f32(
    const float* __restrict__ A, int lda,
    const float* __restrict__ B, int ldb,
    float* __restrict__ C, int ldc, int M, int N, int K)
{
    __shared__ float As[16][128];
    __shared__ float Bs[16][128];
    const int m0 = blockIdx.y * 128, n0 = blockIdx.x * 128;
    const int tid = threadIdx.x;
    const int tx = tid & 15, ty = tid >> 4;
    float acc[8][8];
#pragma unroll
    for (int i = 0; i < 8; ++i)
#pragma unroll
        for (int j = 0; j < 8; ++j) acc[i][j] = 0.0f;
    for (int k0 = 0; k0 < K; k0 += 16) {
#pragma unroll
        for (int v = 0; v < 2; ++v) {
            int idx = tid + v * 256;
            int row = idx >> 2, c4 = idx & 3;
            float4 av = make_float4(0, 0, 0, 0);
            int gm = m0 + row;
            if (gm < M) av = *(const float4*)&A[(size_t)gm * lda + k0 + c4 * 4];
            As[c4 * 4 + 0][row] = av.x; As[c4 * 4 + 1][row] = av.y;
            As[c4 * 4 + 2][row] = av.z; As[c4 * 4 + 3][row] = av.w;
            float4 bv = make_float4(0, 0, 0, 0);
            int gn = n0 + row;
            if (gn < N) bv = *(const float4*)&B[(size_t)gn * ldb + k0 + c4 * 4];
            Bs[c4 * 4 + 0][row] = bv.x; Bs[c4 * 4 + 1][row] = bv.y;
            Bs[c4 * 4 + 2][row] = bv.z; Bs[c4 * 4 + 3][row] = bv.w;
        }
        __syncthreads();
#pragma unroll
        for (int kk = 0; kk < 16; ++kk) {
            float4 a0 = *(const float4*)&As[kk][ty * 8];
            float4 a1 = *(const float4*)&As[kk][ty * 8 + 4];
            float4 b0 = *(const float4*)&Bs[kk][tx * 8];
            float4 b1 = *(const float4*)&Bs[kk][tx * 8 + 4];
            float av[8] = { a0.x,a0.y,a0.z,a0.w,a1.x,a1.y,a1.z,a1.w };
            float bv[8] = { b0.x,b0.y,b0.z,b0.w,b1.x,b1.y,b1.z,b1.w };
#pragma unroll
            for (int i = 0; i < 8; ++i)
#pragma unroll
                for (int j = 0; j < 8; ++j)
                    acc[i][j] = fmaf(av[i], bv[j], acc[i][j]);
        }
        __syncthreads();
    }
#pragma unroll
    for (int i = 0; i < 8; ++i) {
        int gm = m0 + ty * 8 + i;
        if (gm >= M) break;
#pragma unroll
        for (int j = 0; j < 8; ++j) {
            int gn = n0 + tx * 8 + j;
            if (gn < N) C[(size_t)gm * ldc + gn] = acc[i][j];
        }
    }
}

// ---------------- elementwise / prep kernels ----------------

// LSTM step (uh path, R5-proven): g f32 [n,4HH] -> hf f32, hh f16, c f32
template<int HH>
__global__ __launch_bounds__(256) void lstm_step(
    const float* __restrict__ g, float* __restrict__ hf, f16* __restrict__ hh,
    float* __restrict__ c, int n, int init)
{
    int idx = blockIdx.x * 256 + threadIdx.x;
    int tot = n * (HH / 4);
    if (idx >= tot) return;
    int row = idx / (HH / 4);
    int c4 = (idx - row * (HH / 4)) * 4;
    const float* gr = g + (size_t)row * 4 * HH;
    float4 gi = *(const float4*)&gr[c4];
    float4 gf = *(const float4*)&gr[HH + c4];
    float4 gg = *(const float4*)&gr[2 * HH + c4];
    float4 go = *(const float4*)&gr[3 * HH + c4];
    size_t off = (size_t)row * HH + c4;
    float4 cp = make_float4(0.f, 0.f, 0.f, 0.f);
    if (!init) cp = *(const float4*)&c[off];
    float gia[4] = { gi.x,gi.y,gi.z,gi.w }, gfa[4] = { gf.x,gf.y,gf.z,gf.w };
    float gga[4] = { gg.x,gg.y,gg.z,gg.w }, goa[4] = { go.x,go.y,go.z,go.w };
    float cpa[4] = { cp.x,cp.y,cp.z,cp.w };
    float cc[4], hv[4]; f16x4 hq;
#pragma unroll
    for (int j = 0; j < 4; ++j) {
        float v = sigf(gia[j]) * tanhf(gga[j]);
        if (!init) v = fmaf(sigf(gfa[j]), cpa[j], v);
        cc[j] = v;
        hv[j] = sigf(goa[j]) * tanhf(v);
        hq[j] = (f16)hv[j];
    }
    *(float4*)&c[off] = make_float4(cc[0], cc[1], cc[2], cc[3]);
    *(float4*)&hf[off] = make_float4(hv[0], hv[1], hv[2], hv[3]);
    *(f16x4*)&hh[off] = hq;
}

// leaves: iou f32 [count,768] -> h f16, c f32 (pointers pre-offset)
__global__ __launch_bounds__(256) void leaf_apply(
    const float* __restrict__ iou, f16* __restrict__ hh, float* __restrict__ c,
    int count)
{
    int idx = blockIdx.x * 256 + threadIdx.x;
    int tot = count * (H / 4);
    if (idx >= tot) return;
    int row = idx >> 6;
    int c4 = (idx & 63) * 4;
    const float* r = iou + (size_t)row * H3;
    float4 vi = *(const float4*)&r[c4];
    float4 vo = *(const float4*)&r[H + c4];
    float4 vu = *(const float4*)&r[2 * H + c4];
    float ia[4] = { vi.x,vi.y,vi.z,vi.w }, oa[4] = { vo.x,vo.y,vo.z,vo.w }, ua[4] = { vu.x,vu.y,vu.z,vu.w };
    size_t off = (size_t)row * H + c4;
    float cc[4]; f16x4 hq;
#pragma unroll
    for (int j = 0; j < 4; ++j) {
        cc[j] = sigf(ia[j]) * tanhf(ua[j]);
        hq[j] = (f16)(sigf(oa[j]) * tanhf(cc[j]));
    }
    *(float4*)&c[off] = make_float4(cc[0], cc[1], cc[2], cc[3]);
    *(f16x4*)&hh[off] = hq;
}

// internal apply: f32 masters in; h f16 + c f32 out (pointers pre-offset)
__global__ __launch_bounds__(256) void node_apply(
    const float* __restrict__ xiou, const float* __restrict__ h_uh,
    const float* __restrict__ hfc, f16* __restrict__ hh, float* __restrict__ c,
    int Cn)
{
    int idx = blockIdx.x * 256 + threadIdx.x;
    int tot = Cn * (H / 4);
    if (idx >= tot) return;
    int row = idx >> 6;
    int c4 = (idx & 63) * 4;
    const float* xr = xiou + (size_t)row * H3;
    const float* ur = h_uh + (size_t)row * H3;
    float4 xi = *(const float4*)&xr[c4];
    float4 xo = *(const float4*)&xr[H + c4];
    float4 xu = *(const float4*)&xr[2 * H + c4];
    float4 ui = *(const float4*)&ur[c4];
    float4 uo = *(const float4*)&ur[H + c4];
    float4 uu = *(const float4*)&ur[2 * H + c4];
    float4 fv = *(const float4*)&hfc[(size_t)row * H + c4];
    float xia[4] = { xi.x,xi.y,xi.z,xi.w }, xoa[4] = { xo.x,xo.y,xo.z,xo.w }, xua[4] = { xu.x,xu.y,xu.z,xu.w };
    float uia[4] = { ui.x,ui.y,ui.z,ui.w }, uoa[4] = { uo.x,uo.y,uo.z,uo.w }, uua[4] = { uu.x,uu.y,uu.z,uu.w };
    float fva[4] = { fv.x,fv.y,fv.z,fv.w };
    size_t off = (size_t)row * H + c4;
    float cc[4]; f16x4 hq;
#pragma unroll
    for (int j = 0; j < 4; ++j) {
        float iv = xia[j] + uia[j];
        float ov = xoa[j] + uoa[j];
        float uv = xua[j] + uua[j];
        float cv = sigf(iv) * tanhf(uv) + fva[j];
        cc[j] = cv;
        hq[j] = (f16)(sigf(ov) * tanhf(cv));
    }
    *(float4*)&c[off] = make_float4(cc[0], cc[1], cc[2], cc[3]);
    *(f16x4*)&hh[off] = hq;
}

__global__ __launch_bounds__(256) void bias_sum(
    const float* __restrict__ a, const float* __restrict__ b, float* __restrict__ o, int n)
{
    int i = blockIdx.x * 256 + threadIdx.x;
    if (i < n) o[i] = a[i] + b[i];
}

__global__ __launch_bounds__(256) void cvt_f16(
    const float* __restrict__ in, f16* __restrict__ out, int n)
{
    int idx = blockIdx.x * 256 + threadIdx.x;
    if (idx * 4 >= n) return;
    float4 v = *(const float4*)&in[idx * 4];
    f16x4 o; o[0] = (f16)v.x; o[1] = (f16)v.y; o[2] = (f16)v.z; o[3] = (f16)v.w;
    *(f16x4*)&out[idx * 4] = o;
}

// gate-interleave row permutation + f32->f16:  dst[m,:] = src[gate*HH+unit,:]
__global__ __launch_bounds__(256) void permute_cvt(
    const float* __restrict__ src, f16* __restrict__ dst, int HH, int K, int tot4)
{
    int idx = blockIdx.x * 256 + threadIdx.x;
    if (idx >= tot4) return;
    int kq = K >> 2;
    int m = idx / kq;
    int k4 = (idx - m * kq) * 4;
    int gate = (m >> 4) & 3;
    int unit = (m >> 7) * 32 + ((m >> 6) & 1) * 16 + (m & 15);
    float4 v = *(const float4*)&src[(size_t)(gate * HH + unit) * K + k4];
    f16x4 o; o[0] = (f16)v.x; o[1] = (f16)v.y; o[2] = (f16)v.z; o[3] = (f16)v.w;
    *(f16x4*)&dst[(size_t)m * K + k4] = o;
}

__global__ __launch_bounds__(256) void permute_bias(
    const float* __restrict__ src, float* __restrict__ dst, int HH, int n)
{
    int m = blockIdx.x * 256 + threadIdx.x;
    if (m >= n) return;
    int gate = (m >> 4) & 3;
    int unit = (m >> 7) * 32 + ((m >> 6) & 1) * 16 + (m & 15);
    dst[m] = src[gate * HH + unit];
}

// U_iou_w f32 [768,256] -> f32 [256,768] transpose
__global__ __launch_bounds__(256) void transpose_f32(
    const float* __restrict__ in, float* __restrict__ out)
{
    int idx = blockIdx.x * 256 + threadIdx.x;
    if (idx >= H3 * E) return;
    int r = idx >> 8, c = idx & 255;
    out[(size_t)c * H3 + r] = in[idx];
}

// LayerNorm(512)+tanh in-place, one wave per row
__global__ __launch_bounds__(256) void ln_tanh(
    float* __restrict__ y, const float* __restrict__ g, const float* __restrict__ b,
    int Nrows)
{
    int wave = threadIdx.x >> 6;
    int lane = threadIdx.x & 63;
    int row = blockIdx.x * 4 + wave;
    if (row >= Nrows) return;
    float* yr = y + (size_t)row * DEC;
    float4 v0 = *(const float4*)&yr[lane * 8];
    float4 v1 = *(const float4*)&yr[lane * 8 + 4];
    float s = v0.x + v0.y + v0.z + v0.w + v1.x + v1.y + v1.z + v1.w;
    float s2 = v0.x * v0.x + v0.y * v0.y + v0.z * v0.z + v0.w * v0.w +
               v1.x * v1.x + v1.y * v1.y + v1.z * v1.z + v1.w * v1.w;
#pragma unroll
    for (int off = 32; off; off >>= 1) {
        s += __shfl_xor(s, off);
        s2 += __shfl_xor(s2, off);
    }
    float m = s * (1.0f / DEC);
    float var = s2 * (1.0f / DEC) - m * m;
    float rstd = rsqrtf(var + 1e-5f);
    float vals[8] = { v0.x,v0.y,v0.z,v0.w,v1.x,v1.y,v1.z,v1.w };
    float o[8];
#pragma unroll
    for (int j = 0; j < 8; ++j) {
        int colj = lane * 8 + j;
        o[j] = tanhf((vals[j] - m) * rstd * g[colj] + b[colj]);
    }
    *(float4*)&yr[lane * 8] = make_float4(o[0], o[1], o[2], o[3]);
    *(float4*)&yr[lane * 8 + 4] = make_float4(o[4], o[5], o[6], o[7]);
}

// ---------------- host ----------------
extern "C" void kernel_launch(void* const* d_in, const int* in_sizes, int n_in,
                              void* d_out, int out_size, void* d_ws, size_t ws_size,
                              hipStream_t stream)
{
    (void)in_sizes; (void)n_in; (void)out_size;
    const float* embed   = (const float*)d_in[0];
    const float* W_iou_w = (const float*)d_in[1];
    const float* W_iou_b = (const float*)d_in[2];
    const float* U_iou_w = (const float*)d_in[3];
    const float* W_f_w   = (const float*)d_in[4];
    const float* W_f_b   = (const float*)d_in[5];
    const float* U_f_w   = (const float*)d_in[6];
    const float* uh_wih  = (const float*)d_in[7];
    const float* uh_whh  = (const float*)d_in[8];
    const float* uh_bih  = (const float*)d_in[9];
    const float* uh_bhh  = (const float*)d_in[10];
    const float* fc_wih  = (const float*)d_in[11];
    const float* fc_whh  = (const float*)d_in[12];
    const float* fc_bih  = (const float*)d_in[13];
    const float* fc_bhh  = (const float*)d_in[14];
    const float* out_w   = (const float*)d_in[15];
    const float* out_b   = (const float*)d_in[16];
    const float* ln_g    = (const float*)d_in[17];
    const float* ln_b    = (const float*)d_in[18];

    // d_out: cbuf f32 [NNODES,H] low half (dead before final projection writes)
    float* out  = (float*)d_out;
    float* cbuf = out;

    float* ws = (float*)d_ws;
    size_t o = 0;
    f16* embed_h = (f16*)(ws + o); o += (size_t)NNODES * E / 2;
    f16* hbuf_h  = (f16*)(ws + o); o += (size_t)NNODES * H / 2;
    f16* wiou_h  = (f16*)(ws + o); o += (size_t)H3 * E / 2;
    f16* wf_h    = (f16*)(ws + o); o += (size_t)H * E / 2;
    f16* uf_h    = (f16*)(ws + o); o += (size_t)H * H / 2;
    f16* wih_h   = (f16*)(ws + o); o += (size_t)GUH * H3 / 2;   // PLAIN (uh path)
    f16* whh_h   = (f16*)(ws + o); o += (size_t)GUH * H3 / 2;   // PLAIN (uh path)
    f16* fih_p   = (f16*)(ws + o); o += (size_t)GFC * H / 2;    // gate-interleaved
    f16* fhh_p   = (f16*)(ws + o); o += (size_t)GFC * H / 2;    // gate-interleaved
    f16* ow_h    = (f16*)(ws + o); o += (size_t)DEC * H / 2;
    f16* fold_h  = (f16*)(ws + o); o += (size_t)GUH * E / 2;    // PLAIN (uh path)
    float* fold_f = ws + o; o += (size_t)GUH * E;
    float* Ut     = ws + o; o += (size_t)E * H3;
    float* bsu    = ws + o; o += GUH;   // plain bias sum (uh)
    float* bsf    = ws + o; o += GFC;
    float* pbf    = ws + o; o += GFC;   // permuted bias sum (fc)

    // per-chunk f32 words/row:
    // xiou_f 768 + xiou_h 384 + xf_f 256 + xf_h 128 + gbuf 3072 + hfc_h 128
    // + hfc_f 256 + cfc 256 + h_uh_h 384 + h_uh_f 768 + c_uh 768 + fcm_h 512 = 7680
    size_t avail = ws_size / 4;
    long long room = (long long)avail - (long long)o - 8192;
    long long Cl = room / 7680;
    int C;
    if (Cl >= 16384) C = 16384;
    else if (Cl <= 256) C = 256;
    else C = (int)((Cl / 256) * 256);

    float* xiou_f = ws + o; o += (size_t)C * H3;
    f16*   xiou_h = (f16*)(ws + o); o += (size_t)C * H3 / 2;
    float* xf_f   = ws + o; o += (size_t)C * H;
    f16*   xf_h   = (f16*)(ws + o); o += (size_t)C * H / 2;
    float* gbuf   = ws + o; o += (size_t)C * GUH;   // uh gates f32; also leaf iou [4C,768]
    f16*   hfc_h  = (f16*)(ws + o); o += (size_t)C * H / 2;
    float* hfc_f  = ws + o; o += (size_t)C * H;
    float* cfc    = ws + o; o += (size_t)C * H;
    f16*   h_uh_h = (f16*)(ws + o); o += (size_t)C * H3 / 2;
    float* h_uh_f = ws + o; o += (size_t)C * H3;
    float* c_uh   = ws + o; o += (size_t)C * H3;
    f16*   fcm_h  = (f16*)(ws + o); o += (size_t)4 * C * H / 2;

    // ---- prep ----
    auto CVT = [&](const float* s, f16* dv, int n) {
        cvt_f16<<<(n / 4 + 255) / 256, 256, 0, stream>>>(s, dv, n);
    };
    CVT(embed, embed_h, NNODES * E);
    CVT(W_iou_w, wiou_h, H3 * E);
    CVT(W_f_w, wf_h, H * E);
    CVT(U_f_w, uf_h, H * H);
    CVT(out_w, ow_h, DEC * H);
    CVT(uh_wih, wih_h, GUH * H3);                       // plain
    CVT(uh_whh, whh_h, GUH * H3);                       // plain
    permute_cvt<<<(GFC * H / 4 + 255) / 256, 256, 0, stream>>>(fc_wih, fih_p, H, H, GFC * H / 4);
    permute_cvt<<<(GFC * H / 4 + 255) / 256, 256, 0, stream>>>(fc_whh, fhh_p, H, H, GFC * H / 4);
    bias_sum<<<(GUH + 255) / 256, 256, 0, stream>>>(uh_bih, uh_bhh, bsu, GUH);
    bias_sum<<<(GFC + 255) / 256, 256, 0, stream>>>(fc_bih, fc_bhh, bsf, GFC);
    permute_bias<<<(GFC + 255) / 256, 256, 0, stream>>>(bsf, pbf, H, GFC);
    transpose_f32<<<(H3 * E + 255) / 256, 256, 0, stream>>>(U_iou_w, Ut);
    {   // folded = uh_wih @ U_iou_w (f32), then plain cast
        dim3 grid(E / 128, GUH / 128);
        gemm_nt_f32<<<grid, 256, 0, stream>>>(uh_wih, H3, Ut, H3, fold_f, E, GUH, E, H3);
        CVT(fold_f, fold_h, GUH * E);
    }

    auto G0 = [&](const GArg& a, int nx, int ny) {
        gemm_one<0><<<dim3(nx, ny), 256, 0, stream>>>(a);
    };

    // ---- leaves ----
    for (int ls = 0; ls < NLEAF; ls += 4 * C) {
        int Ln = NLEAF - ls < 4 * C ? NLEAF - ls : 4 * C;
        GArg a{};
        a.A0 = embed_h + (size_t)(LEAF0 + ls) * E; a.la0 = E;
        a.B0 = wiou_h; a.lb0 = E; a.K0 = E;
        a.bias = W_iou_b; a.Cf = gbuf; a.ldc = H3; a.M = Ln; a.N = H3;
        G0(a, H3 / 128, (Ln + 127) / 128);
        leaf_apply<<<(Ln * 64 + 255) / 256, 256, 0, stream>>>(
            gbuf, hbuf_h + (size_t)(LEAF0 + ls) * H, cbuf + (size_t)(LEAF0 + ls) * H, Ln);
    }

    // ---- levels, deepest internal -> root ----
    const int counts[8] = { 1, 4, 16, 64, 256, 1024, 4096, 16384 };
    const int offs[8]   = { 0, 1, 5, 21, 85, 341, 1365, 5461 };
    for (int d = 7; d >= 0; --d) {
        int n = counts[d], start = offs[d];
        for (int s = 0; s < n; s += C) {
            int Cn = n - s < C ? n - s : C;
            int sa = start + s;
            int cst = 4 * sa + 1;
            int Mb = (Cn + 127) / 128;

            // x projections (f32 master + f16 shadow)
            {
                GArg u{};
                u.A0 = embed_h + (size_t)sa * E; u.la0 = E;
                u.B0 = wiou_h; u.lb0 = E; u.K0 = E;
                u.bias = W_iou_b; u.Cf = xiou_f; u.Ch = xiou_h; u.ldc = H3;
                u.M = Cn; u.N = H3;
                G0(u, H3 / 128, Mb);
                GArg f = u;
                f.B0 = wf_h; f.bias = W_f_b; f.Cf = xf_f; f.Ch = xf_h; f.ldc = H; f.N = H;
                G0(f, H / 128, Mb);
            }
            // fc messages (GEMM + fc_msg fused; x_f read from f32 master)
            {
                GArg a{};
                a.A0 = hbuf_h + (size_t)cst * H; a.la0 = H;
                a.B0 = uf_h; a.lb0 = H; a.K0 = H;
                a.xff = xf_f; a.cch = cbuf + (size_t)cst * H; a.fcm = fcm_h;
                a.M = 4 * Cn; a.N = H;
                gemm_one<2><<<dim3(H / 128, (4 * Cn + 127) / 128), 256, 0, stream>>>(a);
            }
            // 6 LSTM steps: uh via EPI-0 + lstm_step, fc via EPI-1 fusion
            for (int t = 0; t <= 5; ++t) {
                // uh: gates to gbuf (f32), plain weights + bsu
                GArg u{};
                u.bias = bsu; u.Cf = gbuf; u.ldc = GUH; u.M = Cn; u.N = GUH;
                if (t == 0) {
                    u.A0 = xiou_h; u.la0 = H3; u.B0 = wih_h; u.lb0 = H3; u.K0 = H3;
                } else if (t <= 4) {
                    u.A0 = hbuf_h + (size_t)(cst + t - 1) * H; u.la0 = 4 * H;
                    u.B0 = fold_h; u.lb0 = E; u.K0 = E;
                    u.A1 = h_uh_h; u.la1 = H3; u.B1 = whh_h; u.lb1 = H3; u.K1 = H3;
                } else {
                    u.A0 = xiou_h; u.la0 = H3; u.B0 = wih_h; u.lb0 = H3; u.K0 = H3;
                    u.A1 = h_uh_h; u.la1 = H3; u.B1 = whh_h; u.lb1 = H3; u.K1 = H3;
                }
                G0(u, GUH / 128, Mb);
                lstm_step<H3><<<(Cn * 192 + 255) / 256, 256, 0, stream>>>(
                    gbuf, h_uh_f, h_uh_h, c_uh, Cn, t == 0);

                // fc: fused EPI-1 with permuted weights + pbf
                GArg f{};
                f.bias = pbf; f.cb = cfc; f.hb = hfc_h; f.HH = H; f.M = Cn; f.N = GFC;
                if (t == 5) f.hf = hfc_f;
                if (t == 0) {
                    f.A0 = xf_h; f.la0 = H; f.B0 = fih_p; f.lb0 = H; f.K0 = H;
                    f.init = 1;
                } else if (t <= 4) {
                    f.A0 = fcm_h + (size_t)(t - 1) * H; f.la0 = 4 * H;
                    f.B0 = fih_p; f.lb0 = H; f.K0 = H;
                    f.A1 = hfc_h; f.la1 = H; f.B1 = fhh_p; f.lb1 = H; f.K1 = H;
                } else {
                    f.A0 = xf_h; f.la0 = H; f.B0 = fih_p; f.lb0 = H; f.K0 = H;
                    f.A1 = hfc_h; f.la1 = H; f.B1 = fhh_p; f.lb1 = H; f.K1 = H;
                }
                gemm_one<1><<<dim3(GFC / 128, Mb), 256, 0, stream>>>(f);
            }
            // apply node func (f32 masters in)
            node_apply<<<(Cn * 64 + 255) / 256, 256, 0, stream>>>(
                xiou_f, h_uh_f, hfc_f,
                hbuf_h + (size_t)sa * H, cbuf + (size_t)sa * H, Cn);
        }
    }

    // ---- output projection (reads only ws; cbuf is dead) + LN/tanh ----
    {
        GArg a{};
        a.A0 = hbuf_h; a.la0 = H; a.B0 = ow_h; a.lb0 = H; a.K0 = H;
        a.bias = out_b; a.Cf = out; a.ldc = DEC; a.M = NNODES; a.N = DEC;
        G0(a, DEC / 128, (NNODES + 127) / 128);
    }
    ln_tanh<<<(NNODES + 3) / 4, 256, 0, stream>>>(out, ln_g, ln_b, NNODES);
}

// Round 14
// 4666.801 us; speedup vs baseline: 5.6246x; 1.1443x over previous
//
#include <hip/hip_runtime.h>
#include <math.h>
#include <cstddef>

// ---------------- constants ----------------
constexpr int E = 256, H = 256, H3 = 768;
constexpr int GUH = 3072, GFC = 1024, DEC = 512;
constexpr int NNODES = 87381, LEAF0 = 21845, NLEAF = 65536;

using f16 = _Float16;
typedef __attribute__((ext_vector_type(8))) _Float16 f16x8;
typedef __attribute__((ext_vector_type(4))) _Float16 f16x4;
typedef __attribute__((ext_vector_type(4))) float f32x4;
typedef unsigned int u32;
typedef __attribute__((address_space(1))) const u32 gu32;
typedef __attribute__((address_space(3))) u32 lu32;

static __device__ __forceinline__ float sigf(float x) { return 1.0f / (1.0f + expf(-x)); }
static __device__ __forceinline__ void gload16(const void* g, void* l) {
    __builtin_amdgcn_global_load_lds((gu32*)g, (lu32*)l, 16, 0, 0);
}

// ---------------- fused MFMA NT GEMM (single GArg per launch) ----------------
// out[m,n] = sum_k A0[m,k]B0[n,k] + sum_k A1[m,k]B1[n,k]  (K0/K1 mult of 32)
// EPI 0: +bias -> Cf f32 / Ch f16 (either or both)
// EPI 1: LSTM cell. B rows gate-interleaved: row m <-> gate=(m>>4)&3,
//        unit=(m>>7)*32+((m>>6)&1)*16+(m&15). Fragment j == gate. Writes
//        c (f32), h (f16), optional h f32 master.
//        RACE SAFETY: hb must be a DIFFERENT buffer than any A input
//        (h is double-buffered across steps by the host).
// EPI 2: fc-message: fcm[r,col] = cch[r,col] * sigmoid(xff[r>>2,col] + acc)
// A rows clamped to M-1 during staging. LDS bank-conflict swizzle: chunk
// c_phys = c_logical ^ ((row>>1)&3) on source addr and read addr.
// XCD-aware bijective block swizzle (m204): order-only, correctness-neutral.
struct GArg {
    const f16 *A0 = nullptr, *B0 = nullptr, *A1 = nullptr, *B1 = nullptr;
    int la0 = 0, lb0 = 0, K0 = 0, la1 = 0, lb1 = 0, K1 = 0;
    const float* bias = nullptr;
    float* Cf = nullptr; f16* Ch = nullptr; int ldc = 0;              // EPI 0
    float* cb = nullptr; f16* hb = nullptr; float* hf = nullptr;     // EPI 1
    int HH = 0; int init = 0;                                        // EPI 1
    const float* xff = nullptr; const float* cch = nullptr; f16* fcm = nullptr; // EPI 2
    int M = 0, N = 0;
};

template<int EPI>
__global__ __launch_bounds__(256) void gemm_one(GArg a)
{
    __shared__ f16 As[2][128 * 32];
    __shared__ f16 Bs[2][128 * 32];
    const int tid = threadIdx.x;

    // XCD-aware bijective swizzle of the linear block id (m204)
    const int gX = gridDim.x;
    const int nwg = gX * gridDim.y;
    const int orig = blockIdx.y * gX + blockIdx.x;
    const int q = nwg >> 3, r = nwg & 7;
    const int xcd = orig & 7, rem = orig >> 3;
    const int wgid = (xcd < r ? xcd * (q + 1) : r * (q + 1) + (xcd - r) * q) + rem;
    const int bx = wgid % gX, by = wgid / gX;

    const int m0 = by * 128, n0 = bx * 128;
    const int wave = tid >> 6, lane = tid & 63;
    const int wm = (wave >> 1) * 64, wn = (wave & 1) * 64;
    const int lr = lane & 15, kg = lane >> 4;
    const int px = kg ^ ((lr >> 1) & 3);   // swizzled chunk for fragment reads

    f32x4 acc[4][4];
#pragma unroll
    for (int i = 0; i < 4; ++i)
#pragma unroll
        for (int j = 0; j < 4; ++j) acc[i][j] = (f32x4){0.f, 0.f, 0.f, 0.f};

    const int nt1 = a.K0 >> 5;
    const int nt = nt1 + (a.K1 >> 5);

    auto stage = [&](int t, int b) {
        const f16* Ap; const f16* Bp; int la, lb, k0;
        if (t < nt1) { Ap = a.A0; Bp = a.B0; la = a.la0; lb = a.lb0; k0 = t * 32; }
        else         { Ap = a.A1; Bp = a.B1; la = a.la1; lb = a.lb1; k0 = (t - nt1) * 32; }
#pragma unroll
        for (int v = 0; v < 2; ++v) {
            int idx = v * 256 + tid;
            int row = idx >> 2, cph = idx & 3;
            int clog = cph ^ ((row >> 1) & 3);     // inverse swizzle on source
            int ar = m0 + row;                     // clamp A rows
            if (ar >= a.M) ar = a.M - 1;
            gload16(Ap + (size_t)ar * la + k0 + clog * 8, &As[b][idx * 8]);
            gload16(Bp + (size_t)(n0 + row) * lb + k0 + clog * 8, &Bs[b][idx * 8]);
        }
    };

    stage(0, 0);
    for (int t = 0; t < nt; ++t) {
        __syncthreads();                  // compiler drains vmcnt before barrier
        if (t + 1 < nt) stage(t + 1, (t + 1) & 1);
        const f16* as = As[t & 1];
        const f16* bs = Bs[t & 1];
        f16x8 af[4], bfr[4];
#pragma unroll
        for (int i = 0; i < 4; ++i) {
            af[i]  = *(const f16x8*)&as[(wm + i * 16 + lr) * 32 + px * 8];
            bfr[i] = *(const f16x8*)&bs[(wn + i * 16 + lr) * 32 + px * 8];
        }
#pragma unroll
        for (int i = 0; i < 4; ++i)
#pragma unroll
            for (int j = 0; j < 4; ++j)
                acc[i][j] = __builtin_amdgcn_mfma_f32_16x16x32_f16(af[i], bfr[j], acc[i][j], 0, 0, 0);
    }

    // D: col = lane&15, row = (lane>>4)*4 + r
    if constexpr (EPI == 0) {
#pragma unroll
        for (int i = 0; i < 4; ++i)
#pragma unroll
            for (int j = 0; j < 4; ++j) {
                int col = n0 + wn + j * 16 + lr;
                float bv = a.bias ? a.bias[col] : 0.f;
#pragma unroll
                for (int r = 0; r < 4; ++r) {
                    int rowg = m0 + wm + i * 16 + kg * 4 + r;
                    if (rowg < a.M) {
                        float v = acc[i][j][r] + bv;
                        if (a.Cf) a.Cf[(size_t)rowg * a.ldc + col] = v;
                        if (a.Ch) a.Ch[(size_t)rowg * a.ldc + col] = (f16)v;
                    }
                }
            }
    } else if constexpr (EPI == 1) {
        // unit index for this lane; fragment j is the gate (i,f,g,o)
        int ub = (n0 >> 2) + (wave & 1) * 16 + lr;
        float b0 = a.bias[n0 + wn + lr];
        float b1 = a.bias[n0 + wn + 16 + lr];
        float b2 = a.bias[n0 + wn + 32 + lr];
        float b3 = a.bias[n0 + wn + 48 + lr];
#pragma unroll
        for (int i = 0; i < 4; ++i)
#pragma unroll
            for (int r = 0; r < 4; ++r) {
                int rowg = m0 + wm + i * 16 + kg * 4 + r;
                if (rowg < a.M) {
                    float gi = acc[i][0][r] + b0;
                    float gf = acc[i][1][r] + b1;
                    float gg = acc[i][2][r] + b2;
                    float go = acc[i][3][r] + b3;
                    size_t off = (size_t)rowg * a.HH + ub;
                    float cn = sigf(gi) * tanhf(gg);
                    if (!a.init) cn = fmaf(sigf(gf), a.cb[off], cn);
                    a.cb[off] = cn;
                    float hv = sigf(go) * tanhf(cn);
                    a.hb[off] = (f16)hv;
                    if (a.hf) a.hf[off] = hv;     // f32 master (final step)
                }
            }
    } else {
#pragma unroll
        for (int i = 0; i < 4; ++i)
#pragma unroll
            for (int j = 0; j < 4; ++j) {
                int col = n0 + wn + j * 16 + lr;
#pragma unroll
                for (int r = 0; r < 4; ++r) {
                    int rowg = m0 + wm + i * 16 + kg * 4 + r;
                    if (rowg < a.M) {
                        float xv = a.xff[(size_t)(rowg >> 2) * H + col];
                        float cv = a.cch[(size_t)rowg * H + col];
                        a.fcm[(size_t)rowg * H + col] =
                            (f16)(cv * sigf(xv + acc[i][j][r]));
                    }
                }
            }
    }
}

// ---------------- f32 tiled NT GEMM (prep only: folded weight) ----------------
__global__ __launch_bounds__(256) void gemm_nt_f32(
    const float* __restrict__ A, int lda,
    const float* __restrict__ B, int ldb,
    float* __restrict__ C, int ldc, int M, int N, int K)
{
    __shared__ float As[16][128];
    __shared__ float Bs[16][128];
    const int m0 = blockIdx.y * 128, n0 = blockIdx.x * 128;
    const int tid = threadIdx.x;
    const int tx = tid & 15, ty = tid >> 4;
    float acc[8][8];
#pragma unroll
    for (int i = 0; i < 8; ++i)
#pragma unroll
        for (int j = 0; j < 8; ++j) acc[i][j] = 0.0f;
    for (int k0 = 0; k0 < K; k0 += 16) {
#pragma unroll
        for (int v = 0; v < 2; ++v) {
            int idx = tid + v * 256;
            int row = idx >> 2, c4 = idx & 3;
            float4 av = make_float4(0, 0, 0, 0);
            int gm = m0 + row;
            if (gm < M) av = *(const float4*)&A[(size_t)gm * lda + k0 + c4 * 4];
            As[c4 * 4 + 0][row] = av.x; As[c4 * 4 + 1][row] = av.y;
            As[c4 * 4 + 2][row] = av.z; As[c4 * 4 + 3][row] = av.w;
            float4 bv = make_float4(0, 0, 0, 0);
            int gn = n0 + row;
            if (gn < N) bv = *(const float4*)&B[(size_t)gn * ldb + k0 + c4 * 4];
            Bs[c4 * 4 + 0][row] = bv.x; Bs[c4 * 4 + 1][row] = bv.y;
            Bs[c4 * 4 + 2][row] = bv.z; Bs[c4 * 4 + 3][row] = bv.w;
        }
        __syncthreads();
#pragma unroll
        for (int kk = 0; kk < 16; ++kk) {
            float4 a0 = *(const float4*)&As[kk][ty * 8];
            float4 a1 = *(const float4*)&As[kk][ty * 8 + 4];
            float4 b0 = *(const float4*)&Bs[kk][tx * 8];
            float4 b1 = *(const float4*)&Bs[kk][tx * 8 + 4];
            float av[8] = { a0.x,a0.y,a0.z,a0.w,a1.x,a1.y,a1.z,a1.w };
            float bv[8] = { b0.x,b0.y,b0.z,b0.w,b1.x,b1.y,b1.z,b1.w };
#pragma unroll
            for (int i = 0; i < 8; ++i)
#pragma unroll
                for (int j = 0; j < 8; ++j)
                    acc[i][j] = fmaf(av[i], bv[j], acc[i][j]);
        }
        __syncthreads();
    }
#pragma unroll
    for (int i = 0; i < 8; ++i) {
        int gm = m0 + ty * 8 + i;
        if (gm >= M) break;
#pragma unroll
        for (int j = 0; j < 8; ++j) {
            int gn = n0 + tx * 8 + j;
            if (gn < N) C[(size_t)gm * ldc + gn] = acc[i][j];
        }
    }
}

// ---------------- elementwise / prep kernels ----------------

// leaves: iou f32 [count,768] -> h f16, c f32 (pointers pre-offset)
__global__ __launch_bounds__(256) void leaf_apply(
    const float* __restrict__ iou, f16* __restrict__ hh, float* __restrict__ c,
    int count)
{
    int idx = blockIdx.x * 256 + threadIdx.x;
    int tot = count * (H / 4);
    if (idx >= tot) return;
    int row = idx >> 6;
    int c4 = (idx & 63) * 4;
    const float* r = iou + (size_t)row * H3;
    float4 vi = *(const float4*)&r[c4];
    float4 vo = *(const float4*)&r[H + c4];
    float4 vu = *(const float4*)&r[2 * H + c4];
    float ia[4] = { vi.x,vi.y,vi.z,vi.w }, oa[4] = { vo.x,vo.y,vo.z,vo.w }, ua[4] = { vu.x,vu.y,vu.z,vu.w };
    size_t off = (size_t)row * H + c4;
    float cc[4]; f16x4 hq;
#pragma unroll
    for (int j = 0; j < 4; ++j) {
        cc[j] = sigf(ia[j]) * tanhf(ua[j]);
        hq[j] = (f16)(sigf(oa[j]) * tanhf(cc[j]));
    }
    *(float4*)&c[off] = make_float4(cc[0], cc[1], cc[2], cc[3]);
    *(f16x4*)&hh[off] = hq;
}

// internal apply: f32 masters in; h f16 + c f32 out (pointers pre-offset)
__global__ __launch_bounds__(256) void node_apply(
    const float* __restrict__ xiou, const float* __restrict__ h_uh,
    const float* __restrict__ hfc, f16* __restrict__ hh, float* __restrict__ c,
    int Cn)
{
    int idx = blockIdx.x * 256 + threadIdx.x;
    int tot = Cn * (H / 4);
    if (idx >= tot) return;
    int row = idx >> 6;
    int c4 = (idx & 63) * 4;
    const float* xr = xiou + (size_t)row * H3;
    const float* ur = h_uh + (size_t)row * H3;
    float4 xi = *(const float4*)&xr[c4];
    float4 xo = *(const float4*)&xr[H + c4];
    float4 xu = *(const float4*)&xr[2 * H + c4];
    float4 ui = *(const float4*)&ur[c4];
    float4 uo = *(const float4*)&ur[H + c4];
    float4 uu = *(const float4*)&ur[2 * H + c4];
    float4 fv = *(const float4*)&hfc[(size_t)row * H + c4];
    float xia[4] = { xi.x,xi.y,xi.z,xi.w }, xoa[4] = { xo.x,xo.y,xo.z,xo.w }, xua[4] = { xu.x,xu.y,xu.z,xu.w };
    float uia[4] = { ui.x,ui.y,ui.z,ui.w }, uoa[4] = { uo.x,uo.y,uo.z,uo.w }, uua[4] = { uu.x,uu.y,uu.z,uu.w };
    float fva[4] = { fv.x,fv.y,fv.z,fv.w };
    size_t off = (size_t)row * H + c4;
    float cc[4]; f16x4 hq;
#pragma unroll
    for (int j = 0; j < 4; ++j) {
        float iv = xia[j] + uia[j];
        float ov = xoa[j] + uoa[j];
        float uv = xua[j] + uua[j];
        float cv = sigf(iv) * tanhf(uv) + fva[j];
        cc[j] = cv;
        hq[j] = (f16)(sigf(ov) * tanhf(cv));
    }
    *(float4*)&c[off] = make_float4(cc[0], cc[1], cc[2], cc[3]);
    *(f16x4*)&hh[off] = hq;
}

__global__ __launch_bounds__(256) void bias_sum(
    const float* __restrict__ a, const float* __restrict__ b, float* __restrict__ o, int n)
{
    int i = blockIdx.x * 256 + threadIdx.x;
    if (i < n) o[i] = a[i] + b[i];
}

__global__ __launch_bounds__(256) void cvt_f16(
    const float* __restrict__ in, f16* __restrict__ out, int n)
{
    int idx = blockIdx.x * 256 + threadIdx.x;
    if (idx * 4 >= n) return;
    float4 v = *(const float4*)&in[idx * 4];
    f16x4 o; o[0] = (f16)v.x; o[1] = (f16)v.y; o[2] = (f16)v.z; o[3] = (f16)v.w;
    *(f16x4*)&out[idx * 4] = o;
}

// gate-interleave row permutation + f32->f16:  dst[m,:] = src[gate*HH+unit,:]
__global__ __launch_bounds__(256) void permute_cvt(
    const float* __restrict__ src, f16* __restrict__ dst, int HH, int K, int tot4)
{
    int idx = blockIdx.x * 256 + threadIdx.x;
    if (idx >= tot4) return;
    int kq = K >> 2;
    int m = idx / kq;
    int k4 = (idx - m * kq) * 4;
    int gate = (m >> 4) & 3;
    int unit = (m >> 7) * 32 + ((m >> 6) & 1) * 16 + (m & 15);
    float4 v = *(const float4*)&src[(size_t)(gate * HH + unit) * K + k4];
    f16x4 o; o[0] = (f16)v.x; o[1] = (f16)v.y; o[2] = (f16)v.z; o[3] = (f16)v.w;
    *(f16x4*)&dst[(size_t)m * K + k4] = o;
}

__global__ __launch_bounds__(256) void permute_bias(
    const float* __restrict__ src, float* __restrict__ dst, int HH, int n)
{
    int m = blockIdx.x * 256 + threadIdx.x;
    if (m >= n) return;
    int gate = (m >> 4) & 3;
    int unit = (m >> 7) * 32 + ((m >> 6) & 1) * 16 + (m & 15);
    dst[m] = src[gate * HH + unit];
}

// U_iou_w f32 [768,256] -> f32 [256,768] transpose
__global__ __launch_bounds__(256) void transpose_f32(
    const float* __restrict__ in, float* __restrict__ out)
{
    int idx = blockIdx.x * 256 + threadIdx.x;
    if (idx >= H3 * E) return;
    int r = idx >> 8, c = idx & 255;
    out[(size_t)c * H3 + r] = in[idx];
}

// LayerNorm(512)+tanh in-place, one wave per row
__global__ __launch_bounds__(256) void ln_tanh(
    float* __restrict__ y, const float* __restrict__ g, const float* __restrict__ b,
    int Nrows)
{
    int wave = threadIdx.x >> 6;
    int lane = threadIdx.x & 63;
    int row = blockIdx.x * 4 + wave;
    if (row >= Nrows) return;
    float* yr = y + (size_t)row * DEC;
    float4 v0 = *(const float4*)&yr[lane * 8];
    float4 v1 = *(const float4*)&yr[lane * 8 + 4];
    float s = v0.x + v0.y + v0.z + v0.w + v1.x + v1.y + v1.z + v1.w;
    float s2 = v0.x * v0.x + v0.y * v0.y + v0.z * v0.z + v0.w * v0.w +
               v1.x * v1.x + v1.y * v1.y + v1.z * v1.z + v1.w * v1.w;
#pragma unroll
    for (int off = 32; off; off >>= 1) {
        s += __shfl_xor(s, off);
        s2 += __shfl_xor(s2, off);
    }
    float m = s * (1.0f / DEC);
    float var = s2 * (1.0f / DEC) - m * m;
    float rstd = rsqrtf(var + 1e-5f);
    float vals[8] = { v0.x,v0.y,v0.z,v0.w,v1.x,v1.y,v1.z,v1.w };
    float o[8];
#pragma unroll
    for (int j = 0; j < 8; ++j) {
        int colj = lane * 8 + j;
        o[j] = tanhf((vals[j] - m) * rstd * g[colj] + b[colj]);
    }
    *(float4*)&yr[lane * 8] = make_float4(o[0], o[1], o[2], o[3]);
    *(float4*)&yr[lane * 8 + 4] = make_float4(o[4], o[5], o[6], o[7]);
}

// ---------------- host ----------------
extern "C" void kernel_launch(void* const* d_in, const int* in_sizes, int n_in,
                              void* d_out, int out_size, void* d_ws, size_t ws_size,
                              hipStream_t stream)
{
    (void)in_sizes; (void)n_in; (void)out_size;
    const float* embed   = (const float*)d_in[0];
    const float* W_iou_w = (const float*)d_in[1];
    const float* W_iou_b = (const float*)d_in[2];
    const float* U_iou_w = (const float*)d_in[3];
    const float* W_f_w   = (const float*)d_in[4];
    const float* W_f_b   = (const float*)d_in[5];
    const float* U_f_w   = (const float*)d_in[6];
    const float* uh_wih  = (const float*)d_in[7];
    const float* uh_whh  = (const float*)d_in[8];
    const float* uh_bih  = (const float*)d_in[9];
    const float* uh_bhh  = (const float*)d_in[10];
    const float* fc_wih  = (const float*)d_in[11];
    const float* fc_whh  = (const float*)d_in[12];
    const float* fc_bih  = (const float*)d_in[13];
    const float* fc_bhh  = (const float*)d_in[14];
    const float* out_w   = (const float*)d_in[15];
    const float* out_b   = (const float*)d_in[16];
    const float* ln_g    = (const float*)d_in[17];
    const float* ln_b    = (const float*)d_in[18];

    // d_out: cbuf f32 [NNODES,H] low half (dead before final projection writes)
    float* out  = (float*)d_out;
    float* cbuf = out;

    float* ws = (float*)d_ws;
    size_t o = 0;
    f16* embed_h = (f16*)(ws + o); o += (size_t)NNODES * E / 2;
    f16* hbuf_h  = (f16*)(ws + o); o += (size_t)NNODES * H / 2;
    f16* wiou_h  = (f16*)(ws + o); o += (size_t)H3 * E / 2;
    f16* wf_h    = (f16*)(ws + o); o += (size_t)H * E / 2;
    f16* uf_h    = (f16*)(ws + o); o += (size_t)H * H / 2;
    f16* wih_p   = (f16*)(ws + o); o += (size_t)GUH * H3 / 2;   // gate-interleaved (uh)
    f16* whh_p   = (f16*)(ws + o); o += (size_t)GUH * H3 / 2;   // gate-interleaved (uh)
    f16* fih_p   = (f16*)(ws + o); o += (size_t)GFC * H / 2;    // gate-interleaved (fc)
    f16* fhh_p   = (f16*)(ws + o); o += (size_t)GFC * H / 2;    // gate-interleaved (fc)
    f16* ow_h    = (f16*)(ws + o); o += (size_t)DEC * H / 2;
    f16* fold_p  = (f16*)(ws + o); o += (size_t)GUH * E / 2;    // gate-interleaved (uh)
    float* fold_f = ws + o; o += (size_t)GUH * E;
    float* Ut     = ws + o; o += (size_t)E * H3;
    float* bsu    = ws + o; o += GUH;   // plain bias sum (uh)
    float* bsf    = ws + o; o += GFC;
    float* pbu    = ws + o; o += GUH;   // permuted bias sum (uh)
    float* pbf    = ws + o; o += GFC;   // permuted bias sum (fc)

    // per-chunk f32 words/row:
    // xiou_f 768 + xiou_h 384 + xf_f 256 + xf_h 128 + gbuf 3072 (leaf iou)
    // + hfc0 128 + hfc1 128 + hfc_f 256 + cfc 256 + huh0 384 + huh1 384
    // + h_uh_f 768 + c_uh 768 + fcm_h 512 = 8192
    size_t avail = ws_size / 4;
    long long room = (long long)avail - (long long)o - 8192;
    long long Cl = room / 8192;
    int C;
    if (Cl >= 16384) C = 16384;
    else if (Cl <= 256) C = 256;
    else C = (int)((Cl / 256) * 256);

    float* xiou_f = ws + o; o += (size_t)C * H3;
    f16*   xiou_h = (f16*)(ws + o); o += (size_t)C * H3 / 2;
    float* xf_f   = ws + o; o += (size_t)C * H;
    f16*   xf_h   = (f16*)(ws + o); o += (size_t)C * H / 2;
    float* gbuf   = ws + o; o += (size_t)4 * C * H3;            // leaf iou f32 [4C,768]
    f16*   hfc0   = (f16*)(ws + o); o += (size_t)C * H / 2;     // fc h double buffer
    f16*   hfc1   = (f16*)(ws + o); o += (size_t)C * H / 2;
    float* hfc_f  = ws + o; o += (size_t)C * H;
    float* cfc    = ws + o; o += (size_t)C * H;
    f16*   huh0   = (f16*)(ws + o); o += (size_t)C * H3 / 2;    // uh h double buffer
    f16*   huh1   = (f16*)(ws + o); o += (size_t)C * H3 / 2;
    float* h_uh_f = ws + o; o += (size_t)C * H3;
    float* c_uh   = ws + o; o += (size_t)C * H3;
    f16*   fcm_h  = (f16*)(ws + o); o += (size_t)4 * C * H / 2;

    f16* huh[2] = { huh0, huh1 };
    f16* hfc[2] = { hfc0, hfc1 };

    // ---- prep ----
    auto CVT = [&](const float* s, f16* dv, int n) {
        cvt_f16<<<(n / 4 + 255) / 256, 256, 0, stream>>>(s, dv, n);
    };
    CVT(embed, embed_h, NNODES * E);
    CVT(W_iou_w, wiou_h, H3 * E);
    CVT(W_f_w, wf_h, H * E);
    CVT(U_f_w, uf_h, H * H);
    CVT(out_w, ow_h, DEC * H);
    permute_cvt<<<(GUH * H3 / 4 + 255) / 256, 256, 0, stream>>>(uh_wih, wih_p, H3, H3, GUH * H3 / 4);
    permute_cvt<<<(GUH * H3 / 4 + 255) / 256, 256, 0, stream>>>(uh_whh, whh_p, H3, H3, GUH * H3 / 4);
    permute_cvt<<<(GFC * H / 4 + 255) / 256, 256, 0, stream>>>(fc_wih, fih_p, H, H, GFC * H / 4);
    permute_cvt<<<(GFC * H / 4 + 255) / 256, 256, 0, stream>>>(fc_whh, fhh_p, H, H, GFC * H / 4);
    bias_sum<<<(GUH + 255) / 256, 256, 0, stream>>>(uh_bih, uh_bhh, bsu, GUH);
    bias_sum<<<(GFC + 255) / 256, 256, 0, stream>>>(fc_bih, fc_bhh, bsf, GFC);
    permute_bias<<<(GUH + 255) / 256, 256, 0, stream>>>(bsu, pbu, H3, GUH);
    permute_bias<<<(GFC + 255) / 256, 256, 0, stream>>>(bsf, pbf, H, GFC);
    transpose_f32<<<(H3 * E + 255) / 256, 256, 0, stream>>>(U_iou_w, Ut);
    {   // folded = uh_wih @ U_iou_w (f32), then permute+cast
        dim3 grid(E / 128, GUH / 128);
        gemm_nt_f32<<<grid, 256, 0, stream>>>(uh_wih, H3, Ut, H3, fold_f, E, GUH, E, H3);
        permute_cvt<<<(GUH * E / 4 + 255) / 256, 256, 0, stream>>>(fold_f, fold_p, H3, E, GUH * E / 4);
    }

    auto G0 = [&](const GArg& a, int nx, int ny) {
        gemm_one<0><<<dim3(nx, ny), 256, 0, stream>>>(a);
    };

    // ---- leaves ----
    for (int ls = 0; ls < NLEAF; ls += 4 * C) {
        int Ln = NLEAF - ls < 4 * C ? NLEAF - ls : 4 * C;
        GArg a{};
        a.A0 = embed_h + (size_t)(LEAF0 + ls) * E; a.la0 = E;
        a.B0 = wiou_h; a.lb0 = E; a.K0 = E;
        a.bias = W_iou_b; a.Cf = gbuf; a.ldc = H3; a.M = Ln; a.N = H3;
        G0(a, H3 / 128, (Ln + 127) / 128);
        leaf_apply<<<(Ln * 64 + 255) / 256, 256, 0, stream>>>(
            gbuf, hbuf_h + (size_t)(LEAF0 + ls) * H, cbuf + (size_t)(LEAF0 + ls) * H, Ln);
    }

    // ---- levels, deepest internal -> root ----
    const int counts[8] = { 1, 4, 16, 64, 256, 1024, 4096, 16384 };
    const int offs[8]   = { 0, 1, 5, 21, 85, 341, 1365, 5461 };
    for (int d = 7; d >= 0; --d) {
        int n = counts[d], start = offs[d];
        for (int s = 0; s < n; s += C) {
            int Cn = n - s < C ? n - s : C;
            int sa = start + s;
            int cst = 4 * sa + 1;
            int Mb = (Cn + 127) / 128;

            // x projections (f32 master + f16 shadow)
            {
                GArg u{};
                u.A0 = embed_h + (size_t)sa * E; u.la0 = E;
                u.B0 = wiou_h; u.lb0 = E; u.K0 = E;
                u.bias = W_iou_b; u.Cf = xiou_f; u.Ch = xiou_h; u.ldc = H3;
                u.M = Cn; u.N = H3;
                G0(u, H3 / 128, Mb);
                GArg f = u;
                f.B0 = wf_h; f.bias = W_f_b; f.Cf = xf_f; f.Ch = xf_h; f.ldc = H; f.N = H;
                G0(f, H / 128, Mb);
            }
            // fc messages (GEMM + fc_msg fused; x_f read from f32 master)
            {
                GArg a{};
                a.A0 = hbuf_h + (size_t)cst * H; a.la0 = H;
                a.B0 = uf_h; a.lb0 = H; a.K0 = H;
                a.xff = xf_f; a.cch = cbuf + (size_t)cst * H; a.fcm = fcm_h;
                a.M = 4 * Cn; a.N = H;
                gemm_one<2><<<dim3(H / 128, (4 * Cn + 127) / 128), 256, 0, stream>>>(a);
            }
            // 6 LSTM steps, both LSTMs fused (EPI-1), h double-buffered:
            // step t reads h[(t+1)&1], writes h[t&1] (disjoint -> no RAW race)
            for (int t = 0; t <= 5; ++t) {
                int wb = t & 1, rb = (t + 1) & 1;

                GArg u{};
                u.bias = pbu; u.cb = c_uh; u.hb = huh[wb]; u.HH = H3;
                u.M = Cn; u.N = GUH;
                if (t == 5) u.hf = h_uh_f;
                if (t == 0) {
                    u.A0 = xiou_h; u.la0 = H3; u.B0 = wih_p; u.lb0 = H3; u.K0 = H3;
                    u.init = 1;
                } else if (t <= 4) {
                    u.A0 = hbuf_h + (size_t)(cst + t - 1) * H; u.la0 = 4 * H;
                    u.B0 = fold_p; u.lb0 = E; u.K0 = E;
                    u.A1 = huh[rb]; u.la1 = H3; u.B1 = whh_p; u.lb1 = H3; u.K1 = H3;
                } else {
                    u.A0 = xiou_h; u.la0 = H3; u.B0 = wih_p; u.lb0 = H3; u.K0 = H3;
                    u.A1 = huh[rb]; u.la1 = H3; u.B1 = whh_p; u.lb1 = H3; u.K1 = H3;
                }
                gemm_one<1><<<dim3(GUH / 128, Mb), 256, 0, stream>>>(u);

                GArg f{};
                f.bias = pbf; f.cb = cfc; f.hb = hfc[wb]; f.HH = H;
                f.M = Cn; f.N = GFC;
                if (t == 5) f.hf = hfc_f;
                if (t == 0) {
                    f.A0 = xf_h; f.la0 = H; f.B0 = fih_p; f.lb0 = H; f.K0 = H;
                    f.init = 1;
                } else if (t <= 4) {
                    f.A0 = fcm_h + (size_t)(t - 1) * H; f.la0 = 4 * H;
                    f.B0 = fih_p; f.lb0 = H; f.K0 = H;
                    f.A1 = hfc[rb]; f.la1 = H; f.B1 = fhh_p; f.lb1 = H; f.K1 = H;
                } else {
                    f.A0 = xf_h; f.la0 = H; f.B0 = fih_p; f.lb0 = H; f.K0 = H;
                    f.A1 = hfc[rb]; f.la1 = H; f.B1 = fhh_p; f.lb1 = H; f.K1 = H;
                }
                gemm_one<1><<<dim3(GFC / 128, Mb), 256, 0, stream>>>(f);
            }
            // apply node func (f32 masters in)
            node_apply<<<(Cn * 64 + 255) / 256, 256, 0, stream>>>(
                xiou_f, h_uh_f, hfc_f,
                hbuf_h + (size_t)sa * H, cbuf + (size_t)sa * H, Cn);
        }
    }

    // ---- output projection (reads only ws; cbuf is dead) + LN/tanh ----
    {
        GArg a{};
        a.A0 = hbuf_h; a.la0 = H; a.B0 = ow_h; a.lb0 = H; a.K0 = H;
        a.bias = out_b; a.Cf = out; a.ldc = DEC; a.M = NNODES; a.N = DEC;
        G0(a, DEC / 128, (NNODES + 127) / 128);
    }
    ln_tanh<<<(NNODES + 3) / 4, 256, 0, stream>>>(out, ln_g, ln_b, NNODES);
}

// Round 16
// 4200.396 us; speedup vs baseline: 6.2492x; 1.1110x over previous
//
#include <hip/hip_runtime.h>
#include <math.h>
#include <cstddef>

// ---------------- constants ----------------
constexpr int E = 256, H = 256, H3 = 768;
constexpr int GUH = 3072, GFC = 1024, DEC = 512;
constexpr int NNODES = 87381, LEAF0 = 21845, NLEAF = 65536;

using f16 = _Float16;
typedef __attribute__((ext_vector_type(8))) _Float16 f16x8;
typedef __attribute__((ext_vector_type(4))) _Float16 f16x4;
typedef __attribute__((ext_vector_type(4))) float f32x4;
typedef unsigned int u32;
typedef __attribute__((address_space(1))) const u32 gu32;
typedef __attribute__((address_space(3))) u32 lu32;

// fast transcendentals: v_exp_f32 / v_rcp_f32 based, ~1e-6 rel err
static __device__ __forceinline__ float frcp(float x) { return __builtin_amdgcn_rcpf(x); }
static __device__ __forceinline__ float sigf(float x) { return frcp(1.0f + __expf(-x)); }
static __device__ __forceinline__ float tanh_f(float x) {
    float e = __expf(fminf(2.0f * x, 30.0f));   // clamp avoids inf/inf
    return (e - 1.0f) * frcp(e + 1.0f);
}
static __device__ __forceinline__ void gload16(const void* g, void* l) {
    __builtin_amdgcn_global_load_lds((gu32*)g, (lu32*)l, 16, 0, 0);
}

// ---------------- fused MFMA NT GEMM (single GArg per launch; inline body —
// LDS dest of global_load_lds MUST stay in-scope of the __shared__ decl) ----
// out[m,n] = sum_k A0[m,k]B0[n,k] + sum_k A1[m,k]B1[n,k]  (K0/K1 mult of 32)
// EPI 0: +bias -> Cf f32 / Ch f16 (either or both)
// EPI 1: LSTM cell. B rows gate-interleaved: row m <-> gate=(m>>4)&3,
//        unit=(m>>7)*32+((m>>6)&1)*16+(m&15). Fragment j == gate. Writes
//        c (f32), h (f16), optional h f32 master.
//        RACE SAFETY: hb must differ from every A input (h double-buffered).
// EPI 2: fc-message: fcm[r,col] = cch[r,col] * sigmoid(xff[r>>2,col] + acc)
// A rows clamped to M-1 during staging. LDS bank-conflict swizzle: chunk
// c_phys = c_logical ^ ((row>>1)&3) on source addr and read addr.
// XCD-aware bijective block swizzle (m204): order-only, correctness-neutral.
struct GArg {
    const f16 *A0 = nullptr, *B0 = nullptr, *A1 = nullptr, *B1 = nullptr;
    int la0 = 0, lb0 = 0, K0 = 0, la1 = 0, lb1 = 0, K1 = 0;
    const float* bias = nullptr;
    float* Cf = nullptr; f16* Ch = nullptr; int ldc = 0;              // EPI 0
    float* cb = nullptr; f16* hb = nullptr; float* hf = nullptr;     // EPI 1
    int HH = 0; int init = 0;                                        // EPI 1
    const float* xff = nullptr; const float* cch = nullptr; f16* fcm = nullptr; // EPI 2
    int M = 0, N = 0;
};

template<int EPI>
__global__ __launch_bounds__(256) void gemm_one(GArg a)
{
    __shared__ f16 As[2][128 * 32];
    __shared__ f16 Bs[2][128 * 32];
    const int tid = threadIdx.x;

    // XCD-aware bijective swizzle of the linear block id (m204)
    const int gX = gridDim.x;
    const int nwg = gX * gridDim.y;
    const int orig = blockIdx.y * gX + blockIdx.x;
    const int q = nwg >> 3, r = nwg & 7;
    const int xcd = orig & 7, rem = orig >> 3;
    const int wgid = (xcd < r ? xcd * (q + 1) : r * (q + 1) + (xcd - r) * q) + rem;
    const int bx = wgid % gX, by = wgid / gX;

    const int m0 = by * 128, n0 = bx * 128;
    const int wave = tid >> 6, lane = tid & 63;
    const int wm = (wave >> 1) * 64, wn = (wave & 1) * 64;
    const int lr = lane & 15, kg = lane >> 4;
    const int px = kg ^ ((lr >> 1) & 3);   // swizzled chunk for fragment reads

    f32x4 acc[4][4];
#pragma unroll
    for (int i = 0; i < 4; ++i)
#pragma unroll
        for (int j = 0; j < 4; ++j) acc[i][j] = (f32x4){0.f, 0.f, 0.f, 0.f};

    const int nt1 = a.K0 >> 5;
    const int nt = nt1 + (a.K1 >> 5);

    auto stage = [&](int t, int b) {
        const f16* Ap; const f16* Bp; int la, lb, k0;
        if (t < nt1) { Ap = a.A0; Bp = a.B0; la = a.la0; lb = a.lb0; k0 = t * 32; }
        else         { Ap = a.A1; Bp = a.B1; la = a.la1; lb = a.lb1; k0 = (t - nt1) * 32; }
#pragma unroll
        for (int v = 0; v < 2; ++v) {
            int idx = v * 256 + tid;
            int row = idx >> 2, cph = idx & 3;
            int clog = cph ^ ((row >> 1) & 3);     // inverse swizzle on source
            int ar = m0 + row;                     // clamp A rows
            if (ar >= a.M) ar = a.M - 1;
            gload16(Ap + (size_t)ar * la + k0 + clog * 8, &As[b][idx * 8]);
            gload16(Bp + (size_t)(n0 + row) * lb + k0 + clog * 8, &Bs[b][idx * 8]);
        }
    };

    stage(0, 0);
    for (int t = 0; t < nt; ++t) {
        __syncthreads();                  // compiler drains vmcnt before barrier
        if (t + 1 < nt) stage(t + 1, (t + 1) & 1);
        const f16* as = As[t & 1];
        const f16* bs = Bs[t & 1];
        f16x8 af[4], bfr[4];
#pragma unroll
        for (int i = 0; i < 4; ++i) {
            af[i]  = *(const f16x8*)&as[(wm + i * 16 + lr) * 32 + px * 8];
            bfr[i] = *(const f16x8*)&bs[(wn + i * 16 + lr) * 32 + px * 8];
        }
#pragma unroll
        for (int i = 0; i < 4; ++i)
#pragma unroll
            for (int j = 0; j < 4; ++j)
                acc[i][j] = __builtin_amdgcn_mfma_f32_16x16x32_f16(af[i], bfr[j], acc[i][j], 0, 0, 0);
    }

    // D: col = lane&15, row = (lane>>4)*4 + r
    if constexpr (EPI == 0) {
#pragma unroll
        for (int i = 0; i < 4; ++i)
#pragma unroll
            for (int j = 0; j < 4; ++j) {
                int col = n0 + wn + j * 16 + lr;
                float bv = a.bias ? a.bias[col] : 0.f;
#pragma unroll
                for (int r = 0; r < 4; ++r) {
                    int rowg = m0 + wm + i * 16 + kg * 4 + r;
                    if (rowg < a.M) {
                        float v = acc[i][j][r] + bv;
                        if (a.Cf) a.Cf[(size_t)rowg * a.ldc + col] = v;
                        if (a.Ch) a.Ch[(size_t)rowg * a.ldc + col] = (f16)v;
                    }
                }
            }
    } else if constexpr (EPI == 1) {
        // unit index for this lane; fragment j is the gate (i,f,g,o)
        int ub = (n0 >> 2) + (wave & 1) * 16 + lr;
        float b0 = a.bias[n0 + wn + lr];
        float b1 = a.bias[n0 + wn + 16 + lr];
        float b2 = a.bias[n0 + wn + 32 + lr];
        float b3 = a.bias[n0 + wn + 48 + lr];
#pragma unroll
        for (int i = 0; i < 4; ++i)
#pragma unroll
            for (int r = 0; r < 4; ++r) {
                int rowg = m0 + wm + i * 16 + kg * 4 + r;
                if (rowg < a.M) {
                    float gi = acc[i][0][r] + b0;
                    float gf = acc[i][1][r] + b1;
                    float gg = acc[i][2][r] + b2;
                    float go = acc[i][3][r] + b3;
                    size_t off = (size_t)rowg * a.HH + ub;
                    float cn = sigf(gi) * tanh_f(gg);
                    if (!a.init) cn = fmaf(sigf(gf), a.cb[off], cn);
                    a.cb[off] = cn;
                    float hv = sigf(go) * tanh_f(cn);
                    a.hb[off] = (f16)hv;
                    if (a.hf) a.hf[off] = hv;     // f32 master (final step)
                }
            }
    } else {
#pragma unroll
        for (int i = 0; i < 4; ++i)
#pragma unroll
            for (int j = 0; j < 4; ++j) {
                int col = n0 + wn + j * 16 + lr;
#pragma unroll
                for (int r = 0; r < 4; ++r) {
                    int rowg = m0 + wm + i * 16 + kg * 4 + r;
                    if (rowg < a.M) {
                        float xv = a.xff[(size_t)(rowg >> 2) * H + col];
                        float cv = a.cch[(size_t)rowg * H + col];
                        a.fcm[(size_t)rowg * H + col] =
                            (f16)(cv * sigf(xv + acc[i][j][r]));
                    }
                }
            }
    }
}

// ---------------- f32 tiled NT GEMM (prep only: folded weight) ----------------
__global__ __launch_bounds__(256) void gemm_nt_f32(
    const float* __restrict__ A, int lda,
    const float* __restrict__ B, int ldb,
    float* __restrict__ C, int ldc, int M, int N, int K)
{
    __shared__ float As[16][128];
    __shared__ float Bs[16][128];
    const int m0 = blockIdx.y * 128, n0 = blockIdx.x * 128;
    const int tid = threadIdx.x;
    const int tx = tid & 15, ty = tid >> 4;
    float acc[8][8];
#pragma unroll
    for (int i = 0; i < 8; ++i)
#pragma unroll
        for (int j = 0; j < 8; ++j) acc[i][j] = 0.0f;
    for (int k0 = 0; k0 < K; k0 += 16) {
#pragma unroll
        for (int v = 0; v < 2; ++v) {
            int idx = tid + v * 256;
            int row = idx >> 2, c4 = idx & 3;
            float4 av = make_float4(0, 0, 0, 0);
            int gm = m0 + row;
            if (gm < M) av = *(const float4*)&A[(size_t)gm * lda + k0 + c4 * 4];
            As[c4 * 4 + 0][row] = av.x; As[c4 * 4 + 1][row] = av.y;
            As[c4 * 4 + 2][row] = av.z; As[c4 * 4 + 3][row] = av.w;
            float4 bv = make_float4(0, 0, 0, 0);
            int gn = n0 + row;
            if (gn < N) bv = *(const float4*)&B[(size_t)gn * ldb + k0 + c4 * 4];
            Bs[c4 * 4 + 0][row] = bv.x; Bs[c4 * 4 + 1][row] = bv.y;
            Bs[c4 * 4 + 2][row] = bv.z; Bs[c4 * 4 + 3][row] = bv.w;
        }
        __syncthreads();
#pragma unroll
        for (int kk = 0; kk < 16; ++kk) {
            float4 a0 = *(const float4*)&As[kk][ty * 8];
            float4 a1 = *(const float4*)&As[kk][ty * 8 + 4];
            float4 b0 = *(const float4*)&Bs[kk][tx * 8];
            float4 b1 = *(const float4*)&Bs[kk][tx * 8 + 4];
            float av[8] = { a0.x,a0.y,a0.z,a0.w,a1.x,a1.y,a1.z,a1.w };
            float bv[8] = { b0.x,b0.y,b0.z,b0.w,b1.x,b1.y,b1.z,b1.w };
#pragma unroll
            for (int i = 0; i < 8; ++i)
#pragma unroll
                for (int j = 0; j < 8; ++j)
                    acc[i][j] = fmaf(av[i], bv[j], acc[i][j]);
        }
        __syncthreads();
    }
#pragma unroll
    for (int i = 0; i < 8; ++i) {
        int gm = m0 + ty * 8 + i;
        if (gm >= M) break;
#pragma unroll
        for (int j = 0; j < 8; ++j) {
            int gn = n0 + tx * 8 + j;
            if (gn < N) C[(size_t)gm * ldc + gn] = acc[i][j];
        }
    }
}

// ---------------- elementwise / prep kernels ----------------

// leaves: iou f32 [count,768] -> h f16, c f32 (pointers pre-offset)
__global__ __launch_bounds__(256) void leaf_apply(
    const float* __restrict__ iou, f16* __restrict__ hh, float* __restrict__ c,
    int count)
{
    int idx = blockIdx.x * 256 + threadIdx.x;
    int tot = count * (H / 4);
    if (idx >= tot) return;
    int row = idx >> 6;
    int c4 = (idx & 63) * 4;
    const float* r = iou + (size_t)row * H3;
    float4 vi = *(const float4*)&r[c4];
    float4 vo = *(const float4*)&r[H + c4];
    float4 vu = *(const float4*)&r[2 * H + c4];
    float ia[4] = { vi.x,vi.y,vi.z,vi.w }, oa[4] = { vo.x,vo.y,vo.z,vo.w }, ua[4] = { vu.x,vu.y,vu.z,vu.w };
    size_t off = (size_t)row * H + c4;
    float cc[4]; f16x4 hq;
#pragma unroll
    for (int j = 0; j < 4; ++j) {
        cc[j] = sigf(ia[j]) * tanh_f(ua[j]);
        hq[j] = (f16)(sigf(oa[j]) * tanh_f(cc[j]));
    }
    *(float4*)&c[off] = make_float4(cc[0], cc[1], cc[2], cc[3]);
    *(f16x4*)&hh[off] = hq;
}

// internal apply: f32 masters in; h f16 + c f32 out (pointers pre-offset)
__global__ __launch_bounds__(256) void node_apply(
    const float* __restrict__ xiou, const float* __restrict__ h_uh,
    const float* __restrict__ hfc, f16* __restrict__ hh, float* __restrict__ c,
    int Cn)
{
    int idx = blockIdx.x * 256 + threadIdx.x;
    int tot = Cn * (H / 4);
    if (idx >= tot) return;
    int row = idx >> 6;
    int c4 = (idx & 63) * 4;
    const float* xr = xiou + (size_t)row * H3;
    const float* ur = h_uh + (size_t)row * H3;
    float4 xi = *(const float4*)&xr[c4];
    float4 xo = *(const float4*)&xr[H + c4];
    float4 xu = *(const float4*)&xr[2 * H + c4];
    float4 ui = *(const float4*)&ur[c4];
    float4 uo = *(const float4*)&ur[H + c4];
    float4 uu = *(const float4*)&ur[2 * H + c4];
    float4 fv = *(const float4*)&hfc[(size_t)row * H + c4];
    float xia[4] = { xi.x,xi.y,xi.z,xi.w }, xoa[4] = { xo.x,xo.y,xo.z,xo.w }, xua[4] = { xu.x,xu.y,xu.z,xu.w };
    float uia[4] = { ui.x,ui.y,ui.z,ui.w }, uoa[4] = { uo.x,uo.y,uo.z,uo.w }, uua[4] = { uu.x,uu.y,uu.z,uu.w };
    float fva[4] = { fv.x,fv.y,fv.z,fv.w };
    size_t off = (size_t)row * H + c4;
    float cc[4]; f16x4 hq;
#pragma unroll
    for (int j = 0; j < 4; ++j) {
        float iv = xia[j] + uia[j];
        float ov = xoa[j] + uoa[j];
        float uv = xua[j] + uua[j];
        float cv = sigf(iv) * tanh_f(uv) + fva[j];
        cc[j] = cv;
        hq[j] = (f16)(sigf(ov) * tanh_f(cv));
    }
    *(float4*)&c[off] = make_float4(cc[0], cc[1], cc[2], cc[3]);
    *(f16x4*)&hh[off] = hq;
}

__global__ __launch_bounds__(256) void bias_sum(
    const float* __restrict__ a, const float* __restrict__ b, float* __restrict__ o, int n)
{
    int i = blockIdx.x * 256 + threadIdx.x;
    if (i < n) o[i] = a[i] + b[i];
}

__global__ __launch_bounds__(256) void cvt_f16(
    const float* __restrict__ in, f16* __restrict__ out, int n)
{
    int idx = blockIdx.x * 256 + threadIdx.x;
    if (idx * 4 >= n) return;
    float4 v = *(const float4*)&in[idx * 4];
    f16x4 o; o[0] = (f16)v.x; o[1] = (f16)v.y; o[2] = (f16)v.z; o[3] = (f16)v.w;
    *(f16x4*)&out[idx * 4] = o;
}

// gate-interleave row permutation + f32->f16:  dst[m,:] = src[gate*HH+unit,:]
__global__ __launch_bounds__(256) void permute_cvt(
    const float* __restrict__ src, f16* __restrict__ dst, int HH, int K, int tot4)
{
    int idx = blockIdx.x * 256 + threadIdx.x;
    if (idx >= tot4) return;
    int kq = K >> 2;
    int m = idx / kq;
    int k4 = (idx - m * kq) * 4;
    int gate = (m >> 4) & 3;
    int unit = (m >> 7) * 32 + ((m >> 6) & 1) * 16 + (m & 15);
    float4 v = *(const float4*)&src[(size_t)(gate * HH + unit) * K + k4];
    f16x4 o; o[0] = (f16)v.x; o[1] = (f16)v.y; o[2] = (f16)v.z; o[3] = (f16)v.w;
    *(f16x4*)&dst[(size_t)m * K + k4] = o;
}

__global__ __launch_bounds__(256) void permute_bias(
    const float* __restrict__ src, float* __restrict__ dst, int HH, int n)
{
    int m = blockIdx.x * 256 + threadIdx.x;
    if (m >= n) return;
    int gate = (m >> 4) & 3;
    int unit = (m >> 7) * 32 + ((m >> 6) & 1) * 16 + (m & 15);
    dst[m] = src[gate * HH + unit];
}

// U_iou_w f32 [768,256] -> f32 [256,768] transpose
__global__ __launch_bounds__(256) void transpose_f32(
    const float* __restrict__ in, float* __restrict__ out)
{
    int idx = blockIdx.x * 256 + threadIdx.x;
    if (idx >= H3 * E) return;
    int r = idx >> 8, c = idx & 255;
    out[(size_t)c * H3 + r] = in[idx];
}

// LayerNorm(512)+tanh in-place, one wave per row
__global__ __launch_bounds__(256) void ln_tanh(
    float* __restrict__ y, const float* __restrict__ g, const float* __restrict__ b,
    int Nrows)
{
    int wave = threadIdx.x >> 6;
    int lane = threadIdx.x & 63;
    int row = blockIdx.x * 4 + wave;
    if (row >= Nrows) return;
    float* yr = y + (size_t)row * DEC;
    float4 v0 = *(const float4*)&yr[lane * 8];
    float4 v1 = *(const float4*)&yr[lane * 8 + 4];
    float s = v0.x + v0.y + v0.z + v0.w + v1.x + v1.y + v1.z + v1.w;
    float s2 = v0.x * v0.x + v0.y * v0.y + v0.z * v0.z + v0.w * v0.w +
               v1.x * v1.x + v1.y * v1.y + v1.z * v1.z + v1.w * v1.w;
#pragma unroll
    for (int off = 32; off; off >>= 1) {
        s += __shfl_xor(s, off);
        s2 += __shfl_xor(s2, off);
    }
    float m = s * (1.0f / DEC);
    float var = s2 * (1.0f / DEC) - m * m;
    float rstd = rsqrtf(var + 1e-5f);
    float vals[8] = { v0.x,v0.y,v0.z,v0.w,v1.x,v1.y,v1.z,v1.w };
    float o[8];
#pragma unroll
    for (int j = 0; j < 8; ++j) {
        int colj = lane * 8 + j;
        o[j] = tanh_f((vals[j] - m) * rstd * g[colj] + b[colj]);
    }
    *(float4*)&yr[lane * 8] = make_float4(o[0], o[1], o[2], o[3]);
    *(float4*)&yr[lane * 8 + 4] = make_float4(o[4], o[5], o[6], o[7]);
}

// ---------------- host ----------------
extern "C" void kernel_launch(void* const* d_in, const int* in_sizes, int n_in,
                              void* d_out, int out_size, void* d_ws, size_t ws_size,
                              hipStream_t stream)
{
    (void)in_sizes; (void)n_in; (void)out_size;
    const float* embed   = (const float*)d_in[0];
    const float* W_iou_w = (const float*)d_in[1];
    const float* W_iou_b = (const float*)d_in[2];
    const float* U_iou_w = (const float*)d_in[3];
    const float* W_f_w   = (const float*)d_in[4];
    const float* W_f_b   = (const float*)d_in[5];
    const float* U_f_w   = (const float*)d_in[6];
    const float* uh_wih  = (const float*)d_in[7];
    const float* uh_whh  = (const float*)d_in[8];
    const float* uh_bih  = (const float*)d_in[9];
    const float* uh_bhh  = (const float*)d_in[10];
    const float* fc_wih  = (const float*)d_in[11];
    const float* fc_whh  = (const float*)d_in[12];
    const float* fc_bih  = (const float*)d_in[13];
    const float* fc_bhh  = (const float*)d_in[14];
    const float* out_w   = (const float*)d_in[15];
    const float* out_b   = (const float*)d_in[16];
    const float* ln_g    = (const float*)d_in[17];
    const float* ln_b    = (const float*)d_in[18];

    // d_out: cbuf f32 [NNODES,H] low half (dead before final projection writes)
    float* out  = (float*)d_out;
    float* cbuf = out;

    float* ws = (float*)d_ws;
    size_t o = 0;
    f16* embed_h = (f16*)(ws + o); o += (size_t)NNODES * E / 2;
    f16* hbuf_h  = (f16*)(ws + o); o += (size_t)NNODES * H / 2;
    f16* wiou_h  = (f16*)(ws + o); o += (size_t)H3 * E / 2;
    f16* wf_h    = (f16*)(ws + o); o += (size_t)H * E / 2;
    f16* uf_h    = (f16*)(ws + o); o += (size_t)H * H / 2;
    f16* wih_p   = (f16*)(ws + o); o += (size_t)GUH * H3 / 2;   // gate-interleaved (uh)
    f16* whh_p   = (f16*)(ws + o); o += (size_t)GUH * H3 / 2;   // gate-interleaved (uh)
    f16* fih_p   = (f16*)(ws + o); o += (size_t)GFC * H / 2;    // gate-interleaved (fc)
    f16* fhh_p   = (f16*)(ws + o); o += (size_t)GFC * H / 2;    // gate-interleaved (fc)
    f16* ow_h    = (f16*)(ws + o); o += (size_t)DEC * H / 2;
    f16* fold_p  = (f16*)(ws + o); o += (size_t)GUH * E / 2;    // gate-interleaved (uh)
    float* fold_f = ws + o; o += (size_t)GUH * E;
    float* Ut     = ws + o; o += (size_t)E * H3;
    float* bsu    = ws + o; o += GUH;
    float* bsf    = ws + o; o += GFC;
    float* pbu    = ws + o; o += GUH;   // permuted bias sum (uh)
    float* pbf    = ws + o; o += GFC;   // permuted bias sum (fc)

    // per-chunk f32 words/row:
    // xiou_f 768 + xiou_h 384 + xf_f 256 + xf_h 128 + gbuf 3072 (leaf iou)
    // + hfc0 128 + hfc1 128 + hfc_f 256 + cfc 256 + huh0 384 + huh1 384
    // + h_uh_f 768 + c_uh 768 + fcm_h 512 = 8192
    size_t avail = ws_size / 4;
    long long room = (long long)avail - (long long)o - 8192;
    long long Cl = room / 8192;
    int C;
    if (Cl >= 16384) C = 16384;
    else if (Cl <= 256) C = 256;
    else C = (int)((Cl / 256) * 256);

    float* xiou_f = ws + o; o += (size_t)C * H3;
    f16*   xiou_h = (f16*)(ws + o); o += (size_t)C * H3 / 2;
    float* xf_f   = ws + o; o += (size_t)C * H;
    f16*   xf_h   = (f16*)(ws + o); o += (size_t)C * H / 2;
    float* gbuf   = ws + o; o += (size_t)4 * C * H3;            // leaf iou f32 [4C,768]
    f16*   hfc0   = (f16*)(ws + o); o += (size_t)C * H / 2;     // fc h double buffer
    f16*   hfc1   = (f16*)(ws + o); o += (size_t)C * H / 2;
    float* hfc_f  = ws + o; o += (size_t)C * H;
    float* cfc    = ws + o; o += (size_t)C * H;
    f16*   huh0   = (f16*)(ws + o); o += (size_t)C * H3 / 2;    // uh h double buffer
    f16*   huh1   = (f16*)(ws + o); o += (size_t)C * H3 / 2;
    float* h_uh_f = ws + o; o += (size_t)C * H3;
    float* c_uh   = ws + o; o += (size_t)C * H3;
    f16*   fcm_h  = (f16*)(ws + o); o += (size_t)4 * C * H / 2;

    f16* huh[2] = { huh0, huh1 };
    f16* hfc[2] = { hfc0, hfc1 };

    // ---- prep ----
    auto CVT = [&](const float* s, f16* dv, int n) {
        cvt_f16<<<(n / 4 + 255) / 256, 256, 0, stream>>>(s, dv, n);
    };
    CVT(embed, embed_h, NNODES * E);
    CVT(W_iou_w, wiou_h, H3 * E);
    CVT(W_f_w, wf_h, H * E);
    CVT(U_f_w, uf_h, H * H);
    CVT(out_w, ow_h, DEC * H);
    permute_cvt<<<(GUH * H3 / 4 + 255) / 256, 256, 0, stream>>>(uh_wih, wih_p, H3, H3, GUH * H3 / 4);
    permute_cvt<<<(GUH * H3 / 4 + 255) / 256, 256, 0, stream>>>(uh_whh, whh_p, H3, H3, GUH * H3 / 4);
    permute_cvt<<<(GFC * H / 4 + 255) / 256, 256, 0, stream>>>(fc_wih, fih_p, H, H, GFC * H / 4);
    permute_cvt<<<(GFC * H / 4 + 255) / 256, 256, 0, stream>>>(fc_whh, fhh_p, H, H, GFC * H / 4);
    bias_sum<<<(GUH + 255) / 256, 256, 0, stream>>>(uh_bih, uh_bhh, bsu, GUH);
    bias_sum<<<(GFC + 255) / 256, 256, 0, stream>>>(fc_bih, fc_bhh, bsf, GFC);
    permute_bias<<<(GUH + 255) / 256, 256, 0, stream>>>(bsu, pbu, H3, GUH);
    permute_bias<<<(GFC + 255) / 256, 256, 0, stream>>>(bsf, pbf, H, GFC);
    transpose_f32<<<(H3 * E + 255) / 256, 256, 0, stream>>>(U_iou_w, Ut);
    {   // folded = uh_wih @ U_iou_w (f32), then permute+cast
        dim3 grid(E / 128, GUH / 128);
        gemm_nt_f32<<<grid, 256, 0, stream>>>(uh_wih, H3, Ut, H3, fold_f, E, GUH, E, H3);
        permute_cvt<<<(GUH * E / 4 + 255) / 256, 256, 0, stream>>>(fold_f, fold_p, H3, E, GUH * E / 4);
    }

    // ---- leaves ----
    for (int ls = 0; ls < NLEAF; ls += 4 * C) {
        int Ln = NLEAF - ls < 4 * C ? NLEAF - ls : 4 * C;
        GArg a{};
        a.A0 = embed_h + (size_t)(LEAF0 + ls) * E; a.la0 = E;
        a.B0 = wiou_h; a.lb0 = E; a.K0 = E;
        a.bias = W_iou_b; a.Cf = gbuf; a.ldc = H3; a.M = Ln; a.N = H3;
        gemm_one<0><<<dim3(H3 / 128, (Ln + 127) / 128), 256, 0, stream>>>(a);
        leaf_apply<<<(Ln * 64 + 255) / 256, 256, 0, stream>>>(
            gbuf, hbuf_h + (size_t)(LEAF0 + ls) * H, cbuf + (size_t)(LEAF0 + ls) * H, Ln);
    }

    // ---- levels, deepest internal -> root ----
    const int counts[8] = { 1, 4, 16, 64, 256, 1024, 4096, 16384 };
    const int offs[8]   = { 0, 1, 5, 21, 85, 341, 1365, 5461 };
    for (int d = 7; d >= 0; --d) {
        int n = counts[d], start = offs[d];
        for (int s = 0; s < n; s += C) {
            int Cn = n - s < C ? n - s : C;
            int sa = start + s;
            int cst = 4 * sa + 1;
            int Mb = (Cn + 127) / 128;

            // x projections (f32 master + f16 shadow)
            {
                GArg u{};
                u.A0 = embed_h + (size_t)sa * E; u.la0 = E;
                u.B0 = wiou_h; u.lb0 = E; u.K0 = E;
                u.bias = W_iou_b; u.Cf = xiou_f; u.Ch = xiou_h; u.ldc = H3;
                u.M = Cn; u.N = H3;
                gemm_one<0><<<dim3(H3 / 128, Mb), 256, 0, stream>>>(u);
                GArg f = u;
                f.B0 = wf_h; f.bias = W_f_b; f.Cf = xf_f; f.Ch = xf_h; f.ldc = H; f.N = H;
                gemm_one<0><<<dim3(H / 128, Mb), 256, 0, stream>>>(f);
            }
            // fc messages (GEMM + fc_msg fused; x_f read from f32 master)
            {
                GArg a{};
                a.A0 = hbuf_h + (size_t)cst * H; a.la0 = H;
                a.B0 = uf_h; a.lb0 = H; a.K0 = H;
                a.xff = xf_f; a.cch = cbuf + (size_t)cst * H; a.fcm = fcm_h;
                a.M = 4 * Cn; a.N = H;
                gemm_one<2><<<dim3(H / 128, (4 * Cn + 127) / 128), 256, 0, stream>>>(a);
            }
            // 6 LSTM steps, both LSTMs fused (EPI-1), h double-buffered:
            // step t reads h[(t+1)&1], writes h[t&1] (disjoint -> no RAW race)
            for (int t = 0; t <= 5; ++t) {
                int wb = t & 1, rb = (t + 1) & 1;

                GArg u{};
                u.bias = pbu; u.cb = c_uh; u.hb = huh[wb]; u.HH = H3;
                u.M = Cn; u.N = GUH;
                if (t == 5) u.hf = h_uh_f;
                if (t == 0) {
                    u.A0 = xiou_h; u.la0 = H3; u.B0 = wih_p; u.lb0 = H3; u.K0 = H3;
                    u.init = 1;
                } else if (t <= 4) {
                    u.A0 = hbuf_h + (size_t)(cst + t - 1) * H; u.la0 = 4 * H;
                    u.B0 = fold_p; u.lb0 = E; u.K0 = E;
                    u.A1 = huh[rb]; u.la1 = H3; u.B1 = whh_p; u.lb1 = H3; u.K1 = H3;
                } else {
                    u.A0 = xiou_h; u.la0 = H3; u.B0 = wih_p; u.lb0 = H3; u.K0 = H3;
                    u.A1 = huh[rb]; u.la1 = H3; u.B1 = whh_p; u.lb1 = H3; u.K1 = H3;
                }
                gemm_one<1><<<dim3(GUH / 128, Mb), 256, 0, stream>>>(u);

                GArg f{};
                f.bias = pbf; f.cb = cfc; f.hb = hfc[wb]; f.HH = H;
                f.M = Cn; f.N = GFC;
                if (t == 5) f.hf = hfc_f;
                if (t == 0) {
                    f.A0 = xf_h; f.la0 = H; f.B0 = fih_p; f.lb0 = H; f.K0 = H;
                    f.init = 1;
                } else if (t <= 4) {
                    f.A0 = fcm_h + (size_t)(t - 1) * H; f.la0 = 4 * H;
                    f.B0 = fih_p; f.lb0 = H; f.K0 = H;
                    f.A1 = hfc[rb]; f.la1 = H; f.B1 = fhh_p; f.lb1 = H; f.K1 = H;
                } else {
                    f.A0 = xf_h; f.la0 = H; f.B0 = fih_p; f.lb0 = H; f.K0 = H;
                    f.A1 = hfc[rb]; f.la1 = H; f.B1 = fhh_p; f.lb1 = H; f.K1 = H;
                }
                gemm_one<1><<<dim3(GFC / 128, Mb), 256, 0, stream>>>(f);
            }
            // apply node func (f32 masters in)
            node_apply<<<(Cn * 64 + 255) / 256, 256, 0, stream>>>(
                xiou_f, h_uh_f, hfc_f,
                hbuf_h + (size_t)sa * H, cbuf + (size_t)sa * H, Cn);
        }
    }

    // ---- output projection (reads only ws; cbuf is dead) + LN/tanh ----
    {
        GArg a{};
        a.A0 = hbuf_h; a.la0 = H; a.B0 = ow_h; a.lb0 = H; a.K0 = H;
        a.bias = out_b; a.Cf = out; a.ldc = DEC; a.M = NNODES; a.N = DEC;
        gemm_one<0><<<dim3(DEC / 128, (NNODES + 127) / 128), 256, 0, stream>>>(a);
    }
    ln_tanh<<<(NNODES + 3) / 4, 256, 0, stream>>>(out, ln_g, ln_b, NNODES);
}